// Round 12
// baseline (249.647 us; speedup 1.0000x reference)
//
#include <hip/hip_runtime.h>
#include <hip/hip_bf16.h>
#include <math.h>

// Problem constants (fixed by setup_inputs)
#define SEQ    2048
#define BATCH  4
#define XDIM   16
#define DMODEL 256
#define NHEAD  8
#define DH     32
#define DFF    512
#define NLAYER 2
#define MPOS   1024
#define ROWS   (SEQ*BATCH)   // 8192

#define ATT_SCALE 0.17677669529663687f  // 1/sqrt(32)

typedef __attribute__((ext_vector_type(8))) short bf16x8;  // MFMA A/B frag
typedef __attribute__((ext_vector_type(4))) float f32x4;   // MFMA C/D frag

__device__ __forceinline__ float gelu_exact(float x) {
    return 0.5f * x * (1.0f + erff(x * 0.70710678118654752f));
}
__device__ __forceinline__ short f2bf(float f) {
    unsigned int u = __float_as_uint(f);
    u += 0x7FFFu + ((u >> 16) & 1u);
    return (short)(u >> 16);
}
__device__ __forceinline__ float bf2f(unsigned short u) {
    return __uint_as_float(((unsigned int)u) << 16);
}
__device__ __forceinline__ void gload16(const unsigned short* g, unsigned short* l) {
    __builtin_amdgcn_global_load_lds(
        (const __attribute__((address_space(1))) unsigned int*)g,
        (__attribute__((address_space(3))) unsigned int*)l, 16, 0, 0);
}
#define VMWAIT(N) asm volatile("s_waitcnt vmcnt(" #N ")" ::: "memory")
__device__ __forceinline__ void pipe_barrier() {
    __builtin_amdgcn_sched_barrier(0);
    __builtin_amdgcn_s_barrier();
    __builtin_amdgcn_sched_barrier(0);
}

// ---------------- encoder (4 rows/block) + weight casts, ONE launch -----------
__global__ __launch_bounds__(256) void encode_cast(
    const float* __restrict__ x, const float* __restrict__ y,
    const float* __restrict__ xw, const float* __restrict__ xb,
    const float* __restrict__ yw, const float* __restrict__ yb,
    float* __restrict__ h, unsigned short* __restrict__ hb,
    const float* __restrict__ s0, const float* __restrict__ s1,
    const float* __restrict__ s2, const float* __restrict__ s3,
    const float* __restrict__ s4,
    unsigned short* __restrict__ d0, unsigned short* __restrict__ d1,
    unsigned short* __restrict__ d2, unsigned short* __restrict__ d3,
    unsigned short* __restrict__ d4)
{
    if (blockIdx.x < ROWS/4) {
        int g = blockIdx.x;        // token index s (4 batch rows share it)
        int d = threadIdx.x;       // 0..255
        __shared__ float xs[4][XDIM];
        __shared__ float ys[4];
        if (d < 64) xs[d>>4][d&15] = x[(size_t)(g*4 + (d>>4))*XDIM + (d&15)];
        if (d < 4)  ys[d] = y[g*4 + d];
        __syncthreads();
        float wreg[XDIM];
        #pragma unroll
        for (int k = 0; k < XDIM; ++k) wreg[k] = xw[d*XDIM + k];
        const float xbv = xb[d], ywv = yw[d], ybv = yb[d];
        const bool train = (g < MPOS);
        #pragma unroll
        for (int r = 0; r < 4; ++r) {
            int row = g*4 + r;
            float acc = xbv;
            #pragma unroll
            for (int k = 0; k < XDIM; ++k) acc = fmaf(xs[r][k], wreg[k], acc);
            if (train) acc += ys[r]*ywv + ybv;
            h[(size_t)row*DMODEL + d]  = acc;
            hb[(size_t)row*DMODEL + d] = (unsigned short)f2bf(acc);
        }
        return;
    }
    int i = (blockIdx.x - ROWS/4)*256 + threadIdx.x;
    if (i >= 147456) return;
    const float* s; unsigned short* d; int off;
    if      (i <  49152) { s = s0; d = d0; off = i; }
    else if (i <  65536) { s = s1; d = d1; off = i - 49152; }
    else if (i <  98304) { s = s2; d = d2; off = i - 65536; }
    else if (i < 131072) { s = s3; d = d3; off = i - 98304; }
    else                 { s = s4; d = d4; off = i - 131072; }
    float4 a = *(const float4*)(s + (size_t)off*8);
    float4 c = *(const float4*)(s + (size_t)off*8 + 4);
    ushort4 u0, u1;
    u0.x=(unsigned short)f2bf(a.x); u0.y=(unsigned short)f2bf(a.y);
    u0.z=(unsigned short)f2bf(a.z); u0.w=(unsigned short)f2bf(a.w);
    u1.x=(unsigned short)f2bf(c.x); u1.y=(unsigned short)f2bf(c.y);
    u1.z=(unsigned short)f2bf(c.z); u1.w=(unsigned short)f2bf(c.w);
    *(ushort4*)(d + (size_t)off*8)     = u0;
    *(ushort4*)(d + (size_t)off*8 + 4) = u1;
}

// ------- qkv GEMM 128x64, BK=64 (NS=4), 2-buffer, swizzled, XCD-local A ------
__global__ __launch_bounds__(256) void gemm_qkv(
    const unsigned short* __restrict__ A, const unsigned short* __restrict__ B,
    const float* __restrict__ bias,
    unsigned short* __restrict__ Qg, unsigned short* __restrict__ Kg,
    unsigned short* __restrict__ Vg, int K)
{
    __shared__ unsigned short As[2][128][64];   // 32 KB (reused as transpose buf)
    __shared__ unsigned short Bs[2][64][64];    // 16 KB
    int tid  = threadIdx.x;
    int w    = tid >> 6, lane = tid & 63;
    int col  = lane & 15, quad = lane >> 4;
    int u    = blockIdx.x >> 3, xcd = blockIdx.x & 7;
    int by   = xcd*8 + u/12, bx = u%12;
    int m0   = by * 128, n0 = bx * 64;
    int l8   = lane >> 3;
    int c8s  = (((lane & 7) ^ l8) * 8);

    f32x4 acc[2][4];
    #pragma unroll
    for (int i = 0; i < 2; ++i)
        #pragma unroll
        for (int j = 0; j < 4; ++j) acc[i][j] = (f32x4){0.f,0.f,0.f,0.f};

    const unsigned short* ga = A + (size_t)(m0 + w*32 + l8)*K + c8s;
    const unsigned short* gb = B + (size_t)(n0 + w*16 + l8)*K + c8s;
    const int NS = K / 64;  // 4

    #pragma unroll
    for (int t = 0; t < 4; ++t) gload16(ga + (size_t)(t*8)*K, &As[0][w*32 + t*8][0]);
    #pragma unroll
    for (int t = 0; t < 2; ++t) gload16(gb + (size_t)(t*8)*K, &Bs[0][w*16 + t*8][0]);

    for (int s = 0; s < NS; ++s) {
        VMWAIT(0);
        pipe_barrier();
        if (s + 1 < NS) {
            int k2 = (s + 1) * 64;
            int nb = (s + 1) & 1;
            #pragma unroll
            for (int t = 0; t < 4; ++t) gload16(ga + k2 + (size_t)(t*8)*K, &As[nb][w*32 + t*8][0]);
            #pragma unroll
            for (int t = 0; t < 2; ++t) gload16(gb + k2 + (size_t)(t*8)*K, &Bs[nb][w*16 + t*8][0]);
        }
        int cur = s & 1;
        #pragma unroll
        for (int kk = 0; kk < 2; ++kk) {
            const int so = (((kk*4 + quad) ^ (col & 7)) * 8);
            bf16x8 af[2], bfr[4];
            #pragma unroll
            for (int i = 0; i < 2; ++i) af[i]  = *(const bf16x8*)&As[cur][w*32 + i*16 + col][so];
            #pragma unroll
            for (int j = 0; j < 4; ++j) bfr[j] = *(const bf16x8*)&Bs[cur][j*16 + col][so];
            #pragma unroll
            for (int i = 0; i < 2; ++i)
                #pragma unroll
                for (int j = 0; j < 4; ++j)
                    acc[i][j] = __builtin_amdgcn_mfma_f32_16x16x32_bf16(bfr[j], af[i], acc[i][j], 0, 0, 0);
        }
    }

    int region = n0 >> 8;   // 0=Q, 1=K, 2=V (uniform per block)
    if (region < 2) {
        #pragma unroll
        for (int i = 0; i < 2; ++i) {
            int m = m0 + w*32 + i*16 + col;
            int s = m >> 2, bidx = m & 3;
            #pragma unroll
            for (int j = 0; j < 4; ++j) {
                int ng = n0 + j*16 + quad*4;
                float4 bi = *(const float4*)&bias[ng];
                ushort4 uu;
                uu.x=(unsigned short)f2bf(acc[i][j][0] + bi.x);
                uu.y=(unsigned short)f2bf(acc[i][j][1] + bi.y);
                uu.z=(unsigned short)f2bf(acc[i][j][2] + bi.z);
                uu.w=(unsigned short)f2bf(acc[i][j][3] + bi.w);
                int np = ng - (region << 8);
                int hh = np >> 5, d = np & 31;
                int bh = bidx*NHEAD + hh;
                if (region == 0)
                    *(ushort4*)(Qg + ((size_t)(bh*SEQ + s))*DH + d) = uu;
                else
                    *(ushort4*)(Kg + ((size_t)(bh*SEQ + s))*DH + d) = uu;
            }
        }
    } else {
        __syncthreads();
        unsigned short* T3 = (unsigned short*)As;   // 16 KB scratch
        #pragma unroll
        for (int i = 0; i < 2; ++i) {
            int mi = w*32 + i*16 + col;
            int ss = mi >> 2, bidx = mi & 3;
            #pragma unroll
            for (int j = 0; j < 4; ++j) {
                int ni = j*16 + quad*4;
                float4 bi = *(const float4*)&bias[n0 + ni];
                T3[((ni    )*4 + bidx)*32 + ss] = (unsigned short)f2bf(acc[i][j][0] + bi.x);
                T3[((ni + 1)*4 + bidx)*32 + ss] = (unsigned short)f2bf(acc[i][j][1] + bi.y);
                T3[((ni + 2)*4 + bidx)*32 + ss] = (unsigned short)f2bf(acc[i][j][2] + bi.z);
                T3[((ni + 3)*4 + bidx)*32 + ss] = (unsigned short)f2bf(acc[i][j][3] + bi.w);
            }
        }
        __syncthreads();
        int sBase = m0 >> 2;
        #pragma unroll
        for (int r = 0; r < 4; ++r) {
            int chunk = tid + 256*r;
            int l = chunk >> 2, p = chunk & 3;
            int d = l & 31, hh_l = (l >> 5) & 1, bidx = l >> 6;
            int ni = hh_l*32 + d;
            int hh = ((n0 & 255) + ni) >> 5;
            int bh = bidx*NHEAD + hh;
            uint4 val = *(const uint4*)&T3[(ni*4 + bidx)*32 + p*8];
            *(uint4*)(Vg + ((size_t)(bh*DH + d))*SEQ + sBase + p*8) = val;
        }
    }
}

// ---------------- MFMA flash attention, QUAD q-tile, KVBLK=128 ---------------
// Block owns 4 q-tiles: A0=q0, A1=q0+64 (low, <MPOS), B0=MPOS+q0, B1=MPOS+q0+64.
// K/V staging + barriers shared by all four. 8 main 128-key tiles + one 128-key
// diag tile (B0 masks first-64 diag, B1 second-64 diag; exact +0 elsewhere).
__global__ __launch_bounds__(256) void attn_mfma(
    const unsigned short* __restrict__ Qg,
    const unsigned short* __restrict__ Kg,
    const unsigned short* __restrict__ Vg,
    unsigned short* __restrict__ o)           // bf16 [s*B+b][256]
{
    const int id  = blockIdx.x;               // 0..255
    const int sl  = id >> 3;                  // 0..31
    const int bh  = (id & 7) * 4 + (sl >> 3); // XCD (id&7) owns bh [4x,4x+4)
    const int qt4 = sl & 7;
    const int h   = bh & 7;
    const int b   = bh >> 3;
    const int q0  = qt4 * 128;
    const int tid  = threadIdx.x;
    const int w    = tid >> 6;
    const int lane = tid & 63;
    const int col  = lane & 15;
    const int quad = lane >> 4;

    __shared__ unsigned short Kt[2][128][40];    // 20 KB
    __shared__ unsigned short Vt[2][32][136];    // 17 KB
    __shared__ unsigned short PtA0[4][16][136];  // 17 KB each
    __shared__ unsigned short PtA1[4][16][136];
    __shared__ unsigned short PtB0[4][16][136];
    __shared__ unsigned short PtB1[4][16][136];

    const int qA0 = q0 + 16*w + col;
    const int qA1 = q0 + 64 + 16*w + col;
    const int qB0 = MPOS + q0 + 16*w + col;
    const int qB1 = MPOS + q0 + 64 + 16*w + col;
    bf16x8 qfA0 = *(const bf16x8*)(Qg + ((size_t)(bh*SEQ + qA0))*DH + quad*8);
    bf16x8 qfA1 = *(const bf16x8*)(Qg + ((size_t)(bh*SEQ + qA1))*DH + quad*8);
    bf16x8 qfB0 = *(const bf16x8*)(Qg + ((size_t)(bh*SEQ + qB0))*DH + quad*8);
    bf16x8 qfB1 = *(const bf16x8*)(Qg + ((size_t)(bh*SEQ + qB1))*DH + quad*8);

    f32x4 O0A0 = {0.f,0.f,0.f,0.f}, O1A0 = {0.f,0.f,0.f,0.f};
    f32x4 O0A1 = {0.f,0.f,0.f,0.f}, O1A1 = {0.f,0.f,0.f,0.f};
    f32x4 O0B0 = {0.f,0.f,0.f,0.f}, O1B0 = {0.f,0.f,0.f,0.f};
    f32x4 O0B1 = {0.f,0.f,0.f,0.f}, O1B1 = {0.f,0.f,0.f,0.f};
    float lsumA0 = 0.f, lsumA1 = 0.f, lsumB0 = 0.f, lsumB1 = 0.f;

    const int kRow = tid >> 2, kCh = (tid & 3) * 8;
    const int vD   = tid >> 3, vCh = (tid & 7) * 8;

    uint4 kreg0 = *(const uint4*)(Kg + ((size_t)(bh*SEQ + kRow     ))*DH + kCh);
    uint4 kreg1 = *(const uint4*)(Kg + ((size_t)(bh*SEQ + kRow + 64))*DH + kCh);
    uint4 vreg0 = *(const uint4*)(Vg + ((size_t)(bh*DH + vD))*SEQ + vCh);
    uint4 vreg1 = *(const uint4*)(Vg + ((size_t)(bh*DH + vD))*SEQ + vCh + 64);

    for (int kt = 0; kt < 8; ++kt) {
        const int p = kt & 1;
        *(uint4*)&Kt[p][kRow     ][kCh] = kreg0;
        *(uint4*)&Kt[p][kRow + 64][kCh] = kreg1;
        *(uint4*)&Vt[p][vD][vCh     ]   = vreg0;
        *(uint4*)&Vt[p][vD][vCh + 64]   = vreg1;
        __syncthreads();
        {
            int kn = (kt < 7) ? (kt + 1) * 128 : (MPOS + q0);
            kreg0 = *(const uint4*)(Kg + ((size_t)(bh*SEQ + kn + kRow     ))*DH + kCh);
            kreg1 = *(const uint4*)(Kg + ((size_t)(bh*SEQ + kn + kRow + 64))*DH + kCh);
            vreg0 = *(const uint4*)(Vg + ((size_t)(bh*DH + vD))*SEQ + kn + vCh);
            vreg1 = *(const uint4*)(Vg + ((size_t)(bh*DH + vD))*SEQ + kn + vCh + 64);
        }

        #pragma unroll
        for (int mt = 0; mt < 8; ++mt) {
            bf16x8 kf = *(const bf16x8*)&Kt[p][mt*16 + col][quad*8];
            f32x4 st; ushort4 pw;

            st = (f32x4){0.f,0.f,0.f,0.f};
            st = __builtin_amdgcn_mfma_f32_16x16x32_bf16(kf, qfA0, st, 0, 0, 0);
            #pragma unroll
            for (int i = 0; i < 4; ++i) {
                unsigned short us = (unsigned short)f2bf(__expf(st[i]*ATT_SCALE));
                ((unsigned short*)&pw)[i] = us; lsumA0 += bf2f(us);
            }
            *(ushort4*)&PtA0[w][col][mt*16 + quad*4] = pw;

            st = (f32x4){0.f,0.f,0.f,0.f};
            st = __builtin_amdgcn_mfma_f32_16x16x32_bf16(kf, qfA1, st, 0, 0, 0);
            #pragma unroll
            for (int i = 0; i < 4; ++i) {
                unsigned short us = (unsigned short)f2bf(__expf(st[i]*ATT_SCALE));
                ((unsigned short*)&pw)[i] = us; lsumA1 += bf2f(us);
            }
            *(ushort4*)&PtA1[w][col][mt*16 + quad*4] = pw;

            st = (f32x4){0.f,0.f,0.f,0.f};
            st = __builtin_amdgcn_mfma_f32_16x16x32_bf16(kf, qfB0, st, 0, 0, 0);
            #pragma unroll
            for (int i = 0; i < 4; ++i) {
                unsigned short us = (unsigned short)f2bf(__expf(st[i]*ATT_SCALE));
                ((unsigned short*)&pw)[i] = us; lsumB0 += bf2f(us);
            }
            *(ushort4*)&PtB0[w][col][mt*16 + quad*4] = pw;

            st = (f32x4){0.f,0.f,0.f,0.f};
            st = __builtin_amdgcn_mfma_f32_16x16x32_bf16(kf, qfB1, st, 0, 0, 0);
            #pragma unroll
            for (int i = 0; i < 4; ++i) {
                unsigned short us = (unsigned short)f2bf(__expf(st[i]*ATT_SCALE));
                ((unsigned short*)&pw)[i] = us; lsumB1 += bf2f(us);
            }
            *(ushort4*)&PtB1[w][col][mt*16 + quad*4] = pw;
        }
        #pragma unroll
        for (int c = 0; c < 4; ++c) {
            bf16x8 v0 = *(const bf16x8*)&Vt[p][col     ][c*32 + quad*8];
            bf16x8 v1 = *(const bf16x8*)&Vt[p][col + 16][c*32 + quad*8];
            bf16x8 pf;
            pf = *(const bf16x8*)&PtA0[w][col][c*32 + quad*8];
            O0A0 = __builtin_amdgcn_mfma_f32_16x16x32_bf16(v0, pf, O0A0, 0, 0, 0);
            O1A0 = __builtin_amdgcn_mfma_f32_16x16x32_bf16(v1, pf, O1A0, 0, 0, 0);
            pf = *(const bf16x8*)&PtA1[w][col][c*32 + quad*8];
            O0A1 = __builtin_amdgcn_mfma_f32_16x16x32_bf16(v0, pf, O0A1, 0, 0, 0);
            O1A1 = __builtin_amdgcn_mfma_f32_16x16x32_bf16(v1, pf, O1A1, 0, 0, 0);
            pf = *(const bf16x8*)&PtB0[w][col][c*32 + quad*8];
            O0B0 = __builtin_amdgcn_mfma_f32_16x16x32_bf16(v0, pf, O0B0, 0, 0, 0);
            O1B0 = __builtin_amdgcn_mfma_f32_16x16x32_bf16(v1, pf, O1B0, 0, 0, 0);
            pf = *(const bf16x8*)&PtB1[w][col][c*32 + quad*8];
            O0B1 = __builtin_amdgcn_mfma_f32_16x16x32_bf16(v0, pf, O0B1, 0, 0, 0);
            O1B1 = __builtin_amdgcn_mfma_f32_16x16x32_bf16(v1, pf, O1B1, 0, 0, 0);
        }
    }

    // ---- diag tile (keys [MPOS+q0, MPOS+q0+128)), buffer 0 ----
    // Buffer 0 last read at kt=6; all waves passed kt=7's barrier since.
    *(uint4*)&Kt[0][kRow     ][kCh] = kreg0;
    *(uint4*)&Kt[0][kRow + 64][kCh] = kreg1;
    *(uint4*)&Vt[0][vD][vCh     ]   = vreg0;
    *(uint4*)&Vt[0][vD][vCh + 64]   = vreg1;
    __syncthreads();
    #pragma unroll
    for (int mt = 0; mt < 4; ++mt) {   // B0: keys 0..63 of tile
        bf16x8 kf = *(const bf16x8*)&Kt[0][mt*16 + col][quad*8];
        f32x4 st = {0.f,0.f,0.f,0.f};
        st = __builtin_amdgcn_mfma_f32_16x16x32_bf16(kf, qfB0, st, 0, 0, 0);
        ushort4 pw;
        #pragma unroll
        for (int i = 0; i < 4; ++i) {
            float pv = __expf(st[i]*ATT_SCALE);
            if (mt*16 + quad*4 + i != 16*w + col) pv = 0.f;
            unsigned short us = (unsigned short)f2bf(pv);
            ((unsigned short*)&pw)[i] = us; lsumB0 += bf2f(us);
        }
        *(ushort4*)&PtB0[w][col][mt*16 + quad*4] = pw;
    }
    #pragma unroll
    for (int mt = 4; mt < 8; ++mt) {   // B1: keys 64..127 of tile
        bf16x8 kf = *(const bf16x8*)&Kt[0][mt*16 + col][quad*8];
        f32x4 st = {0.f,0.f,0.f,0.f};
        st = __builtin_amdgcn_mfma_f32_16x16x32_bf16(kf, qfB1, st, 0, 0, 0);
        ushort4 pw;
        #pragma unroll
        for (int i = 0; i < 4; ++i) {
            float pv = __expf(st[i]*ATT_SCALE);
            if (mt*16 + quad*4 + i - 64 != 16*w + col) pv = 0.f;
            unsigned short us = (unsigned short)f2bf(pv);
            ((unsigned short*)&pw)[i] = us; lsumB1 += bf2f(us);
        }
        *(ushort4*)&PtB1[w][col][(mt-4)*16 + quad*4] = pw;
    }
    #pragma unroll
    for (int c = 0; c < 2; ++c) {      // B0 PV over keys 0..63
        bf16x8 v0 = *(const bf16x8*)&Vt[0][col     ][c*32 + quad*8];
        bf16x8 v1 = *(const bf16x8*)&Vt[0][col + 16][c*32 + quad*8];
        bf16x8 pf = *(const bf16x8*)&PtB0[w][col][c*32 + quad*8];
        O0B0 = __builtin_amdgcn_mfma_f32_16x16x32_bf16(v0, pf, O0B0, 0, 0, 0);
        O1B0 = __builtin_amdgcn_mfma_f32_16x16x32_bf16(v1, pf, O1B0, 0, 0, 0);
    }
    #pragma unroll
    for (int c = 0; c < 2; ++c) {      // B1 PV over keys 64..127
        bf16x8 v0 = *(const bf16x8*)&Vt[0][col     ][(c+2)*32 + quad*8];
        bf16x8 v1 = *(const bf16x8*)&Vt[0][col + 16][(c+2)*32 + quad*8];
        bf16x8 pf = *(const bf16x8*)&PtB1[w][col][c*32 + quad*8];
        O0B1 = __builtin_amdgcn_mfma_f32_16x16x32_bf16(v0, pf, O0B1, 0, 0, 0);
        O1B1 = __builtin_amdgcn_mfma_f32_16x16x32_bf16(v1, pf, O1B1, 0, 0, 0);
    }

    lsumA0 += __shfl_xor(lsumA0, 16, 64); lsumA0 += __shfl_xor(lsumA0, 32, 64);
    lsumA1 += __shfl_xor(lsumA1, 16, 64); lsumA1 += __shfl_xor(lsumA1, 32, 64);
    lsumB0 += __shfl_xor(lsumB0, 16, 64); lsumB0 += __shfl_xor(lsumB0, 32, 64);
    lsumB1 += __shfl_xor(lsumB1, 16, 64); lsumB1 += __shfl_xor(lsumB1, 32, 64);
    float invA0 = 1.0f / lsumA0, invA1 = 1.0f / lsumA1;
    float invB0 = 1.0f / lsumB0, invB1 = 1.0f / lsumB1;
    ushort4 u0, u1;
    #pragma unroll
    for (int i = 0; i < 4; ++i) {
        ((unsigned short*)&u0)[i] = (unsigned short)f2bf(O0A0[i]*invA0);
        ((unsigned short*)&u1)[i] = (unsigned short)f2bf(O1A0[i]*invA0);
    }
    unsigned short* op = o + ((size_t)(qA0*BATCH + b))*DMODEL + h*DH;
    *(ushort4*)(op + quad*4) = u0; *(ushort4*)(op + 16 + quad*4) = u1;
    #pragma unroll
    for (int i = 0; i < 4; ++i) {
        ((unsigned short*)&u0)[i] = (unsigned short)f2bf(O0A1[i]*invA1);
        ((unsigned short*)&u1)[i] = (unsigned short)f2bf(O1A1[i]*invA1);
    }
    op = o + ((size_t)(qA1*BATCH + b))*DMODEL + h*DH;
    *(ushort4*)(op + quad*4) = u0; *(ushort4*)(op + 16 + quad*4) = u1;
    #pragma unroll
    for (int i = 0; i < 4; ++i) {
        ((unsigned short*)&u0)[i] = (unsigned short)f2bf(O0B0[i]*invB0);
        ((unsigned short*)&u1)[i] = (unsigned short)f2bf(O1B0[i]*invB0);
    }
    op = o + ((size_t)(qB0*BATCH + b))*DMODEL + h*DH;
    *(ushort4*)(op + quad*4) = u0; *(ushort4*)(op + 16 + quad*4) = u1;
    #pragma unroll
    for (int i = 0; i < 4; ++i) {
        ((unsigned short*)&u0)[i] = (unsigned short)f2bf(O0B1[i]*invB1);
        ((unsigned short*)&u1)[i] = (unsigned short)f2bf(O1B1[i]*invB1);
    }
    op = o + ((size_t)(qB1*BATCH + b))*DMODEL + h*DH;
    *(ushort4*)(op + quad*4) = u0; *(ushort4*)(op + 16 + quad*4) = u1;
}

// ------- fused MLP, TWO 16-row groups per block, BK=64, T14 stage hoists ------
__global__ __launch_bounds__(256) void mlp_fused(
    const unsigned short* __restrict__ attb,
    const unsigned short* __restrict__ Wout, const float* __restrict__ ob,
    const float* __restrict__ g1, const float* __restrict__ be1,
    const unsigned short* __restrict__ W1, const float* __restrict__ fb1,
    const unsigned short* __restrict__ W2, const float* __restrict__ fb2,
    const float* __restrict__ g2, const float* __restrict__ be2,
    float* __restrict__ h, unsigned short* __restrict__ hb,
    const unsigned short* __restrict__ Wh1, const float* __restrict__ hb1,
    const float* __restrict__ hw2, const float* __restrict__ hb2,
    float* __restrict__ out, int doHead)
{
    __shared__ unsigned short Bs[3][256][64];         // 96 KB weight staging
    __shared__ __align__(16) unsigned char smem_u[33280];  // As (12 KB) / Pt (32.5 KB)
    __shared__ unsigned short Ht[2][16][264];         // LN1-out / LN2-out bf16
    __shared__ float sP[2][4][16], qP[2][4][16];

    typedef unsigned short AsT[2][16][64];
    AsT* As = reinterpret_cast<AsT*>(smem_u);
    typedef unsigned short PtT[16][520];
    PtT* Pt = reinterpret_cast<PtT*>(smem_u);

    const int tid  = threadIdx.x;
    const int w    = tid >> 6;
    const int lane = tid & 63;
    const int col  = lane & 15;
    const int quad = lane >> 4;
    const int l8   = lane >> 3;
    const int c8s  = (((lane & 7) ^ l8) * 8);
    const int bid  = blockIdx.x;
    const int m0a  = bid * 16;
    const int m0b  = 4096 + bid * 16;
    const int ma   = m0a + col;
    const int mb   = m0b + col;

    float resid[2][4][4];

    // ================= stage A: out-proj (K=256, NS=4) + residual + LN1 =======
    {
        f32x4 acc[2][4];
        #pragma unroll
        for (int g = 0; g < 2; ++g)
            #pragma unroll
            for (int j = 0; j < 4; ++j) acc[g][j] = (f32x4){0.f,0.f,0.f,0.f};

        const int gr = w >> 1;
        const unsigned short* gaw = attb + (size_t)((gr ? m0b : m0a) + (w&1)*8 + l8)*DMODEL + c8s;
        const unsigned short* gb  = Wout + (size_t)(w*64 + l8)*DMODEL + c8s;
        const int NS = DMODEL / 64;  // 4

        #pragma unroll
        for (int pb = 0; pb < 2; ++pb) {
            int k = pb * 64;
            gload16(gaw + k, &As[pb][gr][(w&1)*8][0]);
            #pragma unroll
            for (int t = 0; t < 8; ++t)
                gload16(gb + k + (size_t)(t*8)*DMODEL, &Bs[pb][w*64 + t*8][0]);
        }
        int bcur = 0;
        for (int s = 0; s < NS; ++s) {
            if (s == NS - 1) { VMWAIT(0); } else { VMWAIT(9); }
            pipe_barrier();
            if (s + 2 < NS) {
                int bpre = bcur + 2; if (bpre >= 3) bpre -= 3;
                int k2 = (s + 2) * 64;
                gload16(gaw + k2, &As[bpre][gr][(w&1)*8][0]);
                #pragma unroll
                for (int t = 0; t < 8; ++t)
                    gload16(gb + k2 + (size_t)(t*8)*DMODEL, &Bs[bpre][w*64 + t*8][0]);
            }
            #pragma unroll
            for (int kk = 0; kk < 2; ++kk) {
                const int so = (((kk*4 + quad) ^ (col & 7)) * 8);
                bf16x8 af0 = *(const bf16x8*)&As[bcur][0][col][so];
                bf16x8 af1 = *(const bf16x8*)&As[bcur][1][col][so];
                #pragma unroll
                for (int j = 0; j < 4; ++j) {
                    bf16x8 bfr = *(const bf16x8*)&Bs[bcur][w*64 + j*16 + col][so];
                    acc[0][j] = __builtin_amdgcn_mfma_f32_16x16x32_bf16(bfr, af0, acc[0][j], 0, 0, 0);
                    acc[1][j] = __builtin_amdgcn_mfma_f32_16x16x32_bf16(bfr, af1, acc[1][j], 0, 0, 0);
                }
            }
            bcur = (bcur == 2) ? 0 : bcur + 1;
        }
        pipe_barrier();   // all waves past Bs/As reads

        // residual loads FIRST (so their waits don't drain the hoisted staging)
        float4 hv[2][4];
        #pragma unroll
        for (int g = 0; g < 2; ++g) {
            int m = g ? mb : ma;
            #pragma unroll
            for (int j = 0; j < 4; ++j)
                hv[g][j] = *(const float4*)&h[(size_t)m*DMODEL + w*64 + j*16 + quad*4];
        }
        // T14 hoist: stage B nh=0 staging in flight under the LN epilogue
        {
            const unsigned short* gbB = W1 + (size_t)(w*64 + l8)*DMODEL + c8s;
            #pragma unroll
            for (int pb = 0; pb < 2; ++pb)
                #pragma unroll
                for (int t = 0; t < 8; ++t)
                    gload16(gbB + pb*64 + (size_t)(t*8)*DMODEL, &Bs[pb][w*64 + t*8][0]);
        }

        float ssum[2] = {0.f, 0.f}, qsum[2] = {0.f, 0.f};
        #pragma unroll
        for (int g = 0; g < 2; ++g)
            #pragma unroll
            for (int j = 0; j < 4; ++j) {
                int n = w*64 + j*16 + quad*4;
                float4 bi = *(const float4*)&ob[n];
                #pragma unroll
                for (int i = 0; i < 4; ++i) {
                    float val = acc[g][j][i] + ((const float*)&bi)[i] + ((const float*)&hv[g][j])[i];
                    resid[g][j][i] = val;
                    ssum[g] += val; qsum[g] += val*val;
                }
            }
        #pragma unroll
        for (int g = 0; g < 2; ++g) {
            ssum[g] += __shfl_xor(ssum[g], 16, 64); ssum[g] += __shfl_xor(ssum[g], 32, 64);
            qsum[g] += __shfl_xor(qsum[g], 16, 64); qsum[g] += __shfl_xor(qsum[g], 32, 64);
        }
        if (quad == 0) {
            sP[0][w][col] = ssum[0]; qP[0][w][col] = qsum[0];
            sP[1][w][col] = ssum[1]; qP[1][w][col] = qsum[1];
        }
        __syncthreads();
        #pragma unroll
        for (int g = 0; g < 2; ++g) {
            float st = sP[g][0][col] + sP[g][1][col] + sP[g][2][col] + sP[g][3][col];
            float qt = qP[g][0][col] + qP[g][1][col] + qP[g][2][col] + qP[g][3][col];
            float mu   = st * (1.0f/DMODEL);
            float var  = qt * (1.0f/DMODEL) - mu*mu;
            float rstd = rsqrtf(var + 1e-5f);
            #pragma unroll
            for (int j = 0; j < 4; ++j) {
                int n = w*64 + j*16 + quad*4;
                float4 gv = *(const float4*)&g1[n];
                float4 bv = *(const float4*)&be1[n];
                ushort4 u;
                #pragma unroll
                for (int i = 0; i < 4; ++i) {
                    float o = (resid[g][j][i]-mu)*rstd*((const float*)&gv)[i] + ((const float*)&bv)[i];
                    resid[g][j][i] = o;
                    ((unsigned short*)&u)[i] = (unsigned short)f2bf(o);
                }
                *(ushort4*)&Ht[g][col][n] = u;
            }
        }
        __syncthreads();
    }

    // ================= stage B: ff1 (K=256 NS=4, two N-halves) + gelu =========
    #pragma unroll 1
    for (int nh = 0; nh < 2; ++nh) {
        f32x4 acc[2][4];
        #pragma unroll
        for (int g = 0; g < 2; ++g)
            #pragma unroll
            for (int j = 0; j < 4; ++j) acc[g][j] = (f32x4){0.f,0.f,0.f,0.f};
        const unsigned short* gb = W1 + (size_t)(nh*256 + w*64 + l8)*DMODEL + c8s;
        const int NS = DMODEL / 64;  // 4
        // pb0/pb1 already staged by previous stage's epilogue hoist
        int bcur = 0;
        for (int s = 0; s < NS; ++s) {
            if (s == NS - 1) { VMWAIT(0); } else { VMWAIT(8); }
            pipe_barrier();
            if (s + 2 < NS) {
                int bpre = bcur + 2; if (bpre >= 3) bpre -= 3;
                int k2 = (s + 2) * 64;
                #pragma unroll
                for (int t = 0; t < 8; ++t)
                    gload16(gb + k2 + (size_t)(t*8)*DMODEL, &Bs[bpre][w*64 + t*8][0]);
            }
            #pragma unroll
            for (int kk = 0; kk < 2; ++kk) {
                const int so = (((kk*4 + quad) ^ (col & 7)) * 8);
                bf16x8 af0 = *(const bf16x8*)&Ht[0][col][s*64 + kk*32 + quad*8];
                bf16x8 af1 = *(const bf16x8*)&Ht[1][col][s*64 + kk*32 + quad*8];
                #pragma unroll
                for (int j = 0; j < 4; ++j) {
                    bf16x8 bfr = *(const bf16x8*)&Bs[bcur][w*64 + j*16 + col][so];
                    acc[0][j] = __builtin_amdgcn_mfma_f32_16x16x32_bf16(bfr, af0, acc[0][j], 0, 0, 0);
                    acc[1][j] = __builtin_amdgcn_mfma_f32_16x16x32_bf16(bfr, af1, acc[1][j], 0, 0, 0);
                }
            }
            bcur = (bcur == 2) ? 0 : bcur + 1;
        }
        pipe_barrier();   // all waves past Bs reads
        // T14 hoist: next phase's pb0/pb1 staging under the gelu epilogue
        if (nh == 0) {
            const unsigned short* gb2 = W1 + (size_t)(256 + w*64 + l8)*DMODEL + c8s;
            #pragma unroll
            for (int pb = 0; pb < 2; ++pb)
                #pragma unroll
                for (int t = 0; t < 8; ++t)
                    gload16(gb2 + pb*64 + (size_t)(t*8)*DMODEL, &Bs[pb][w*64 + t*8][0]);
        } else {
            const unsigned short* gbC = W2 + (size_t)(w*64 + l8)*DFF + c8s;
            #pragma unroll
            for (int pb = 0; pb < 2; ++pb)
                #pragma unroll
                for (int t = 0; t < 8; ++t)
                    gload16(gbC + pb*64 + (size_t)(t*8)*DFF, &Bs[pb][w*64 + t*8][0]);
        }
        #pragma unroll
        for (int g = 0; g < 2; ++g)
            #pragma unroll
            for (int j = 0; j < 4; ++j) {
                int n2 = nh*256 + w*64 + j*16 + quad*4;
                float4 bi = *(const float4*)&fb1[n2];
                ushort4 u;
                #pragma unroll
                for (int i = 0; i < 4; ++i)
                    ((unsigned short*)&u)[i] = (unsigned short)f2bf(gelu_exact(acc[g][j][i] + ((const float*)&bi)[i]));
                *(ushort4*)&Pt[g][col][n2] = u;
            }
    }

    // ================= stage C: ff2 (K=512 NS=8) + residual + LN2 =============
    {
        __syncthreads();  // Pt visible
        f32x4 acc[2][4];
        #pragma unroll
        for (int g = 0; g < 2; ++g)
            #pragma unroll
            for (int j = 0; j < 4; ++j) acc[g][j] = (f32x4){0.f,0.f,0.f,0.f};
        const unsigned short* gb = W2 + (size_t)(w*64 + l8)*DFF + c8s;
        const int NS = DFF / 64;  // 8
        // pb0/pb1 already staged by stage B nh=1 epilogue hoist
        int bcur = 0;
        for (int s = 0; s < NS; ++s) {
            if (s == NS - 1) { VMWAIT(0); } else { VMWAIT(8); }
            pipe_barrier();
            if (s + 2 < NS) {
                int bpre = bcur + 2; if (bpre >= 3) bpre -= 3;
                int k2 = (s + 2) * 64;
                #pragma unroll
                for (int t = 0; t < 8; ++t)
                    gload16(gb + k2 + (size_t)(t*8)*DFF, &Bs[bpre][w*64 + t*8][0]);
            }
            #pragma unroll
            for (int kk = 0; kk < 2; ++kk) {
                const int so = (((kk*4 + quad) ^ (col & 7)) * 8);
                bf16x8 af0 = *(const bf16x8*)&Pt[0][col][s*64 + kk*32 + quad*8];
                bf16x8 af1 = *(const bf16x8*)&Pt[1][col][s*64 + kk*32 + quad*8];
                #pragma unroll
                for (int j = 0; j < 4; ++j) {
                    bf16x8 bfr = *(const bf16x8*)&Bs[bcur][w*64 + j*16 + col][so];
                    acc[0][j] = __builtin_amdgcn_mfma_f32_16x16x32_bf16(bfr, af0, acc[0][j], 0, 0, 0);
                    acc[1][j] = __builtin_amdgcn_mfma_f32_16x16x32_bf16(bfr, af1, acc[1][j], 0, 0, 0);
                }
            }
            bcur = (bcur == 2) ? 0 : bcur + 1;
        }

        float ssum[2] = {0.f, 0.f}, qsum[2] = {0.f, 0.f};
        #pragma unroll
        for (int g = 0; g < 2; ++g)
            #pragma unroll
            for (int j = 0; j < 4; ++j) {
                int n = w*64 + j*16 + quad*4;
                float4 bi = *(const float4*)&fb2[n];
                #pragma unroll
                for (int i = 0; i < 4; ++i) {
                    float val = acc[g][j][i] + ((const float*)&bi)[i] + resid[g][j][i];
                    resid[g][j][i] = val;
                    ssum[g] += val; qsum[g] += val*val;
                }
            }
        #pragma unroll
        for (int g = 0; g < 2; ++g) {
            ssum[g] += __shfl_xor(ssum[g], 16, 64); ssum[g] += __shfl_xor(ssum[g], 32, 64);
            qsum[g] += __shfl_xor(qsum[g], 16, 64); qsum[g] += __shfl_xor(qsum[g], 32, 64);
        }
        if (quad == 0) {
            sP[0][w][col] = ssum[0]; qP[0][w][col] = qsum[0];
            sP[1][w][col] = ssum[1]; qP[1][w][col] = qsum[1];
        }
        __syncthreads();
        #pragma unroll
        for (int g = 0; g < 2; ++g) {
            int m = g ? mb : ma;
            float st = sP[g][0][col] + sP[g][1][col] + sP[g][2][col] + sP[g][3][col];
            float qt = qP[g][0][col] + qP[g][1][col] + qP[g][2][col] + qP[g][3][col];
            float mu   = st * (1.0f/DMODEL);
            float var  = qt * (1.0f/DMODEL) - mu*mu;
            float rstd = rsqrtf(var + 1e-5f);
            #pragma unroll
            for (int j = 0; j < 4; ++j) {
                int n = w*64 + j*16 + quad*4;
                float4 gv = *(const float4*)&g2[n];
                float4 bv = *(const float4*)&be2[n];
                float4 o;
                ushort4 u;
                #pragma unroll
                for (int i = 0; i < 4; ++i) {
                    float ov = (resid[g][j][i]-mu)*rstd*((const float*)&gv)[i] + ((const float*)&bv)[i];
                    ((float*)&o)[i] = ov;
                    ((unsigned short*)&u)[i] = (unsigned short)f2bf(ov);
                }
                *(float4*)&h[(size_t)m*DMODEL + n] = o;
                *(ushort4*)(hb + (size_t)m*DMODEL + n) = u;
                *(ushort4*)&Ht[g][col][n] = u;
            }
        }
        __syncthreads();
    }

    // ================= stage D: head (layer 1; 16 head rows per block) ========
    if (doHead) {
        float sdot = 0.f;
        #pragma unroll 1
        for (int nh = 0; nh < 2; ++nh) {
            f32x4 acc[4];
            #pragma unroll
            for (int j = 0; j < 4; ++j) acc[j] = (f32x4){0.f,0.f,0.f,0.f};
            const unsigned short* gb = Wh1 + (size_t)(nh*256 + w*64 + l8)*DMODEL + c8s;
            const int NS = DMODEL / 64;  // 4

            #pragma unroll
            for (int pb = 0; pb < 2; ++pb)
                #pragma unroll
                for (int t = 0; t < 8; ++t)
                    gload16(gb + pb*64 + (size_t)(t*8)*DMODEL, &Bs[pb][w*64 + t*8][0]);

            int bcur = 0;
            for (int s = 0; s < NS; ++s) {
                if (s == NS - 1) { VMWAIT(0); } else { VMWAIT(8); }
                pipe_barrier();
                if (s + 2 < NS) {
                    int bpre = bcur + 2; if (bpre >= 3) bpre -= 3;
                    int k2 = (s + 2) * 64;
                    #pragma unroll
                    for (int t = 0; t < 8; ++t)
                        gload16(gb + k2 + (size_t)(t*8)*DMODEL, &Bs[bpre][w*64 + t*8][0]);
                }
                #pragma unroll
                for (int kk = 0; kk < 2; ++kk) {
                    const int so = (((kk*4 + quad) ^ (col & 7)) * 8);
                    bf16x8 af = *(const bf16x8*)&Ht[1][col][s*64 + kk*32 + quad*8];
                    #pragma unroll
                    for (int j = 0; j < 4; ++j) {
                        bf16x8 bfr = *(const bf16x8*)&Bs[bcur][w*64 + j*16 + col][so];
                        acc[j] = __builtin_amdgcn_mfma_f32_16x16x32_bf16(bfr, af, acc[j], 0, 0, 0);
                    }
                }
                bcur = (bcur == 2) ? 0 : bcur + 1;
            }
            #pragma unroll
            for (int j = 0; j < 4; ++j) {
                int n2 = nh*256 + w*64 + j*16 + quad*4;
                float4 b1v = *(const float4*)&hb1[n2];
                float4 w2v = *(const float4*)&hw2[n2];
                #pragma unroll
                for (int i = 0; i < 4; ++i)
                    sdot += gelu_exact(acc[j][i] + ((const float*)&b1v)[i]) * ((const float*)&w2v)[i];
            }
            pipe_barrier();
        }
        sdot += __shfl_xor(sdot, 16, 64); sdot += __shfl_xor(sdot, 32, 64);
        if (quad == 0) sP[0][w][col] = sdot;
        __syncthreads();
        if (tid < 16)
            out[bid*16 + tid] = sP[0][0][tid] + sP[0][1][tid] + sP[0][2][tid] + sP[0][3][tid] + hb2[0];
    }
}

extern "C" void kernel_launch(void* const* d_in, const int* in_sizes, int n_in,
                              void* d_out, int out_size, void* d_ws, size_t ws_size,
                              hipStream_t stream)
{
    const float* x        = (const float*)d_in[0];
    const float* y        = (const float*)d_in[1];
    const float* xenc_w   = (const float*)d_in[3];
    const float* xenc_b   = (const float*)d_in[4];
    const float* yenc_w   = (const float*)d_in[5];
    const float* yenc_b   = (const float*)d_in[6];
    const float* in_proj_w  = (const float*)d_in[7];
    const float* in_proj_b  = (const float*)d_in[8];
    const float* out_proj_w = (const float*)d_in[9];
    const float* out_proj_b = (const float*)d_in[10];
    const float* ln1_g    = (const float*)d_in[11];
    const float* ln1_b    = (const float*)d_in[12];
    const float* lin1_w   = (const float*)d_in[13];
    const float* lin1_b   = (const float*)d_in[14];
    const float* lin2_w   = (const float*)d_in[15];
    const float* lin2_b   = (const float*)d_in[16];
    const float* ln2_g    = (const float*)d_in[17];
    const float* ln2_b    = (const float*)d_in[18];
    const float* head_w1  = (const float*)d_in[19];
    const float* head_b1  = (const float*)d_in[20];
    const float* head_w2  = (const float*)d_in[21];
    const float* head_b2  = (const float*)d_in[22];
    float* out = (float*)d_out;

    // ---- workspace layout ----
    float* ws  = (float*)d_ws;
    float* h    = ws;
    unsigned short* hb    = (unsigned short*)(h + (size_t)ROWS*DMODEL);
    unsigned short* attb  = hb    + (size_t)ROWS*DMODEL;
    unsigned short* Qg    = attb  + (size_t)ROWS*DMODEL;
    unsigned short* Kg    = Qg    + (size_t)BATCH*NHEAD*SEQ*DH;
    unsigned short* Vg    = Kg    + (size_t)BATCH*NHEAD*SEQ*DH;
    unsigned short* Wqkv  = Vg    + (size_t)BATCH*NHEAD*SEQ*DH;
    unsigned short* Wout  = Wqkv  + (size_t)NLAYER*3*DMODEL*DMODEL;
    unsigned short* Wl1   = Wout  + (size_t)NLAYER*DMODEL*DMODEL;
    unsigned short* Wl2   = Wl1   + (size_t)NLAYER*DFF*DMODEL;
    unsigned short* Wh1   = Wl2   + (size_t)NLAYER*DMODEL*DFF;

    encode_cast<<<ROWS/4 + 576, 256, 0, stream>>>(
        x, y, xenc_w, xenc_b, yenc_w, yenc_b, h, hb,
        in_proj_w, out_proj_w, lin1_w, lin2_w, head_w1,
        Wqkv, Wout, Wl1, Wl2, Wh1);

    for (int l = 0; l < NLAYER; ++l) {
        gemm_qkv<<<768, 256, 0, stream>>>(
            hb, Wqkv + (size_t)l*3*DMODEL*DMODEL, in_proj_b + l*3*DMODEL,
            Qg, Kg, Vg, DMODEL);
        attn_mfma<<<256, 256, 0, stream>>>(Qg, Kg, Vg, attb);
        mlp_fused<<<256, 256, 0, stream>>>(
            attb,
            Wout + (size_t)l*DMODEL*DMODEL, out_proj_b + l*DMODEL,
            ln1_g + l*DMODEL, ln1_b + l*DMODEL,
            Wl1 + (size_t)l*DFF*DMODEL, lin1_b + l*DFF,
            Wl2 + (size_t)l*DMODEL*DFF, lin2_b + l*DMODEL,
            ln2_g + l*DMODEL, ln2_b + l*DMODEL,
            h, hb,
            Wh1, head_b1, head_w2, head_b2,
            out, (l == NLAYER-1) ? 1 : 0);
    }
}

// Round 13
// 247.851 us; speedup vs baseline: 1.0072x; 1.0072x over previous
//
#include <hip/hip_runtime.h>
#include <hip/hip_bf16.h>
#include <math.h>

// Problem constants (fixed by setup_inputs)
#define SEQ    2048
#define BATCH  4
#define XDIM   16
#define DMODEL 256
#define NHEAD  8
#define DH     32
#define DFF    512
#define NLAYER 2
#define MPOS   1024
#define ROWS   (SEQ*BATCH)   // 8192

#define ATT_SCALE 0.17677669529663687f  // 1/sqrt(32)

typedef __attribute__((ext_vector_type(8))) short bf16x8;  // MFMA A/B frag
typedef __attribute__((ext_vector_type(4))) float f32x4;   // MFMA C/D frag

__device__ __forceinline__ float gelu_exact(float x) {
    return 0.5f * x * (1.0f + erff(x * 0.70710678118654752f));
}
__device__ __forceinline__ short f2bf(float f) {
    unsigned int u = __float_as_uint(f);
    u += 0x7FFFu + ((u >> 16) & 1u);
    return (short)(u >> 16);
}
__device__ __forceinline__ float bf2f(unsigned short u) {
    return __uint_as_float(((unsigned int)u) << 16);
}
__device__ __forceinline__ void gload16(const unsigned short* g, unsigned short* l) {
    __builtin_amdgcn_global_load_lds(
        (const __attribute__((address_space(1))) unsigned int*)g,
        (__attribute__((address_space(3))) unsigned int*)l, 16, 0, 0);
}
#define VMWAIT(N) asm volatile("s_waitcnt vmcnt(" #N ")" ::: "memory")
__device__ __forceinline__ void pipe_barrier() {
    __builtin_amdgcn_sched_barrier(0);
    __builtin_amdgcn_s_barrier();
    __builtin_amdgcn_sched_barrier(0);
}

// ---------------- encoder (4 rows/block) + weight casts, ONE launch -----------
__global__ __launch_bounds__(256) void encode_cast(
    const float* __restrict__ x, const float* __restrict__ y,
    const float* __restrict__ xw, const float* __restrict__ xb,
    const float* __restrict__ yw, const float* __restrict__ yb,
    float* __restrict__ h, unsigned short* __restrict__ hb,
    const float* __restrict__ s0, const float* __restrict__ s1,
    const float* __restrict__ s2, const float* __restrict__ s3,
    const float* __restrict__ s4,
    unsigned short* __restrict__ d0, unsigned short* __restrict__ d1,
    unsigned short* __restrict__ d2, unsigned short* __restrict__ d3,
    unsigned short* __restrict__ d4)
{
    if (blockIdx.x < ROWS/4) {
        int g = blockIdx.x;        // token index s (4 batch rows share it)
        int d = threadIdx.x;       // 0..255
        __shared__ float xs[4][XDIM];
        __shared__ float ys[4];
        if (d < 64) xs[d>>4][d&15] = x[(size_t)(g*4 + (d>>4))*XDIM + (d&15)];
        if (d < 4)  ys[d] = y[g*4 + d];
        __syncthreads();
        float wreg[XDIM];
        #pragma unroll
        for (int k = 0; k < XDIM; ++k) wreg[k] = xw[d*XDIM + k];
        const float xbv = xb[d], ywv = yw[d], ybv = yb[d];
        const bool train = (g < MPOS);
        #pragma unroll
        for (int r = 0; r < 4; ++r) {
            int row = g*4 + r;
            float acc = xbv;
            #pragma unroll
            for (int k = 0; k < XDIM; ++k) acc = fmaf(xs[r][k], wreg[k], acc);
            if (train) acc += ys[r]*ywv + ybv;
            h[(size_t)row*DMODEL + d]  = acc;
            hb[(size_t)row*DMODEL + d] = (unsigned short)f2bf(acc);
        }
        return;
    }
    int i = (blockIdx.x - ROWS/4)*256 + threadIdx.x;
    if (i >= 147456) return;
    const float* s; unsigned short* d; int off;
    if      (i <  49152) { s = s0; d = d0; off = i; }
    else if (i <  65536) { s = s1; d = d1; off = i - 49152; }
    else if (i <  98304) { s = s2; d = d2; off = i - 65536; }
    else if (i < 131072) { s = s3; d = d3; off = i - 98304; }
    else                 { s = s4; d = d4; off = i - 131072; }
    float4 a = *(const float4*)(s + (size_t)off*8);
    float4 c = *(const float4*)(s + (size_t)off*8 + 4);
    ushort4 u0, u1;
    u0.x=(unsigned short)f2bf(a.x); u0.y=(unsigned short)f2bf(a.y);
    u0.z=(unsigned short)f2bf(a.z); u0.w=(unsigned short)f2bf(a.w);
    u1.x=(unsigned short)f2bf(c.x); u1.y=(unsigned short)f2bf(c.y);
    u1.z=(unsigned short)f2bf(c.z); u1.w=(unsigned short)f2bf(c.w);
    *(ushort4*)(d + (size_t)off*8)     = u0;
    *(ushort4*)(d + (size_t)off*8 + 4) = u1;
}

// ------- qkv GEMM 128x64, BK=64 (NS=4), 2-buffer, swizzled, XCD-local A ------
__global__ __launch_bounds__(256) void gemm_qkv(
    const unsigned short* __restrict__ A, const unsigned short* __restrict__ B,
    const float* __restrict__ bias,
    unsigned short* __restrict__ Qg, unsigned short* __restrict__ Kg,
    unsigned short* __restrict__ Vg, int K)
{
    __shared__ unsigned short As[2][128][64];   // 32 KB (reused as transpose buf)
    __shared__ unsigned short Bs[2][64][64];    // 16 KB
    int tid  = threadIdx.x;
    int w    = tid >> 6, lane = tid & 63;
    int col  = lane & 15, quad = lane >> 4;
    int u    = blockIdx.x >> 3, xcd = blockIdx.x & 7;
    int by   = xcd*8 + u/12, bx = u%12;
    int m0   = by * 128, n0 = bx * 64;
    int l8   = lane >> 3;
    int c8s  = (((lane & 7) ^ l8) * 8);

    f32x4 acc[2][4];
    #pragma unroll
    for (int i = 0; i < 2; ++i)
        #pragma unroll
        for (int j = 0; j < 4; ++j) acc[i][j] = (f32x4){0.f,0.f,0.f,0.f};

    const unsigned short* ga = A + (size_t)(m0 + w*32 + l8)*K + c8s;
    const unsigned short* gb = B + (size_t)(n0 + w*16 + l8)*K + c8s;
    const int NS = K / 64;  // 4

    #pragma unroll
    for (int t = 0; t < 4; ++t) gload16(ga + (size_t)(t*8)*K, &As[0][w*32 + t*8][0]);
    #pragma unroll
    for (int t = 0; t < 2; ++t) gload16(gb + (size_t)(t*8)*K, &Bs[0][w*16 + t*8][0]);

    for (int s = 0; s < NS; ++s) {
        VMWAIT(0);
        pipe_barrier();
        if (s + 1 < NS) {
            int k2 = (s + 1) * 64;
            int nb = (s + 1) & 1;
            #pragma unroll
            for (int t = 0; t < 4; ++t) gload16(ga + k2 + (size_t)(t*8)*K, &As[nb][w*32 + t*8][0]);
            #pragma unroll
            for (int t = 0; t < 2; ++t) gload16(gb + k2 + (size_t)(t*8)*K, &Bs[nb][w*16 + t*8][0]);
        }
        int cur = s & 1;
        #pragma unroll
        for (int kk = 0; kk < 2; ++kk) {
            const int so = (((kk*4 + quad) ^ (col & 7)) * 8);
            bf16x8 af[2], bfr[4];
            #pragma unroll
            for (int i = 0; i < 2; ++i) af[i]  = *(const bf16x8*)&As[cur][w*32 + i*16 + col][so];
            #pragma unroll
            for (int j = 0; j < 4; ++j) bfr[j] = *(const bf16x8*)&Bs[cur][j*16 + col][so];
            #pragma unroll
            for (int i = 0; i < 2; ++i)
                #pragma unroll
                for (int j = 0; j < 4; ++j)
                    acc[i][j] = __builtin_amdgcn_mfma_f32_16x16x32_bf16(bfr[j], af[i], acc[i][j], 0, 0, 0);
        }
    }

    int region = n0 >> 8;   // 0=Q, 1=K, 2=V (uniform per block)
    if (region < 2) {
        #pragma unroll
        for (int i = 0; i < 2; ++i) {
            int m = m0 + w*32 + i*16 + col;
            int s = m >> 2, bidx = m & 3;
            #pragma unroll
            for (int j = 0; j < 4; ++j) {
                int ng = n0 + j*16 + quad*4;
                float4 bi = *(const float4*)&bias[ng];
                ushort4 uu;
                uu.x=(unsigned short)f2bf(acc[i][j][0] + bi.x);
                uu.y=(unsigned short)f2bf(acc[i][j][1] + bi.y);
                uu.z=(unsigned short)f2bf(acc[i][j][2] + bi.z);
                uu.w=(unsigned short)f2bf(acc[i][j][3] + bi.w);
                int np = ng - (region << 8);
                int hh = np >> 5, d = np & 31;
                int bh = bidx*NHEAD + hh;
                if (region == 0)
                    *(ushort4*)(Qg + ((size_t)(bh*SEQ + s))*DH + d) = uu;
                else
                    *(ushort4*)(Kg + ((size_t)(bh*SEQ + s))*DH + d) = uu;
            }
        }
    } else {
        __syncthreads();
        unsigned short* T3 = (unsigned short*)As;   // 16 KB scratch
        #pragma unroll
        for (int i = 0; i < 2; ++i) {
            int mi = w*32 + i*16 + col;
            int ss = mi >> 2, bidx = mi & 3;
            #pragma unroll
            for (int j = 0; j < 4; ++j) {
                int ni = j*16 + quad*4;
                float4 bi = *(const float4*)&bias[n0 + ni];
                T3[((ni    )*4 + bidx)*32 + ss] = (unsigned short)f2bf(acc[i][j][0] + bi.x);
                T3[((ni + 1)*4 + bidx)*32 + ss] = (unsigned short)f2bf(acc[i][j][1] + bi.y);
                T3[((ni + 2)*4 + bidx)*32 + ss] = (unsigned short)f2bf(acc[i][j][2] + bi.z);
                T3[((ni + 3)*4 + bidx)*32 + ss] = (unsigned short)f2bf(acc[i][j][3] + bi.w);
            }
        }
        __syncthreads();
        int sBase = m0 >> 2;
        #pragma unroll
        for (int r = 0; r < 4; ++r) {
            int chunk = tid + 256*r;
            int l = chunk >> 2, p = chunk & 3;
            int d = l & 31, hh_l = (l >> 5) & 1, bidx = l >> 6;
            int ni = hh_l*32 + d;
            int hh = ((n0 & 255) + ni) >> 5;
            int bh = bidx*NHEAD + hh;
            uint4 val = *(const uint4*)&T3[(ni*4 + bidx)*32 + p*8];
            *(uint4*)(Vg + ((size_t)(bh*DH + d))*SEQ + sBase + p*8) = val;
        }
    }
}

// ---------------- MFMA flash attention, QUAD q-tile, KVBLK=128 ---------------
// Block owns 4 q-tiles: A0=q0, A1=q0+64 (low, <MPOS), B0=MPOS+q0, B1=MPOS+q0+64.
// K/V staging + barriers shared by all four. 8 main 128-key tiles + one 128-key
// diag tile (B0 masks first-64 diag, B1 second-64 diag; exact +0 elsewhere).
__global__ __launch_bounds__(256) void attn_mfma(
    const unsigned short* __restrict__ Qg,
    const unsigned short* __restrict__ Kg,
    const unsigned short* __restrict__ Vg,
    unsigned short* __restrict__ o)           // bf16 [s*B+b][256]
{
    const int id  = blockIdx.x;               // 0..255
    const int sl  = id >> 3;                  // 0..31
    const int bh  = (id & 7) * 4 + (sl >> 3); // XCD (id&7) owns bh [4x,4x+4)
    const int qt4 = sl & 7;
    const int h   = bh & 7;
    const int b   = bh >> 3;
    const int q0  = qt4 * 128;
    const int tid  = threadIdx.x;
    const int w    = tid >> 6;
    const int lane = tid & 63;
    const int col  = lane & 15;
    const int quad = lane >> 4;

    __shared__ unsigned short Kt[2][128][40];    // 20 KB
    __shared__ unsigned short Vt[2][32][136];    // 17 KB
    __shared__ unsigned short PtA0[4][16][136];  // 17 KB each
    __shared__ unsigned short PtA1[4][16][136];
    __shared__ unsigned short PtB0[4][16][136];
    __shared__ unsigned short PtB1[4][16][136];

    const int qA0 = q0 + 16*w + col;
    const int qA1 = q0 + 64 + 16*w + col;
    const int qB0 = MPOS + q0 + 16*w + col;
    const int qB1 = MPOS + q0 + 64 + 16*w + col;
    bf16x8 qfA0 = *(const bf16x8*)(Qg + ((size_t)(bh*SEQ + qA0))*DH + quad*8);
    bf16x8 qfA1 = *(const bf16x8*)(Qg + ((size_t)(bh*SEQ + qA1))*DH + quad*8);
    bf16x8 qfB0 = *(const bf16x8*)(Qg + ((size_t)(bh*SEQ + qB0))*DH + quad*8);
    bf16x8 qfB1 = *(const bf16x8*)(Qg + ((size_t)(bh*SEQ + qB1))*DH + quad*8);

    f32x4 O0A0 = {0.f,0.f,0.f,0.f}, O1A0 = {0.f,0.f,0.f,0.f};
    f32x4 O0A1 = {0.f,0.f,0.f,0.f}, O1A1 = {0.f,0.f,0.f,0.f};
    f32x4 O0B0 = {0.f,0.f,0.f,0.f}, O1B0 = {0.f,0.f,0.f,0.f};
    f32x4 O0B1 = {0.f,0.f,0.f,0.f}, O1B1 = {0.f,0.f,0.f,0.f};
    float lsumA0 = 0.f, lsumA1 = 0.f, lsumB0 = 0.f, lsumB1 = 0.f;

    const int kRow = tid >> 2, kCh = (tid & 3) * 8;
    const int vD   = tid >> 3, vCh = (tid & 7) * 8;

    uint4 kreg0 = *(const uint4*)(Kg + ((size_t)(bh*SEQ + kRow     ))*DH + kCh);
    uint4 kreg1 = *(const uint4*)(Kg + ((size_t)(bh*SEQ + kRow + 64))*DH + kCh);
    uint4 vreg0 = *(const uint4*)(Vg + ((size_t)(bh*DH + vD))*SEQ + vCh);
    uint4 vreg1 = *(const uint4*)(Vg + ((size_t)(bh*DH + vD))*SEQ + vCh + 64);

    for (int kt = 0; kt < 8; ++kt) {
        const int p = kt & 1;
        *(uint4*)&Kt[p][kRow     ][kCh] = kreg0;
        *(uint4*)&Kt[p][kRow + 64][kCh] = kreg1;
        *(uint4*)&Vt[p][vD][vCh     ]   = vreg0;
        *(uint4*)&Vt[p][vD][vCh + 64]   = vreg1;
        __syncthreads();
        {
            int kn = (kt < 7) ? (kt + 1) * 128 : (MPOS + q0);
            kreg0 = *(const uint4*)(Kg + ((size_t)(bh*SEQ + kn + kRow     ))*DH + kCh);
            kreg1 = *(const uint4*)(Kg + ((size_t)(bh*SEQ + kn + kRow + 64))*DH + kCh);
            vreg0 = *(const uint4*)(Vg + ((size_t)(bh*DH + vD))*SEQ + kn + vCh);
            vreg1 = *(const uint4*)(Vg + ((size_t)(bh*DH + vD))*SEQ + kn + vCh + 64);
        }

        #pragma unroll
        for (int mt = 0; mt < 8; ++mt) {
            bf16x8 kf = *(const bf16x8*)&Kt[p][mt*16 + col][quad*8];
            f32x4 st; ushort4 pw;

            st = (f32x4){0.f,0.f,0.f,0.f};
            st = __builtin_amdgcn_mfma_f32_16x16x32_bf16(kf, qfA0, st, 0, 0, 0);
            #pragma unroll
            for (int i = 0; i < 4; ++i) {
                unsigned short us = (unsigned short)f2bf(__expf(st[i]*ATT_SCALE));
                ((unsigned short*)&pw)[i] = us; lsumA0 += bf2f(us);
            }
            *(ushort4*)&PtA0[w][col][mt*16 + quad*4] = pw;

            st = (f32x4){0.f,0.f,0.f,0.f};
            st = __builtin_amdgcn_mfma_f32_16x16x32_bf16(kf, qfA1, st, 0, 0, 0);
            #pragma unroll
            for (int i = 0; i < 4; ++i) {
                unsigned short us = (unsigned short)f2bf(__expf(st[i]*ATT_SCALE));
                ((unsigned short*)&pw)[i] = us; lsumA1 += bf2f(us);
            }
            *(ushort4*)&PtA1[w][col][mt*16 + quad*4] = pw;

            st = (f32x4){0.f,0.f,0.f,0.f};
            st = __builtin_amdgcn_mfma_f32_16x16x32_bf16(kf, qfB0, st, 0, 0, 0);
            #pragma unroll
            for (int i = 0; i < 4; ++i) {
                unsigned short us = (unsigned short)f2bf(__expf(st[i]*ATT_SCALE));
                ((unsigned short*)&pw)[i] = us; lsumB0 += bf2f(us);
            }
            *(ushort4*)&PtB0[w][col][mt*16 + quad*4] = pw;

            st = (f32x4){0.f,0.f,0.f,0.f};
            st = __builtin_amdgcn_mfma_f32_16x16x32_bf16(kf, qfB1, st, 0, 0, 0);
            #pragma unroll
            for (int i = 0; i < 4; ++i) {
                unsigned short us = (unsigned short)f2bf(__expf(st[i]*ATT_SCALE));
                ((unsigned short*)&pw)[i] = us; lsumB1 += bf2f(us);
            }
            *(ushort4*)&PtB1[w][col][mt*16 + quad*4] = pw;
        }
        #pragma unroll
        for (int c = 0; c < 4; ++c) {
            bf16x8 v0 = *(const bf16x8*)&Vt[p][col     ][c*32 + quad*8];
            bf16x8 v1 = *(const bf16x8*)&Vt[p][col + 16][c*32 + quad*8];
            bf16x8 pf;
            pf = *(const bf16x8*)&PtA0[w][col][c*32 + quad*8];
            O0A0 = __builtin_amdgcn_mfma_f32_16x16x32_bf16(v0, pf, O0A0, 0, 0, 0);
            O1A0 = __builtin_amdgcn_mfma_f32_16x16x32_bf16(v1, pf, O1A0, 0, 0, 0);
            pf = *(const bf16x8*)&PtA1[w][col][c*32 + quad*8];
            O0A1 = __builtin_amdgcn_mfma_f32_16x16x32_bf16(v0, pf, O0A1, 0, 0, 0);
            O1A1 = __builtin_amdgcn_mfma_f32_16x16x32_bf16(v1, pf, O1A1, 0, 0, 0);
            pf = *(const bf16x8*)&PtB0[w][col][c*32 + quad*8];
            O0B0 = __builtin_amdgcn_mfma_f32_16x16x32_bf16(v0, pf, O0B0, 0, 0, 0);
            O1B0 = __builtin_amdgcn_mfma_f32_16x16x32_bf16(v1, pf, O1B0, 0, 0, 0);
            pf = *(const bf16x8*)&PtB1[w][col][c*32 + quad*8];
            O0B1 = __builtin_amdgcn_mfma_f32_16x16x32_bf16(v0, pf, O0B1, 0, 0, 0);
            O1B1 = __builtin_amdgcn_mfma_f32_16x16x32_bf16(v1, pf, O1B1, 0, 0, 0);
        }
    }

    // ---- diag tile (keys [MPOS+q0, MPOS+q0+128)), buffer 0 ----
    *(uint4*)&Kt[0][kRow     ][kCh] = kreg0;
    *(uint4*)&Kt[0][kRow + 64][kCh] = kreg1;
    *(uint4*)&Vt[0][vD][vCh     ]   = vreg0;
    *(uint4*)&Vt[0][vD][vCh + 64]   = vreg1;
    __syncthreads();
    #pragma unroll
    for (int mt = 0; mt < 4; ++mt) {   // B0: keys 0..63 of tile
        bf16x8 kf = *(const bf16x8*)&Kt[0][mt*16 + col][quad*8];
        f32x4 st = {0.f,0.f,0.f,0.f};
        st = __builtin_amdgcn_mfma_f32_16x16x32_bf16(kf, qfB0, st, 0, 0, 0);
        ushort4 pw;
        #pragma unroll
        for (int i = 0; i < 4; ++i) {
            float pv = __expf(st[i]*ATT_SCALE);
            if (mt*16 + quad*4 + i != 16*w + col) pv = 0.f;
            unsigned short us = (unsigned short)f2bf(pv);
            ((unsigned short*)&pw)[i] = us; lsumB0 += bf2f(us);
        }
        *(ushort4*)&PtB0[w][col][mt*16 + quad*4] = pw;
    }
    #pragma unroll
    for (int mt = 4; mt < 8; ++mt) {   // B1: keys 64..127 of tile
        bf16x8 kf = *(const bf16x8*)&Kt[0][mt*16 + col][quad*8];
        f32x4 st = {0.f,0.f,0.f,0.f};
        st = __builtin_amdgcn_mfma_f32_16x16x32_bf16(kf, qfB1, st, 0, 0, 0);
        ushort4 pw;
        #pragma unroll
        for (int i = 0; i < 4; ++i) {
            float pv = __expf(st[i]*ATT_SCALE);
            if (mt*16 + quad*4 + i - 64 != 16*w + col) pv = 0.f;
            unsigned short us = (unsigned short)f2bf(pv);
            ((unsigned short*)&pw)[i] = us; lsumB1 += bf2f(us);
        }
        *(ushort4*)&PtB1[w][col][(mt-4)*16 + quad*4] = pw;
    }
    #pragma unroll
    for (int c = 0; c < 2; ++c) {      // B0 PV over keys 0..63
        bf16x8 v0 = *(const bf16x8*)&Vt[0][col     ][c*32 + quad*8];
        bf16x8 v1 = *(const bf16x8*)&Vt[0][col + 16][c*32 + quad*8];
        bf16x8 pf = *(const bf16x8*)&PtB0[w][col][c*32 + quad*8];
        O0B0 = __builtin_amdgcn_mfma_f32_16x16x32_bf16(v0, pf, O0B0, 0, 0, 0);
        O1B0 = __builtin_amdgcn_mfma_f32_16x16x32_bf16(v1, pf, O1B0, 0, 0, 0);
    }
    #pragma unroll
    for (int c = 0; c < 2; ++c) {      // B1 PV over keys 64..127
        bf16x8 v0 = *(const bf16x8*)&Vt[0][col     ][(c+2)*32 + quad*8];
        bf16x8 v1 = *(const bf16x8*)&Vt[0][col + 16][(c+2)*32 + quad*8];
        bf16x8 pf = *(const bf16x8*)&PtB1[w][col][c*32 + quad*8];
        O0B1 = __builtin_amdgcn_mfma_f32_16x16x32_bf16(v0, pf, O0B1, 0, 0, 0);
        O1B1 = __builtin_amdgcn_mfma_f32_16x16x32_bf16(v1, pf, O1B1, 0, 0, 0);
    }

    lsumA0 += __shfl_xor(lsumA0, 16, 64); lsumA0 += __shfl_xor(lsumA0, 32, 64);
    lsumA1 += __shfl_xor(lsumA1, 16, 64); lsumA1 += __shfl_xor(lsumA1, 32, 64);
    lsumB0 += __shfl_xor(lsumB0, 16, 64); lsumB0 += __shfl_xor(lsumB0, 32, 64);
    lsumB1 += __shfl_xor(lsumB1, 16, 64); lsumB1 += __shfl_xor(lsumB1, 32, 64);
    float invA0 = 1.0f / lsumA0, invA1 = 1.0f / lsumA1;
    float invB0 = 1.0f / lsumB0, invB1 = 1.0f / lsumB1;
    ushort4 u0, u1;
    #pragma unroll
    for (int i = 0; i < 4; ++i) {
        ((unsigned short*)&u0)[i] = (unsigned short)f2bf(O0A0[i]*invA0);
        ((unsigned short*)&u1)[i] = (unsigned short)f2bf(O1A0[i]*invA0);
    }
    unsigned short* op = o + ((size_t)(qA0*BATCH + b))*DMODEL + h*DH;
    *(ushort4*)(op + quad*4) = u0; *(ushort4*)(op + 16 + quad*4) = u1;
    #pragma unroll
    for (int i = 0; i < 4; ++i) {
        ((unsigned short*)&u0)[i] = (unsigned short)f2bf(O0A1[i]*invA1);
        ((unsigned short*)&u1)[i] = (unsigned short)f2bf(O1A1[i]*invA1);
    }
    op = o + ((size_t)(qA1*BATCH + b))*DMODEL + h*DH;
    *(ushort4*)(op + quad*4) = u0; *(ushort4*)(op + 16 + quad*4) = u1;
    #pragma unroll
    for (int i = 0; i < 4; ++i) {
        ((unsigned short*)&u0)[i] = (unsigned short)f2bf(O0B0[i]*invB0);
        ((unsigned short*)&u1)[i] = (unsigned short)f2bf(O1B0[i]*invB0);
    }
    op = o + ((size_t)(qB0*BATCH + b))*DMODEL + h*DH;
    *(ushort4*)(op + quad*4) = u0; *(ushort4*)(op + 16 + quad*4) = u1;
    #pragma unroll
    for (int i = 0; i < 4; ++i) {
        ((unsigned short*)&u0)[i] = (unsigned short)f2bf(O0B1[i]*invB1);
        ((unsigned short*)&u1)[i] = (unsigned short)f2bf(O1B1[i]*invB1);
    }
    op = o + ((size_t)(qB1*BATCH + b))*DMODEL + h*DH;
    *(ushort4*)(op + quad*4) = u0; *(ushort4*)(op + 16 + quad*4) = u1;
}

// ------- fused MLP, TWO 16-row groups per block, BK=64 K-steps (R11 form) -----
__global__ __launch_bounds__(256) void mlp_fused(
    const unsigned short* __restrict__ attb,
    const unsigned short* __restrict__ Wout, const float* __restrict__ ob,
    const float* __restrict__ g1, const float* __restrict__ be1,
    const unsigned short* __restrict__ W1, const float* __restrict__ fb1,
    const unsigned short* __restrict__ W2, const float* __restrict__ fb2,
    const float* __restrict__ g2, const float* __restrict__ be2,
    float* __restrict__ h, unsigned short* __restrict__ hb,
    const unsigned short* __restrict__ Wh1, const float* __restrict__ hb1,
    const float* __restrict__ hw2, const float* __restrict__ hb2,
    float* __restrict__ out, int doHead)
{
    __shared__ unsigned short Bs[3][256][64];         // 96 KB weight staging
    __shared__ __align__(16) unsigned char smem_u[33280];  // As (12 KB) / Pt (32.5 KB)
    __shared__ unsigned short Ht[2][16][264];         // LN1-out / LN2-out bf16
    __shared__ float sP[2][4][16], qP[2][4][16];

    typedef unsigned short AsT[2][16][64];
    AsT* As = reinterpret_cast<AsT*>(smem_u);
    typedef unsigned short PtT[16][520];
    PtT* Pt = reinterpret_cast<PtT*>(smem_u);

    const int tid  = threadIdx.x;
    const int w    = tid >> 6;
    const int lane = tid & 63;
    const int col  = lane & 15;
    const int quad = lane >> 4;
    const int l8   = lane >> 3;
    const int c8s  = (((lane & 7) ^ l8) * 8);
    const int bid  = blockIdx.x;
    const int m0a  = bid * 16;
    const int m0b  = 4096 + bid * 16;
    const int ma   = m0a + col;
    const int mb   = m0b + col;

    float resid[2][4][4];

    // ================= stage A: out-proj (K=256, NS=4) + residual + LN1 =======
    {
        f32x4 acc[2][4];
        #pragma unroll
        for (int g = 0; g < 2; ++g)
            #pragma unroll
            for (int j = 0; j < 4; ++j) acc[g][j] = (f32x4){0.f,0.f,0.f,0.f};

        const int gr = w >> 1;
        const unsigned short* gaw = attb + (size_t)((gr ? m0b : m0a) + (w&1)*8 + l8)*DMODEL + c8s;
        const unsigned short* gb  = Wout + (size_t)(w*64 + l8)*DMODEL + c8s;
        const int NS = DMODEL / 64;  // 4

        #pragma unroll
        for (int pb = 0; pb < 2; ++pb) {
            int k = pb * 64;
            gload16(gaw + k, &As[pb][gr][(w&1)*8][0]);
            #pragma unroll
            for (int t = 0; t < 8; ++t)
                gload16(gb + k + (size_t)(t*8)*DMODEL, &Bs[pb][w*64 + t*8][0]);
        }
        int bcur = 0;
        for (int s = 0; s < NS; ++s) {
            if (s == NS - 1) { VMWAIT(0); } else { VMWAIT(9); }
            pipe_barrier();
            if (s + 2 < NS) {
                int bpre = bcur + 2; if (bpre >= 3) bpre -= 3;
                int k2 = (s + 2) * 64;
                gload16(gaw + k2, &As[bpre][gr][(w&1)*8][0]);
                #pragma unroll
                for (int t = 0; t < 8; ++t)
                    gload16(gb + k2 + (size_t)(t*8)*DMODEL, &Bs[bpre][w*64 + t*8][0]);
            }
            #pragma unroll
            for (int kk = 0; kk < 2; ++kk) {
                const int so = (((kk*4 + quad) ^ (col & 7)) * 8);
                bf16x8 af0 = *(const bf16x8*)&As[bcur][0][col][so];
                bf16x8 af1 = *(const bf16x8*)&As[bcur][1][col][so];
                #pragma unroll
                for (int j = 0; j < 4; ++j) {
                    bf16x8 bfr = *(const bf16x8*)&Bs[bcur][w*64 + j*16 + col][so];
                    acc[0][j] = __builtin_amdgcn_mfma_f32_16x16x32_bf16(bfr, af0, acc[0][j], 0, 0, 0);
                    acc[1][j] = __builtin_amdgcn_mfma_f32_16x16x32_bf16(bfr, af1, acc[1][j], 0, 0, 0);
                }
            }
            bcur = (bcur == 2) ? 0 : bcur + 1;
        }

        float ssum[2] = {0.f, 0.f}, qsum[2] = {0.f, 0.f};
        #pragma unroll
        for (int g = 0; g < 2; ++g) {
            int m = g ? mb : ma;
            #pragma unroll
            for (int j = 0; j < 4; ++j) {
                int n = w*64 + j*16 + quad*4;
                float4 bi = *(const float4*)&ob[n];
                float4 hv = *(const float4*)&h[(size_t)m*DMODEL + n];
                #pragma unroll
                for (int i = 0; i < 4; ++i) {
                    float val = acc[g][j][i] + ((const float*)&bi)[i] + ((const float*)&hv)[i];
                    resid[g][j][i] = val;
                    ssum[g] += val; qsum[g] += val*val;
                }
            }
        }
        #pragma unroll
        for (int g = 0; g < 2; ++g) {
            ssum[g] += __shfl_xor(ssum[g], 16, 64); ssum[g] += __shfl_xor(ssum[g], 32, 64);
            qsum[g] += __shfl_xor(qsum[g], 16, 64); qsum[g] += __shfl_xor(qsum[g], 32, 64);
        }
        if (quad == 0) {
            sP[0][w][col] = ssum[0]; qP[0][w][col] = qsum[0];
            sP[1][w][col] = ssum[1]; qP[1][w][col] = qsum[1];
        }
        __syncthreads();
        #pragma unroll
        for (int g = 0; g < 2; ++g) {
            float st = sP[g][0][col] + sP[g][1][col] + sP[g][2][col] + sP[g][3][col];
            float qt = qP[g][0][col] + qP[g][1][col] + qP[g][2][col] + qP[g][3][col];
            float mu   = st * (1.0f/DMODEL);
            float var  = qt * (1.0f/DMODEL) - mu*mu;
            float rstd = rsqrtf(var + 1e-5f);
            #pragma unroll
            for (int j = 0; j < 4; ++j) {
                int n = w*64 + j*16 + quad*4;
                float4 gv = *(const float4*)&g1[n];
                float4 bv = *(const float4*)&be1[n];
                ushort4 u;
                #pragma unroll
                for (int i = 0; i < 4; ++i) {
                    float o = (resid[g][j][i]-mu)*rstd*((const float*)&gv)[i] + ((const float*)&bv)[i];
                    resid[g][j][i] = o;
                    ((unsigned short*)&u)[i] = (unsigned short)f2bf(o);
                }
                *(ushort4*)&Ht[g][col][n] = u;
            }
        }
        __syncthreads();   // Ht visible; all waves past As/Bs reads
    }

    // ================= stage B: ff1 (K=256 NS=4, two N-halves) + gelu =========
    #pragma unroll 1
    for (int nh = 0; nh < 2; ++nh) {
        f32x4 acc[2][4];
        #pragma unroll
        for (int g = 0; g < 2; ++g)
            #pragma unroll
            for (int j = 0; j < 4; ++j) acc[g][j] = (f32x4){0.f,0.f,0.f,0.f};
        const unsigned short* gb = W1 + (size_t)(nh*256 + w*64 + l8)*DMODEL + c8s;
        const int NS = DMODEL / 64;  // 4

        #pragma unroll
        for (int pb = 0; pb < 2; ++pb)
            #pragma unroll
            for (int t = 0; t < 8; ++t)
                gload16(gb + pb*64 + (size_t)(t*8)*DMODEL, &Bs[pb][w*64 + t*8][0]);

        int bcur = 0;
        for (int s = 0; s < NS; ++s) {
            if (s == NS - 1) { VMWAIT(0); } else { VMWAIT(8); }
            pipe_barrier();
            if (s + 2 < NS) {
                int bpre = bcur + 2; if (bpre >= 3) bpre -= 3;
                int k2 = (s + 2) * 64;
                #pragma unroll
                for (int t = 0; t < 8; ++t)
                    gload16(gb + k2 + (size_t)(t*8)*DMODEL, &Bs[bpre][w*64 + t*8][0]);
            }
            #pragma unroll
            for (int kk = 0; kk < 2; ++kk) {
                const int so = (((kk*4 + quad) ^ (col & 7)) * 8);
                bf16x8 af0 = *(const bf16x8*)&Ht[0][col][s*64 + kk*32 + quad*8];
                bf16x8 af1 = *(const bf16x8*)&Ht[1][col][s*64 + kk*32 + quad*8];
                #pragma unroll
                for (int j = 0; j < 4; ++j) {
                    bf16x8 bfr = *(const bf16x8*)&Bs[bcur][w*64 + j*16 + col][so];
                    acc[0][j] = __builtin_amdgcn_mfma_f32_16x16x32_bf16(bfr, af0, acc[0][j], 0, 0, 0);
                    acc[1][j] = __builtin_amdgcn_mfma_f32_16x16x32_bf16(bfr, af1, acc[1][j], 0, 0, 0);
                }
            }
            bcur = (bcur == 2) ? 0 : bcur + 1;
        }
        #pragma unroll
        for (int g = 0; g < 2; ++g)
            #pragma unroll
            for (int j = 0; j < 4; ++j) {
                int n2 = nh*256 + w*64 + j*16 + quad*4;
                float4 bi = *(const float4*)&fb1[n2];
                ushort4 u;
                #pragma unroll
                for (int i = 0; i < 4; ++i)
                    ((unsigned short*)&u)[i] = (unsigned short)f2bf(gelu_exact(acc[g][j][i] + ((const float*)&bi)[i]));
                *(ushort4*)&Pt[g][col][n2] = u;
            }
        pipe_barrier();   // all waves past Bs reads before next half's staging
    }

    // ================= stage C: ff2 (K=512 NS=8) + residual + LN2 =============
    {
        __syncthreads();  // Pt visible
        f32x4 acc[2][4];
        #pragma unroll
        for (int g = 0; g < 2; ++g)
            #pragma unroll
            for (int j = 0; j < 4; ++j) acc[g][j] = (f32x4){0.f,0.f,0.f,0.f};
        const unsigned short* gb = W2 + (size_t)(w*64 + l8)*DFF + c8s;
        const int NS = DFF / 64;  // 8

        #pragma unroll
        for (int pb = 0; pb < 2; ++pb)
            #pragma unroll
            for (int t = 0; t < 8; ++t)
                gload16(gb + pb*64 + (size_t)(t*8)*DFF, &Bs[pb][w*64 + t*8][0]);

        int bcur = 0;
        for (int s = 0; s < NS; ++s) {
            if (s == NS - 1) { VMWAIT(0); } else { VMWAIT(8); }
            pipe_barrier();
            if (s + 2 < NS) {
                int bpre = bcur + 2; if (bpre >= 3) bpre -= 3;
                int k2 = (s + 2) * 64;
                #pragma unroll
                for (int t = 0; t < 8; ++t)
                    gload16(gb + k2 + (size_t)(t*8)*DFF, &Bs[bpre][w*64 + t*8][0]);
            }
            #pragma unroll
            for (int kk = 0; kk < 2; ++kk) {
                const int so = (((kk*4 + quad) ^ (col & 7)) * 8);
                bf16x8 af0 = *(const bf16x8*)&Pt[0][col][s*64 + kk*32 + quad*8];
                bf16x8 af1 = *(const bf16x8*)&Pt[1][col][s*64 + kk*32 + quad*8];
                #pragma unroll
                for (int j = 0; j < 4; ++j) {
                    bf16x8 bfr = *(const bf16x8*)&Bs[bcur][w*64 + j*16 + col][so];
                    acc[0][j] = __builtin_amdgcn_mfma_f32_16x16x32_bf16(bfr, af0, acc[0][j], 0, 0, 0);
                    acc[1][j] = __builtin_amdgcn_mfma_f32_16x16x32_bf16(bfr, af1, acc[1][j], 0, 0, 0);
                }
            }
            bcur = (bcur == 2) ? 0 : bcur + 1;
        }

        float ssum[2] = {0.f, 0.f}, qsum[2] = {0.f, 0.f};
        #pragma unroll
        for (int g = 0; g < 2; ++g)
            #pragma unroll
            for (int j = 0; j < 4; ++j) {
                int n = w*64 + j*16 + quad*4;
                float4 bi = *(const float4*)&fb2[n];
                #pragma unroll
                for (int i = 0; i < 4; ++i) {
                    float val = acc[g][j][i] + ((const float*)&bi)[i] + resid[g][j][i];
                    resid[g][j][i] = val;
                    ssum[g] += val; qsum[g] += val*val;
                }
            }
        #pragma unroll
        for (int g = 0; g < 2; ++g) {
            ssum[g] += __shfl_xor(ssum[g], 16, 64); ssum[g] += __shfl_xor(ssum[g], 32, 64);
            qsum[g] += __shfl_xor(qsum[g], 16, 64); qsum[g] += __shfl_xor(qsum[g], 32, 64);
        }
        if (quad == 0) {
            sP[0][w][col] = ssum[0]; qP[0][w][col] = qsum[0];
            sP[1][w][col] = ssum[1]; qP[1][w][col] = qsum[1];
        }
        __syncthreads();
        #pragma unroll
        for (int g = 0; g < 2; ++g) {
            int m = g ? mb : ma;
            float st = sP[g][0][col] + sP[g][1][col] + sP[g][2][col] + sP[g][3][col];
            float qt = qP[g][0][col] + qP[g][1][col] + qP[g][2][col] + qP[g][3][col];
            float mu   = st * (1.0f/DMODEL);
            float var  = qt * (1.0f/DMODEL) - mu*mu;
            float rstd = rsqrtf(var + 1e-5f);
            #pragma unroll
            for (int j = 0; j < 4; ++j) {
                int n = w*64 + j*16 + quad*4;
                float4 gv = *(const float4*)&g2[n];
                float4 bv = *(const float4*)&be2[n];
                float4 o;
                ushort4 u;
                #pragma unroll
                for (int i = 0; i < 4; ++i) {
                    float ov = (resid[g][j][i]-mu)*rstd*((const float*)&gv)[i] + ((const float*)&bv)[i];
                    ((float*)&o)[i] = ov;
                    ((unsigned short*)&u)[i] = (unsigned short)f2bf(ov);
                }
                *(float4*)&h[(size_t)m*DMODEL + n] = o;
                *(ushort4*)(hb + (size_t)m*DMODEL + n) = u;
                *(ushort4*)&Ht[g][col][n] = u;   // LN2 bf16 for head
            }
        }
        __syncthreads();
    }

    // ================= stage D: head (layer 1; 16 head rows per block) ========
    if (doHead) {
        float sdot = 0.f;
        #pragma unroll 1
        for (int nh = 0; nh < 2; ++nh) {
            f32x4 acc[4];
            #pragma unroll
            for (int j = 0; j < 4; ++j) acc[j] = (f32x4){0.f,0.f,0.f,0.f};
            const unsigned short* gb = Wh1 + (size_t)(nh*256 + w*64 + l8)*DMODEL + c8s;
            const int NS = DMODEL / 64;  // 4

            #pragma unroll
            for (int pb = 0; pb < 2; ++pb)
                #pragma unroll
                for (int t = 0; t < 8; ++t)
                    gload16(gb + pb*64 + (size_t)(t*8)*DMODEL, &Bs[pb][w*64 + t*8][0]);

            int bcur = 0;
            for (int s = 0; s < NS; ++s) {
                if (s == NS - 1) { VMWAIT(0); } else { VMWAIT(8); }
                pipe_barrier();
                if (s + 2 < NS) {
                    int bpre = bcur + 2; if (bpre >= 3) bpre -= 3;
                    int k2 = (s + 2) * 64;
                    #pragma unroll
                    for (int t = 0; t < 8; ++t)
                        gload16(gb + k2 + (size_t)(t*8)*DMODEL, &Bs[bpre][w*64 + t*8][0]);
                }
                #pragma unroll
                for (int kk = 0; kk < 2; ++kk) {
                    const int so = (((kk*4 + quad) ^ (col & 7)) * 8);
                    bf16x8 af = *(const bf16x8*)&Ht[1][col][s*64 + kk*32 + quad*8];
                    #pragma unroll
                    for (int j = 0; j < 4; ++j) {
                        bf16x8 bfr = *(const bf16x8*)&Bs[bcur][w*64 + j*16 + col][so];
                        acc[j] = __builtin_amdgcn_mfma_f32_16x16x32_bf16(bfr, af, acc[j], 0, 0, 0);
                    }
                }
                bcur = (bcur == 2) ? 0 : bcur + 1;
            }
            #pragma unroll
            for (int j = 0; j < 4; ++j) {
                int n2 = nh*256 + w*64 + j*16 + quad*4;
                float4 b1v = *(const float4*)&hb1[n2];
                float4 w2v = *(const float4*)&hw2[n2];
                #pragma unroll
                for (int i = 0; i < 4; ++i)
                    sdot += gelu_exact(acc[j][i] + ((const float*)&b1v)[i]) * ((const float*)&w2v)[i];
            }
            pipe_barrier();
        }
        sdot += __shfl_xor(sdot, 16, 64); sdot += __shfl_xor(sdot, 32, 64);
        if (quad == 0) sP[0][w][col] = sdot;
        __syncthreads();
        if (tid < 16)
            out[bid*16 + tid] = sP[0][0][tid] + sP[0][1][tid] + sP[0][2][tid] + sP[0][3][tid] + hb2[0];
    }
}

extern "C" void kernel_launch(void* const* d_in, const int* in_sizes, int n_in,
                              void* d_out, int out_size, void* d_ws, size_t ws_size,
                              hipStream_t stream)
{
    const float* x        = (const float*)d_in[0];
    const float* y        = (const float*)d_in[1];
    const float* xenc_w   = (const float*)d_in[3];
    const float* xenc_b   = (const float*)d_in[4];
    const float* yenc_w   = (const float*)d_in[5];
    const float* yenc_b   = (const float*)d_in[6];
    const float* in_proj_w  = (const float*)d_in[7];
    const float* in_proj_b  = (const float*)d_in[8];
    const float* out_proj_w = (const float*)d_in[9];
    const float* out_proj_b = (const float*)d_in[10];
    const float* ln1_g    = (const float*)d_in[11];
    const float* ln1_b    = (const float*)d_in[12];
    const float* lin1_w   = (const float*)d_in[13];
    const float* lin1_b   = (const float*)d_in[14];
    const float* lin2_w   = (const float*)d_in[15];
    const float* lin2_b   = (const float*)d_in[16];
    const float* ln2_g    = (const float*)d_in[17];
    const float* ln2_b    = (const float*)d_in[18];
    const float* head_w1  = (const float*)d_in[19];
    const float* head_b1  = (const float*)d_in[20];
    const float* head_w2  = (const float*)d_in[21];
    const float* head_b2  = (const float*)d_in[22];
    float* out = (float*)d_out;

    // ---- workspace layout ----
    float* ws  = (float*)d_ws;
    float* h    = ws;
    unsigned short* hb    = (unsigned short*)(h + (size_t)ROWS*DMODEL);
    unsigned short* attb  = hb    + (size_t)ROWS*DMODEL;
    unsigned short* Qg    = attb  + (size_t)ROWS*DMODEL;
    unsigned short* Kg    = Qg    + (size_t)BATCH*NHEAD*SEQ*DH;
    unsigned short* Vg    = Kg    + (size_t)BATCH*NHEAD*SEQ*DH;
    unsigned short* Wqkv  = Vg    + (size_t)BATCH*NHEAD*SEQ*DH;
    unsigned short* Wout  = Wqkv  + (size_t)NLAYER*3*DMODEL*DMODEL;
    unsigned short* Wl1   = Wout  + (size_t)NLAYER*DMODEL*DMODEL;
    unsigned short* Wl2   = Wl1   + (size_t)NLAYER*DFF*DMODEL;
    unsigned short* Wh1   = Wl2   + (size_t)NLAYER*DMODEL*DFF;

    encode_cast<<<ROWS/4 + 576, 256, 0, stream>>>(
        x, y, xenc_w, xenc_b, yenc_w, yenc_b, h, hb,
        in_proj_w, out_proj_w, lin1_w, lin2_w, head_w1,
        Wqkv, Wout, Wl1, Wl2, Wh1);

    for (int l = 0; l < NLAYER; ++l) {
        gemm_qkv<<<768, 256, 0, stream>>>(
            hb, Wqkv + (size_t)l*3*DMODEL*DMODEL, in_proj_b + l*3*DMODEL,
            Qg, Kg, Vg, DMODEL);
        attn_mfma<<<256, 256, 0, stream>>>(Qg, Kg, Vg, attb);
        mlp_fused<<<256, 256, 0, stream>>>(
            attb,
            Wout + (size_t)l*DMODEL*DMODEL, out_proj_b + l*DMODEL,
            ln1_g + l*DMODEL, ln1_b + l*DMODEL,
            Wl1 + (size_t)l*DFF*DMODEL, lin1_b + l*DFF,
            Wl2 + (size_t)l*DMODEL*DFF, lin2_b + l*DMODEL,
            ln2_g + l*DMODEL, ln2_b + l*DMODEL,
            h, hb,
            Wh1, head_b1, head_w2, head_b2,
            out, (l == NLAYER-1) ? 1 : 0);
    }
}

// Round 14
// 229.860 us; speedup vs baseline: 1.0861x; 1.0783x over previous
//
#include <hip/hip_runtime.h>
#include <hip/hip_bf16.h>
#include <math.h>

// Problem constants (fixed by setup_inputs)
#define SEQ    2048
#define BATCH  4
#define XDIM   16
#define DMODEL 256
#define NHEAD  8
#define DH     32
#define DFF    512
#define NLAYER 2
#define MPOS   1024
#define ROWS   (SEQ*BATCH)   // 8192

#define ATT_SCALE 0.17677669529663687f  // 1/sqrt(32)

typedef __attribute__((ext_vector_type(8))) short bf16x8;  // MFMA A/B frag
typedef __attribute__((ext_vector_type(4))) float f32x4;   // MFMA C/D frag

__device__ __forceinline__ float gelu_exact(float x) {
    return 0.5f * x * (1.0f + erff(x * 0.70710678118654752f));
}
__device__ __forceinline__ short f2bf(float f) {
    unsigned int u = __float_as_uint(f);
    u += 0x7FFFu + ((u >> 16) & 1u);
    return (short)(u >> 16);
}
__device__ __forceinline__ float bf2f(unsigned short u) {
    return __uint_as_float(((unsigned int)u) << 16);
}
__device__ __forceinline__ void gload16(const unsigned short* g, unsigned short* l) {
    __builtin_amdgcn_global_load_lds(
        (const __attribute__((address_space(1))) unsigned int*)g,
        (__attribute__((address_space(3))) unsigned int*)l, 16, 0, 0);
}
#define VMWAIT(N) asm volatile("s_waitcnt vmcnt(" #N ")" ::: "memory")
__device__ __forceinline__ void pipe_barrier() {
    __builtin_amdgcn_sched_barrier(0);
    __builtin_amdgcn_s_barrier();
    __builtin_amdgcn_sched_barrier(0);
}

// ---------------- encoder (4 rows/block) + weight casts, ONE launch -----------
__global__ __launch_bounds__(256) void encode_cast(
    const float* __restrict__ x, const float* __restrict__ y,
    const float* __restrict__ xw, const float* __restrict__ xb,
    const float* __restrict__ yw, const float* __restrict__ yb,
    float* __restrict__ h, unsigned short* __restrict__ hb,
    const float* __restrict__ s0, const float* __restrict__ s1,
    const float* __restrict__ s2, const float* __restrict__ s3,
    const float* __restrict__ s4,
    unsigned short* __restrict__ d0, unsigned short* __restrict__ d1,
    unsigned short* __restrict__ d2, unsigned short* __restrict__ d3,
    unsigned short* __restrict__ d4)
{
    if (blockIdx.x < ROWS/4) {
        int g = blockIdx.x;        // token index s (4 batch rows share it)
        int d = threadIdx.x;       // 0..255
        __shared__ float xs[4][XDIM];
        __shared__ float ys[4];
        if (d < 64) xs[d>>4][d&15] = x[(size_t)(g*4 + (d>>4))*XDIM + (d&15)];
        if (d < 4)  ys[d] = y[g*4 + d];
        __syncthreads();
        float wreg[XDIM];
        #pragma unroll
        for (int k = 0; k < XDIM; ++k) wreg[k] = xw[d*XDIM + k];
        const float xbv = xb[d], ywv = yw[d], ybv = yb[d];
        const bool train = (g < MPOS);
        #pragma unroll
        for (int r = 0; r < 4; ++r) {
            int row = g*4 + r;
            float acc = xbv;
            #pragma unroll
            for (int k = 0; k < XDIM; ++k) acc = fmaf(xs[r][k], wreg[k], acc);
            if (train) acc += ys[r]*ywv + ybv;
            h[(size_t)row*DMODEL + d]  = acc;
            hb[(size_t)row*DMODEL + d] = (unsigned short)f2bf(acc);
        }
        return;
    }
    int i = (blockIdx.x - ROWS/4)*256 + threadIdx.x;
    if (i >= 147456) return;
    const float* s; unsigned short* d; int off;
    if      (i <  49152) { s = s0; d = d0; off = i; }
    else if (i <  65536) { s = s1; d = d1; off = i - 49152; }
    else if (i <  98304) { s = s2; d = d2; off = i - 65536; }
    else if (i < 131072) { s = s3; d = d3; off = i - 98304; }
    else                 { s = s4; d = d4; off = i - 131072; }
    float4 a = *(const float4*)(s + (size_t)off*8);
    float4 c = *(const float4*)(s + (size_t)off*8 + 4);
    ushort4 u0, u1;
    u0.x=(unsigned short)f2bf(a.x); u0.y=(unsigned short)f2bf(a.y);
    u0.z=(unsigned short)f2bf(a.z); u0.w=(unsigned short)f2bf(a.w);
    u1.x=(unsigned short)f2bf(c.x); u1.y=(unsigned short)f2bf(c.y);
    u1.z=(unsigned short)f2bf(c.z); u1.w=(unsigned short)f2bf(c.w);
    *(ushort4*)(d + (size_t)off*8)     = u0;
    *(ushort4*)(d + (size_t)off*8 + 4) = u1;
}

// ------- qkv GEMM 128x64, BK=64 (NS=4), 2-buffer, swizzled, XCD-local A ------
__global__ __launch_bounds__(256) void gemm_qkv(
    const unsigned short* __restrict__ A, const unsigned short* __restrict__ B,
    const float* __restrict__ bias,
    unsigned short* __restrict__ Qg, unsigned short* __restrict__ Kg,
    unsigned short* __restrict__ Vg, int K)
{
    __shared__ unsigned short As[2][128][64];   // 32 KB (reused as transpose buf)
    __shared__ unsigned short Bs[2][64][64];    // 16 KB
    int tid  = threadIdx.x;
    int w    = tid >> 6, lane = tid & 63;
    int col  = lane & 15, quad = lane >> 4;
    int u    = blockIdx.x >> 3, xcd = blockIdx.x & 7;
    int by   = xcd*8 + u/12, bx = u%12;
    int m0   = by * 128, n0 = bx * 64;
    int l8   = lane >> 3;
    int c8s  = (((lane & 7) ^ l8) * 8);

    f32x4 acc[2][4];
    #pragma unroll
    for (int i = 0; i < 2; ++i)
        #pragma unroll
        for (int j = 0; j < 4; ++j) acc[i][j] = (f32x4){0.f,0.f,0.f,0.f};

    const unsigned short* ga = A + (size_t)(m0 + w*32 + l8)*K + c8s;
    const unsigned short* gb = B + (size_t)(n0 + w*16 + l8)*K + c8s;
    const int NS = K / 64;  // 4

    #pragma unroll
    for (int t = 0; t < 4; ++t) gload16(ga + (size_t)(t*8)*K, &As[0][w*32 + t*8][0]);
    #pragma unroll
    for (int t = 0; t < 2; ++t) gload16(gb + (size_t)(t*8)*K, &Bs[0][w*16 + t*8][0]);

    for (int s = 0; s < NS; ++s) {
        VMWAIT(0);
        pipe_barrier();
        if (s + 1 < NS) {
            int k2 = (s + 1) * 64;
            int nb = (s + 1) & 1;
            #pragma unroll
            for (int t = 0; t < 4; ++t) gload16(ga + k2 + (size_t)(t*8)*K, &As[nb][w*32 + t*8][0]);
            #pragma unroll
            for (int t = 0; t < 2; ++t) gload16(gb + k2 + (size_t)(t*8)*K, &Bs[nb][w*16 + t*8][0]);
        }
        int cur = s & 1;
        #pragma unroll
        for (int kk = 0; kk < 2; ++kk) {
            const int so = (((kk*4 + quad) ^ (col & 7)) * 8);
            bf16x8 af[2], bfr[4];
            #pragma unroll
            for (int i = 0; i < 2; ++i) af[i]  = *(const bf16x8*)&As[cur][w*32 + i*16 + col][so];
            #pragma unroll
            for (int j = 0; j < 4; ++j) bfr[j] = *(const bf16x8*)&Bs[cur][j*16 + col][so];
            #pragma unroll
            for (int i = 0; i < 2; ++i)
                #pragma unroll
                for (int j = 0; j < 4; ++j)
                    acc[i][j] = __builtin_amdgcn_mfma_f32_16x16x32_bf16(bfr[j], af[i], acc[i][j], 0, 0, 0);
        }
    }

    int region = n0 >> 8;   // 0=Q, 1=K, 2=V (uniform per block)
    if (region < 2) {
        #pragma unroll
        for (int i = 0; i < 2; ++i) {
            int m = m0 + w*32 + i*16 + col;
            int s = m >> 2, bidx = m & 3;
            #pragma unroll
            for (int j = 0; j < 4; ++j) {
                int ng = n0 + j*16 + quad*4;
                float4 bi = *(const float4*)&bias[ng];
                ushort4 uu;
                uu.x=(unsigned short)f2bf(acc[i][j][0] + bi.x);
                uu.y=(unsigned short)f2bf(acc[i][j][1] + bi.y);
                uu.z=(unsigned short)f2bf(acc[i][j][2] + bi.z);
                uu.w=(unsigned short)f2bf(acc[i][j][3] + bi.w);
                int np = ng - (region << 8);
                int hh = np >> 5, d = np & 31;
                int bh = bidx*NHEAD + hh;
                if (region == 0)
                    *(ushort4*)(Qg + ((size_t)(bh*SEQ + s))*DH + d) = uu;
                else
                    *(ushort4*)(Kg + ((size_t)(bh*SEQ + s))*DH + d) = uu;
            }
        }
    } else {
        __syncthreads();
        unsigned short* T3 = (unsigned short*)As;   // 16 KB scratch
        #pragma unroll
        for (int i = 0; i < 2; ++i) {
            int mi = w*32 + i*16 + col;
            int ss = mi >> 2, bidx = mi & 3;
            #pragma unroll
            for (int j = 0; j < 4; ++j) {
                int ni = j*16 + quad*4;
                float4 bi = *(const float4*)&bias[n0 + ni];
                T3[((ni    )*4 + bidx)*32 + ss] = (unsigned short)f2bf(acc[i][j][0] + bi.x);
                T3[((ni + 1)*4 + bidx)*32 + ss] = (unsigned short)f2bf(acc[i][j][1] + bi.y);
                T3[((ni + 2)*4 + bidx)*32 + ss] = (unsigned short)f2bf(acc[i][j][2] + bi.z);
                T3[((ni + 3)*4 + bidx)*32 + ss] = (unsigned short)f2bf(acc[i][j][3] + bi.w);
            }
        }
        __syncthreads();
        int sBase = m0 >> 2;
        #pragma unroll
        for (int r = 0; r < 4; ++r) {
            int chunk = tid + 256*r;
            int l = chunk >> 2, p = chunk & 3;
            int d = l & 31, hh_l = (l >> 5) & 1, bidx = l >> 6;
            int ni = hh_l*32 + d;
            int hh = ((n0 & 255) + ni) >> 5;
            int bh = bidx*NHEAD + hh;
            uint4 val = *(const uint4*)&T3[(ni*4 + bidx)*32 + p*8];
            *(uint4*)(Vg + ((size_t)(bh*DH + d))*SEQ + sBase + p*8) = val;
        }
    }
}

// ---------------- MFMA flash attention, DUAL q-tile, KVBLK=128 (R11) ---------
__global__ __launch_bounds__(256) void attn_mfma(
    const unsigned short* __restrict__ Qg,
    const unsigned short* __restrict__ Kg,
    const unsigned short* __restrict__ Vg,
    unsigned short* __restrict__ o)           // bf16 [s*B+b][256]
{
    const int id  = blockIdx.x;               // 0..511
    const int sl  = id >> 3;                  // 0..63
    const int bh  = (id & 7) * 4 + (sl >> 4); // XCD (id&7) owns bh [4x,4x+4)
    const int qt2 = sl & 15;
    const int h   = bh & 7;
    const int b   = bh >> 3;
    const int q0A = qt2 * 64;                 // low tile, q < MPOS
    const int q0B = MPOS + qt2 * 64;          // high tile, q >= MPOS
    const int tid  = threadIdx.x;
    const int w    = tid >> 6;
    const int lane = tid & 63;
    const int col  = lane & 15;
    const int quad = lane >> 4;

    __shared__ unsigned short Kt[2][128][40];   // [key][d]  20 KB
    __shared__ unsigned short Vt[2][32][136];   // [d][key]  17 KB
    __shared__ unsigned short PtA[4][16][136];  // 17 KB
    __shared__ unsigned short PtB[4][16][136];  // 17 KB

    const int qA = q0A + 16*w + col;
    const int qB = q0B + 16*w + col;
    bf16x8 qfA = *(const bf16x8*)(Qg + ((size_t)(bh*SEQ + qA))*DH + quad*8);
    bf16x8 qfB = *(const bf16x8*)(Qg + ((size_t)(bh*SEQ + qB))*DH + quad*8);

    f32x4 O0A = {0.f,0.f,0.f,0.f}, O1A = {0.f,0.f,0.f,0.f};
    f32x4 O0B = {0.f,0.f,0.f,0.f}, O1B = {0.f,0.f,0.f,0.f};
    float lsumA = 0.f, lsumB = 0.f;

    const int kRow = tid >> 2, kCh = (tid & 3) * 8;
    const int vD   = tid >> 3, vCh = (tid & 7) * 8;

    uint4 kreg0 = *(const uint4*)(Kg + ((size_t)(bh*SEQ + kRow     ))*DH + kCh);
    uint4 kreg1 = *(const uint4*)(Kg + ((size_t)(bh*SEQ + kRow + 64))*DH + kCh);
    uint4 vreg0 = *(const uint4*)(Vg + ((size_t)(bh*DH + vD))*SEQ + vCh);
    uint4 vreg1 = *(const uint4*)(Vg + ((size_t)(bh*DH + vD))*SEQ + vCh + 64);

    for (int kt = 0; kt < 8; ++kt) {
        const int p = kt & 1;
        *(uint4*)&Kt[p][kRow     ][kCh] = kreg0;
        *(uint4*)&Kt[p][kRow + 64][kCh] = kreg1;
        *(uint4*)&Vt[p][vD][vCh     ]   = vreg0;
        *(uint4*)&Vt[p][vD][vCh + 64]   = vreg1;
        __syncthreads();
        if (kt < 7) {
            int kn = (kt + 1) * 128;
            kreg0 = *(const uint4*)(Kg + ((size_t)(bh*SEQ + kn + kRow     ))*DH + kCh);
            kreg1 = *(const uint4*)(Kg + ((size_t)(bh*SEQ + kn + kRow + 64))*DH + kCh);
            vreg0 = *(const uint4*)(Vg + ((size_t)(bh*DH + vD))*SEQ + kn + vCh);
            vreg1 = *(const uint4*)(Vg + ((size_t)(bh*DH + vD))*SEQ + kn + vCh + 64);
        } else {
            // prefetch the 64-key self tile (keys [q0B, q0B+64))
            kreg0 = *(const uint4*)(Kg + ((size_t)(bh*SEQ + q0B + kRow))*DH + kCh);
            vreg0 = *(const uint4*)(Vg + ((size_t)(bh*DH + vD))*SEQ + q0B + vCh);
        }

        #pragma unroll
        for (int mt = 0; mt < 8; ++mt) {
            bf16x8 kf = *(const bf16x8*)&Kt[p][mt*16 + col][quad*8];
            f32x4 stA = {0.f,0.f,0.f,0.f};
            stA = __builtin_amdgcn_mfma_f32_16x16x32_bf16(kf, qfA, stA, 0, 0, 0);
            ushort4 pwA;
            #pragma unroll
            for (int i = 0; i < 4; ++i) {
                float pv = __expf(stA[i]*ATT_SCALE);
                unsigned short us = (unsigned short)f2bf(pv);
                ((unsigned short*)&pwA)[i] = us;
                lsumA += bf2f(us);
            }
            *(ushort4*)&PtA[w][col][mt*16 + quad*4] = pwA;

            f32x4 stB = {0.f,0.f,0.f,0.f};
            stB = __builtin_amdgcn_mfma_f32_16x16x32_bf16(kf, qfB, stB, 0, 0, 0);
            ushort4 pwB;
            #pragma unroll
            for (int i = 0; i < 4; ++i) {
                float pv = __expf(stB[i]*ATT_SCALE);
                unsigned short us = (unsigned short)f2bf(pv);
                ((unsigned short*)&pwB)[i] = us;
                lsumB += bf2f(us);
            }
            *(ushort4*)&PtB[w][col][mt*16 + quad*4] = pwB;
        }
        #pragma unroll
        for (int c = 0; c < 4; ++c) {
            bf16x8 v0 = *(const bf16x8*)&Vt[p][col     ][c*32 + quad*8];
            bf16x8 v1 = *(const bf16x8*)&Vt[p][col + 16][c*32 + quad*8];
            bf16x8 pfA = *(const bf16x8*)&PtA[w][col][c*32 + quad*8];
            O0A = __builtin_amdgcn_mfma_f32_16x16x32_bf16(v0, pfA, O0A, 0, 0, 0);
            O1A = __builtin_amdgcn_mfma_f32_16x16x32_bf16(v1, pfA, O1A, 0, 0, 0);
            bf16x8 pfB = *(const bf16x8*)&PtB[w][col][c*32 + quad*8];
            O0B = __builtin_amdgcn_mfma_f32_16x16x32_bf16(v0, pfB, O0B, 0, 0, 0);
            O1B = __builtin_amdgcn_mfma_f32_16x16x32_bf16(v1, pfB, O1B, 0, 0, 0);
        }
    }

    // ---- self tile (group B diagonal), 64 keys, buffer 0 ----
    *(uint4*)&Kt[0][kRow][kCh] = kreg0;
    *(uint4*)&Vt[0][vD][vCh]   = vreg0;
    __syncthreads();
    #pragma unroll
    for (int mt = 0; mt < 4; ++mt) {
        bf16x8 kf = *(const bf16x8*)&Kt[0][mt*16 + col][quad*8];
        f32x4 stB = {0.f,0.f,0.f,0.f};
        stB = __builtin_amdgcn_mfma_f32_16x16x32_bf16(kf, qfB, stB, 0, 0, 0);
        ushort4 pwB;
        #pragma unroll
        for (int i = 0; i < 4; ++i) {
            float pv = __expf(stB[i]*ATT_SCALE);
            if (mt*16 + quad*4 + i != 16*w + col) pv = 0.f;
            unsigned short us = (unsigned short)f2bf(pv);
            ((unsigned short*)&pwB)[i] = us;
            lsumB += bf2f(us);
        }
        *(ushort4*)&PtB[w][col][mt*16 + quad*4] = pwB;
    }
    #pragma unroll
    for (int c = 0; c < 2; ++c) {
        bf16x8 v0 = *(const bf16x8*)&Vt[0][col     ][c*32 + quad*8];
        bf16x8 v1 = *(const bf16x8*)&Vt[0][col + 16][c*32 + quad*8];
        bf16x8 pfB = *(const bf16x8*)&PtB[w][col][c*32 + quad*8];
        O0B = __builtin_amdgcn_mfma_f32_16x16x32_bf16(v0, pfB, O0B, 0, 0, 0);
        O1B = __builtin_amdgcn_mfma_f32_16x16x32_bf16(v1, pfB, O1B, 0, 0, 0);
    }

    lsumA += __shfl_xor(lsumA, 16, 64); lsumA += __shfl_xor(lsumA, 32, 64);
    lsumB += __shfl_xor(lsumB, 16, 64); lsumB += __shfl_xor(lsumB, 32, 64);
    float invA = 1.0f / lsumA, invB = 1.0f / lsumB;
    ushort4 u0, u1;
    #pragma unroll
    for (int i = 0; i < 4; ++i) {
        ((unsigned short*)&u0)[i] = (unsigned short)f2bf(O0A[i]*invA);
        ((unsigned short*)&u1)[i] = (unsigned short)f2bf(O1A[i]*invA);
    }
    unsigned short* opA = o + ((size_t)(qA*BATCH + b))*DMODEL + h*DH;
    *(ushort4*)(opA + quad*4)      = u0;
    *(ushort4*)(opA + 16 + quad*4) = u1;
    #pragma unroll
    for (int i = 0; i < 4; ++i) {
        ((unsigned short*)&u0)[i] = (unsigned short)f2bf(O0B[i]*invB);
        ((unsigned short*)&u1)[i] = (unsigned short)f2bf(O1B[i]*invB);
    }
    unsigned short* opB = o + ((size_t)(qB*BATCH + b))*DMODEL + h*DH;
    *(ushort4*)(opB + quad*4)      = u0;
    *(ushort4*)(opB + 16 + quad*4) = u1;
}

// ------- fused MLP, TWO 16-row groups, BK=64, 512 THREADS (8 waves) -----------
// Same LDS/math as R11, but 8 waves (2/SIMD) each owning 32 output columns:
// one wave's vmcnt/barrier stall overlaps its SIMD-mate's MFMA (m114 mechanism).
__global__ __launch_bounds__(512) void mlp_fused(
    const unsigned short* __restrict__ attb,
    const unsigned short* __restrict__ Wout, const float* __restrict__ ob,
    const float* __restrict__ g1, const float* __restrict__ be1,
    const unsigned short* __restrict__ W1, const float* __restrict__ fb1,
    const unsigned short* __restrict__ W2, const float* __restrict__ fb2,
    const float* __restrict__ g2, const float* __restrict__ be2,
    float* __restrict__ h, unsigned short* __restrict__ hb,
    const unsigned short* __restrict__ Wh1, const float* __restrict__ hb1,
    const float* __restrict__ hw2, const float* __restrict__ hb2,
    float* __restrict__ out, int doHead)
{
    __shared__ unsigned short Bs[3][256][64];         // 96 KB weight staging
    __shared__ __align__(16) unsigned char smem_u[33280];  // As (12 KB) / Pt (32.5 KB)
    __shared__ unsigned short Ht[2][16][264];         // LN1-out / LN2-out bf16
    __shared__ float sP[2][8][16], qP[2][8][16];

    typedef unsigned short AsT[2][16][64];
    AsT* As = reinterpret_cast<AsT*>(smem_u);
    typedef unsigned short PtT[16][520];
    PtT* Pt = reinterpret_cast<PtT*>(smem_u);

    const int tid  = threadIdx.x;
    const int w    = tid >> 6;            // 0..7
    const int lane = tid & 63;
    const int col  = lane & 15;
    const int quad = lane >> 4;
    const int l8   = lane >> 3;
    const int c8s  = (((lane & 7) ^ l8) * 8);
    const int bid  = blockIdx.x;
    const int m0a  = bid * 16;
    const int m0b  = 4096 + bid * 16;
    const int ma   = m0a + col;
    const int mb   = m0b + col;

    float resid[2][2][4];

    // ================= stage A: out-proj (K=256, NS=4) + residual + LN1 =======
    {
        f32x4 acc[2][2];
        #pragma unroll
        for (int g = 0; g < 2; ++g)
            #pragma unroll
            for (int j = 0; j < 2; ++j) acc[g][j] = (f32x4){0.f,0.f,0.f,0.f};

        const int gr = w >> 1;            // waves 0-3 stage As: group gr, half w&1
        const unsigned short* gaw = attb + (size_t)((gr ? m0b : m0a) + (w&1)*8 + l8)*DMODEL + c8s;
        const unsigned short* gb  = Wout + (size_t)(w*32 + l8)*DMODEL + c8s;
        const int NS = DMODEL / 64;  // 4

        #pragma unroll
        for (int pb = 0; pb < 2; ++pb) {
            int k = pb * 64;
            if (w < 4) gload16(gaw + k, &As[pb][gr][(w&1)*8][0]);
            #pragma unroll
            for (int t = 0; t < 4; ++t)
                gload16(gb + k + (size_t)(t*8)*DMODEL, &Bs[pb][w*32 + t*8][0]);
        }
        int bcur = 0;
        for (int s = 0; s < NS; ++s) {
            if (s == NS - 1)      { VMWAIT(0); }
            else if (w < 4)       { VMWAIT(5); }
            else                  { VMWAIT(4); }
            pipe_barrier();
            if (s + 2 < NS) {
                int bpre = bcur + 2; if (bpre >= 3) bpre -= 3;
                int k2 = (s + 2) * 64;
                if (w < 4) gload16(gaw + k2, &As[bpre][gr][(w&1)*8][0]);
                #pragma unroll
                for (int t = 0; t < 4; ++t)
                    gload16(gb + k2 + (size_t)(t*8)*DMODEL, &Bs[bpre][w*32 + t*8][0]);
            }
            #pragma unroll
            for (int kk = 0; kk < 2; ++kk) {
                const int so = (((kk*4 + quad) ^ (col & 7)) * 8);
                bf16x8 af0 = *(const bf16x8*)&As[bcur][0][col][so];
                bf16x8 af1 = *(const bf16x8*)&As[bcur][1][col][so];
                #pragma unroll
                for (int j = 0; j < 2; ++j) {
                    bf16x8 bfr = *(const bf16x8*)&Bs[bcur][w*32 + j*16 + col][so];
                    acc[0][j] = __builtin_amdgcn_mfma_f32_16x16x32_bf16(bfr, af0, acc[0][j], 0, 0, 0);
                    acc[1][j] = __builtin_amdgcn_mfma_f32_16x16x32_bf16(bfr, af1, acc[1][j], 0, 0, 0);
                }
            }
            bcur = (bcur == 2) ? 0 : bcur + 1;
        }

        float ssum[2] = {0.f, 0.f}, qsum[2] = {0.f, 0.f};
        #pragma unroll
        for (int g = 0; g < 2; ++g) {
            int m = g ? mb : ma;
            #pragma unroll
            for (int j = 0; j < 2; ++j) {
                int n = w*32 + j*16 + quad*4;
                float4 bi = *(const float4*)&ob[n];
                float4 hv = *(const float4*)&h[(size_t)m*DMODEL + n];
                #pragma unroll
                for (int i = 0; i < 4; ++i) {
                    float val = acc[g][j][i] + ((const float*)&bi)[i] + ((const float*)&hv)[i];
                    resid[g][j][i] = val;
                    ssum[g] += val; qsum[g] += val*val;
                }
            }
        }
        #pragma unroll
        for (int g = 0; g < 2; ++g) {
            ssum[g] += __shfl_xor(ssum[g], 16, 64); ssum[g] += __shfl_xor(ssum[g], 32, 64);
            qsum[g] += __shfl_xor(qsum[g], 16, 64); qsum[g] += __shfl_xor(qsum[g], 32, 64);
        }
        if (quad == 0) {
            sP[0][w][col] = ssum[0]; qP[0][w][col] = qsum[0];
            sP[1][w][col] = ssum[1]; qP[1][w][col] = qsum[1];
        }
        __syncthreads();
        #pragma unroll
        for (int g = 0; g < 2; ++g) {
            float st = 0.f, qt = 0.f;
            #pragma unroll
            for (int ww = 0; ww < 8; ++ww) { st += sP[g][ww][col]; qt += qP[g][ww][col]; }
            float mu   = st * (1.0f/DMODEL);
            float var  = qt * (1.0f/DMODEL) - mu*mu;
            float rstd = rsqrtf(var + 1e-5f);
            #pragma unroll
            for (int j = 0; j < 2; ++j) {
                int n = w*32 + j*16 + quad*4;
                float4 gv = *(const float4*)&g1[n];
                float4 bv = *(const float4*)&be1[n];
                ushort4 u;
                #pragma unroll
                for (int i = 0; i < 4; ++i) {
                    float o = (resid[g][j][i]-mu)*rstd*((const float*)&gv)[i] + ((const float*)&bv)[i];
                    resid[g][j][i] = o;
                    ((unsigned short*)&u)[i] = (unsigned short)f2bf(o);
                }
                *(ushort4*)&Ht[g][col][n] = u;
            }
        }
        __syncthreads();   // Ht visible; all waves past As/Bs reads
    }

    // ================= stage B: ff1 (K=256 NS=4, two N-halves) + gelu =========
    #pragma unroll 1
    for (int nh = 0; nh < 2; ++nh) {
        f32x4 acc[2][2];
        #pragma unroll
        for (int g = 0; g < 2; ++g)
            #pragma unroll
            for (int j = 0; j < 2; ++j) acc[g][j] = (f32x4){0.f,0.f,0.f,0.f};
        const unsigned short* gb = W1 + (size_t)(nh*256 + w*32 + l8)*DMODEL + c8s;
        const int NS = DMODEL / 64;  // 4

        #pragma unroll
        for (int pb = 0; pb < 2; ++pb)
            #pragma unroll
            for (int t = 0; t < 4; ++t)
                gload16(gb + pb*64 + (size_t)(t*8)*DMODEL, &Bs[pb][w*32 + t*8][0]);

        int bcur = 0;
        for (int s = 0; s < NS; ++s) {
            if (s == NS - 1) { VMWAIT(0); } else { VMWAIT(4); }
            pipe_barrier();
            if (s + 2 < NS) {
                int bpre = bcur + 2; if (bpre >= 3) bpre -= 3;
                int k2 = (s + 2) * 64;
                #pragma unroll
                for (int t = 0; t < 4; ++t)
                    gload16(gb + k2 + (size_t)(t*8)*DMODEL, &Bs[bpre][w*32 + t*8][0]);
            }
            #pragma unroll
            for (int kk = 0; kk < 2; ++kk) {
                const int so = (((kk*4 + quad) ^ (col & 7)) * 8);
                bf16x8 af0 = *(const bf16x8*)&Ht[0][col][s*64 + kk*32 + quad*8];
                bf16x8 af1 = *(const bf16x8*)&Ht[1][col][s*64 + kk*32 + quad*8];
                #pragma unroll
                for (int j = 0; j < 2; ++j) {
                    bf16x8 bfr = *(const bf16x8*)&Bs[bcur][w*32 + j*16 + col][so];
                    acc[0][j] = __builtin_amdgcn_mfma_f32_16x16x32_bf16(bfr, af0, acc[0][j], 0, 0, 0);
                    acc[1][j] = __builtin_amdgcn_mfma_f32_16x16x32_bf16(bfr, af1, acc[1][j], 0, 0, 0);
                }
            }
            bcur = (bcur == 2) ? 0 : bcur + 1;
        }
        #pragma unroll
        for (int g = 0; g < 2; ++g)
            #pragma unroll
            for (int j = 0; j < 2; ++j) {
                int n2 = nh*256 + w*32 + j*16 + quad*4;
                float4 bi = *(const float4*)&fb1[n2];
                ushort4 u;
                #pragma unroll
                for (int i = 0; i < 4; ++i)
                    ((unsigned short*)&u)[i] = (unsigned short)f2bf(gelu_exact(acc[g][j][i] + ((const float*)&bi)[i]));
                *(ushort4*)&Pt[g][col][n2] = u;
            }
        pipe_barrier();   // all waves past Bs reads before next half's staging
    }

    // ================= stage C: ff2 (K=512 NS=8) + residual + LN2 =============
    {
        __syncthreads();  // Pt visible
        f32x4 acc[2][2];
        #pragma unroll
        for (int g = 0; g < 2; ++g)
            #pragma unroll
            for (int j = 0; j < 2; ++j) acc[g][j] = (f32x4){0.f,0.f,0.f,0.f};
        const unsigned short* gb = W2 + (size_t)(w*32 + l8)*DFF + c8s;
        const int NS = DFF / 64;  // 8

        #pragma unroll
        for (int pb = 0; pb < 2; ++pb)
            #pragma unroll
            for (int t = 0; t < 4; ++t)
                gload16(gb + pb*64 + (size_t)(t*8)*DFF, &Bs[pb][w*32 + t*8][0]);

        int bcur = 0;
        for (int s = 0; s < NS; ++s) {
            if (s == NS - 1) { VMWAIT(0); } else { VMWAIT(4); }
            pipe_barrier();
            if (s + 2 < NS) {
                int bpre = bcur + 2; if (bpre >= 3) bpre -= 3;
                int k2 = (s + 2) * 64;
                #pragma unroll
                for (int t = 0; t < 4; ++t)
                    gload16(gb + k2 + (size_t)(t*8)*DFF, &Bs[bpre][w*32 + t*8][0]);
            }
            #pragma unroll
            for (int kk = 0; kk < 2; ++kk) {
                const int so = (((kk*4 + quad) ^ (col & 7)) * 8);
                bf16x8 af0 = *(const bf16x8*)&Pt[0][col][s*64 + kk*32 + quad*8];
                bf16x8 af1 = *(const bf16x8*)&Pt[1][col][s*64 + kk*32 + quad*8];
                #pragma unroll
                for (int j = 0; j < 2; ++j) {
                    bf16x8 bfr = *(const bf16x8*)&Bs[bcur][w*32 + j*16 + col][so];
                    acc[0][j] = __builtin_amdgcn_mfma_f32_16x16x32_bf16(bfr, af0, acc[0][j], 0, 0, 0);
                    acc[1][j] = __builtin_amdgcn_mfma_f32_16x16x32_bf16(bfr, af1, acc[1][j], 0, 0, 0);
                }
            }
            bcur = (bcur == 2) ? 0 : bcur + 1;
        }

        float ssum[2] = {0.f, 0.f}, qsum[2] = {0.f, 0.f};
        #pragma unroll
        for (int g = 0; g < 2; ++g)
            #pragma unroll
            for (int j = 0; j < 2; ++j) {
                int n = w*32 + j*16 + quad*4;
                float4 bi = *(const float4*)&fb2[n];
                #pragma unroll
                for (int i = 0; i < 4; ++i) {
                    float val = acc[g][j][i] + ((const float*)&bi)[i] + resid[g][j][i];
                    resid[g][j][i] = val;
                    ssum[g] += val; qsum[g] += val*val;
                }
            }
        #pragma unroll
        for (int g = 0; g < 2; ++g) {
            ssum[g] += __shfl_xor(ssum[g], 16, 64); ssum[g] += __shfl_xor(ssum[g], 32, 64);
            qsum[g] += __shfl_xor(qsum[g], 16, 64); qsum[g] += __shfl_xor(qsum[g], 32, 64);
        }
        if (quad == 0) {
            sP[0][w][col] = ssum[0]; qP[0][w][col] = qsum[0];
            sP[1][w][col] = ssum[1]; qP[1][w][col] = qsum[1];
        }
        __syncthreads();
        #pragma unroll
        for (int g = 0; g < 2; ++g) {
            int m = g ? mb : ma;
            float st = 0.f, qt = 0.f;
            #pragma unroll
            for (int ww = 0; ww < 8; ++ww) { st += sP[g][ww][col]; qt += qP[g][ww][col]; }
            float mu   = st * (1.0f/DMODEL);
            float var  = qt * (1.0f/DMODEL) - mu*mu;
            float rstd = rsqrtf(var + 1e-5f);
            #pragma unroll
            for (int j = 0; j < 2; ++j) {
                int n = w*32 + j*16 + quad*4;
                float4 gv = *(const float4*)&g2[n];
                float4 bv = *(const float4*)&be2[n];
                float4 o;
                ushort4 u;
                #pragma unroll
                for (int i = 0; i < 4; ++i) {
                    float ov = (resid[g][j][i]-mu)*rstd*((const float*)&gv)[i] + ((const float*)&bv)[i];
                    ((float*)&o)[i] = ov;
                    ((unsigned short*)&u)[i] = (unsigned short)f2bf(ov);
                }
                *(float4*)&h[(size_t)m*DMODEL + n] = o;
                *(ushort4*)(hb + (size_t)m*DMODEL + n) = u;
                *(ushort4*)&Ht[g][col][n] = u;   // LN2 bf16 for head
            }
        }
        __syncthreads();
    }

    // ================= stage D: head (layer 1; 16 head rows per block) ========
    if (doHead) {
        float sdot = 0.f;
        #pragma unroll 1
        for (int nh = 0; nh < 2; ++nh) {
            f32x4 acc[2];
            #pragma unroll
            for (int j = 0; j < 2; ++j) acc[j] = (f32x4){0.f,0.f,0.f,0.f};
            const unsigned short* gb = Wh1 + (size_t)(nh*256 + w*32 + l8)*DMODEL + c8s;
            const int NS = DMODEL / 64;  // 4

            #pragma unroll
            for (int pb = 0; pb < 2; ++pb)
                #pragma unroll
                for (int t = 0; t < 4; ++t)
                    gload16(gb + pb*64 + (size_t)(t*8)*DMODEL, &Bs[pb][w*32 + t*8][0]);

            int bcur = 0;
            for (int s = 0; s < NS; ++s) {
                if (s == NS - 1) { VMWAIT(0); } else { VMWAIT(4); }
                pipe_barrier();
                if (s + 2 < NS) {
                    int bpre = bcur + 2; if (bpre >= 3) bpre -= 3;
                    int k2 = (s + 2) * 64;
                    #pragma unroll
                    for (int t = 0; t < 4; ++t)
                        gload16(gb + k2 + (size_t)(t*8)*DMODEL, &Bs[bpre][w*32 + t*8][0]);
                }
                #pragma unroll
                for (int kk = 0; kk < 2; ++kk) {
                    const int so = (((kk*4 + quad) ^ (col & 7)) * 8);
                    bf16x8 af = *(const bf16x8*)&Ht[1][col][s*64 + kk*32 + quad*8];
                    #pragma unroll
                    for (int j = 0; j < 2; ++j) {
                        bf16x8 bfr = *(const bf16x8*)&Bs[bcur][w*32 + j*16 + col][so];
                        acc[j] = __builtin_amdgcn_mfma_f32_16x16x32_bf16(bfr, af, acc[j], 0, 0, 0);
                    }
                }
                bcur = (bcur == 2) ? 0 : bcur + 1;
            }
            #pragma unroll
            for (int j = 0; j < 2; ++j) {
                int n2 = nh*256 + w*32 + j*16 + quad*4;
                float4 b1v = *(const float4*)&hb1[n2];
                float4 w2v = *(const float4*)&hw2[n2];
                #pragma unroll
                for (int i = 0; i < 4; ++i)
                    sdot += gelu_exact(acc[j][i] + ((const float*)&b1v)[i]) * ((const float*)&w2v)[i];
            }
            pipe_barrier();
        }
        sdot += __shfl_xor(sdot, 16, 64); sdot += __shfl_xor(sdot, 32, 64);
        if (quad == 0) sP[0][w][col] = sdot;
        __syncthreads();
        if (tid < 16) {
            float r = hb2[0];
            #pragma unroll
            for (int ww = 0; ww < 8; ++ww) r += sP[0][ww][tid];
            out[bid*16 + tid] = r;
        }
    }
}

extern "C" void kernel_launch(void* const* d_in, const int* in_sizes, int n_in,
                              void* d_out, int out_size, void* d_ws, size_t ws_size,
                              hipStream_t stream)
{
    const float* x        = (const float*)d_in[0];
    const float* y        = (const float*)d_in[1];
    const float* xenc_w   = (const float*)d_in[3];
    const float* xenc_b   = (const float*)d_in[4];
    const float* yenc_w   = (const float*)d_in[5];
    const float* yenc_b   = (const float*)d_in[6];
    const float* in_proj_w  = (const float*)d_in[7];
    const float* in_proj_b  = (const float*)d_in[8];
    const float* out_proj_w = (const float*)d_in[9];
    const float* out_proj_b = (const float*)d_in[10];
    const float* ln1_g    = (const float*)d_in[11];
    const float* ln1_b    = (const float*)d_in[12];
    const float* lin1_w   = (const float*)d_in[13];
    const float* lin1_b   = (const float*)d_in[14];
    const float* lin2_w   = (const float*)d_in[15];
    const float* lin2_b   = (const float*)d_in[16];
    const float* ln2_g    = (const float*)d_in[17];
    const float* ln2_b    = (const float*)d_in[18];
    const float* head_w1  = (const float*)d_in[19];
    const float* head_b1  = (const float*)d_in[20];
    const float* head_w2  = (const float*)d_in[21];
    const float* head_b2  = (const float*)d_in[22];
    float* out = (float*)d_out;

    // ---- workspace layout ----
    float* ws  = (float*)d_ws;
    float* h    = ws;
    unsigned short* hb    = (unsigned short*)(h + (size_t)ROWS*DMODEL);
    unsigned short* attb  = hb    + (size_t)ROWS*DMODEL;
    unsigned short* Qg    = attb  + (size_t)ROWS*DMODEL;
    unsigned short* Kg    = Qg    + (size_t)BATCH*NHEAD*SEQ*DH;
    unsigned short* Vg    = Kg    + (size_t)BATCH*NHEAD*SEQ*DH;
    unsigned short* Wqkv  = Vg    + (size_t)BATCH*NHEAD*SEQ*DH;
    unsigned short* Wout  = Wqkv  + (size_t)NLAYER*3*DMODEL*DMODEL;
    unsigned short* Wl1   = Wout  + (size_t)NLAYER*DMODEL*DMODEL;
    unsigned short* Wl2   = Wl1   + (size_t)NLAYER*DFF*DMODEL;
    unsigned short* Wh1   = Wl2   + (size_t)NLAYER*DMODEL*DFF;

    encode_cast<<<ROWS/4 + 576, 256, 0, stream>>>(
        x, y, xenc_w, xenc_b, yenc_w, yenc_b, h, hb,
        in_proj_w, out_proj_w, lin1_w, lin2_w, head_w1,
        Wqkv, Wout, Wl1, Wl2, Wh1);

    for (int l = 0; l < NLAYER; ++l) {
        gemm_qkv<<<768, 256, 0, stream>>>(
            hb, Wqkv + (size_t)l*3*DMODEL*DMODEL, in_proj_b + l*3*DMODEL,
            Qg, Kg, Vg, DMODEL);
        attn_mfma<<<512, 256, 0, stream>>>(Qg, Kg, Vg, attb);
        mlp_fused<<<256, 512, 0, stream>>>(
            attb,
            Wout + (size_t)l*DMODEL*DMODEL, out_proj_b + l*DMODEL,
            ln1_g + l*DMODEL, ln1_b + l*DMODEL,
            Wl1 + (size_t)l*DFF*DMODEL, lin1_b + l*DFF,
            Wl2 + (size_t)l*DMODEL*DFF, lin2_b + l*DMODEL,
            ln2_g + l*DMODEL, ln2_b + l*DMODEL,
            h, hb,
            Wh1, head_b1, head_w2, head_b2,
            out, (l == NLAYER-1) ? 1 : 0);
    }
}

// Round 15
// 226.265 us; speedup vs baseline: 1.1033x; 1.0159x over previous
//
#include <hip/hip_runtime.h>
#include <hip/hip_bf16.h>
#include <math.h>

// Problem constants (fixed by setup_inputs)
#define SEQ    2048
#define BATCH  4
#define XDIM   16
#define DMODEL 256
#define NHEAD  8
#define DH     32
#define DFF    512
#define NLAYER 2
#define MPOS   1024
#define ROWS   (SEQ*BATCH)   // 8192

#define ATT_SCALE 0.17677669529663687f  // 1/sqrt(32)

typedef __attribute__((ext_vector_type(8))) short bf16x8;  // MFMA A/B frag
typedef __attribute__((ext_vector_type(4))) float f32x4;   // MFMA C/D frag

__device__ __forceinline__ float gelu_exact(float x) {
    return 0.5f * x * (1.0f + erff(x * 0.70710678118654752f));
}
__device__ __forceinline__ short f2bf(float f) {
    unsigned int u = __float_as_uint(f);
    u += 0x7FFFu + ((u >> 16) & 1u);
    return (short)(u >> 16);
}
__device__ __forceinline__ float bf2f(unsigned short u) {
    return __uint_as_float(((unsigned int)u) << 16);
}
__device__ __forceinline__ void gload16(const unsigned short* g, unsigned short* l) {
    __builtin_amdgcn_global_load_lds(
        (const __attribute__((address_space(1))) unsigned int*)g,
        (__attribute__((address_space(3))) unsigned int*)l, 16, 0, 0);
}
#define VMWAIT(N) asm volatile("s_waitcnt vmcnt(" #N ")" ::: "memory")
__device__ __forceinline__ void pipe_barrier() {
    __builtin_amdgcn_sched_barrier(0);
    __builtin_amdgcn_s_barrier();
    __builtin_amdgcn_sched_barrier(0);
}

// ---------------- encoder (4 rows/block) + weight casts, ONE launch -----------
__global__ __launch_bounds__(256) void encode_cast(
    const float* __restrict__ x, const float* __restrict__ y,
    const float* __restrict__ xw, const float* __restrict__ xb,
    const float* __restrict__ yw, const float* __restrict__ yb,
    float* __restrict__ h, unsigned short* __restrict__ hb,
    const float* __restrict__ s0, const float* __restrict__ s1,
    const float* __restrict__ s2, const float* __restrict__ s3,
    const float* __restrict__ s4,
    unsigned short* __restrict__ d0, unsigned short* __restrict__ d1,
    unsigned short* __restrict__ d2, unsigned short* __restrict__ d3,
    unsigned short* __restrict__ d4)
{
    if (blockIdx.x < ROWS/4) {
        int g = blockIdx.x;        // token index s (4 batch rows share it)
        int d = threadIdx.x;       // 0..255
        __shared__ float xs[4][XDIM];
        __shared__ float ys[4];
        if (d < 64) xs[d>>4][d&15] = x[(size_t)(g*4 + (d>>4))*XDIM + (d&15)];
        if (d < 4)  ys[d] = y[g*4 + d];
        __syncthreads();
        float wreg[XDIM];
        #pragma unroll
        for (int k = 0; k < XDIM; ++k) wreg[k] = xw[d*XDIM + k];
        const float xbv = xb[d], ywv = yw[d], ybv = yb[d];
        const bool train = (g < MPOS);
        #pragma unroll
        for (int r = 0; r < 4; ++r) {
            int row = g*4 + r;
            float acc = xbv;
            #pragma unroll
            for (int k = 0; k < XDIM; ++k) acc = fmaf(xs[r][k], wreg[k], acc);
            if (train) acc += ys[r]*ywv + ybv;
            h[(size_t)row*DMODEL + d]  = acc;
            hb[(size_t)row*DMODEL + d] = (unsigned short)f2bf(acc);
        }
        return;
    }
    int i = (blockIdx.x - ROWS/4)*256 + threadIdx.x;
    if (i >= 147456) return;
    const float* s; unsigned short* d; int off;
    if      (i <  49152) { s = s0; d = d0; off = i; }
    else if (i <  65536) { s = s1; d = d1; off = i - 49152; }
    else if (i <  98304) { s = s2; d = d2; off = i - 65536; }
    else if (i < 131072) { s = s3; d = d3; off = i - 98304; }
    else                 { s = s4; d = d4; off = i - 131072; }
    float4 a = *(const float4*)(s + (size_t)off*8);
    float4 c = *(const float4*)(s + (size_t)off*8 + 4);
    ushort4 u0, u1;
    u0.x=(unsigned short)f2bf(a.x); u0.y=(unsigned short)f2bf(a.y);
    u0.z=(unsigned short)f2bf(a.z); u0.w=(unsigned short)f2bf(a.w);
    u1.x=(unsigned short)f2bf(c.x); u1.y=(unsigned short)f2bf(c.y);
    u1.z=(unsigned short)f2bf(c.z); u1.w=(unsigned short)f2bf(c.w);
    *(ushort4*)(d + (size_t)off*8)     = u0;
    *(ushort4*)(d + (size_t)off*8 + 4) = u1;
}

// ------- qkv GEMM 128x64, BK=64 (NS=4), 2-buffer, swizzled, XCD-local A ------
__global__ __launch_bounds__(256) void gemm_qkv(
    const unsigned short* __restrict__ A, const unsigned short* __restrict__ B,
    const float* __restrict__ bias,
    unsigned short* __restrict__ Qg, unsigned short* __restrict__ Kg,
    unsigned short* __restrict__ Vg, int K)
{
    __shared__ unsigned short As[2][128][64];   // 32 KB (reused as transpose buf)
    __shared__ unsigned short Bs[2][64][64];    // 16 KB
    int tid  = threadIdx.x;
    int w    = tid >> 6, lane = tid & 63;
    int col  = lane & 15, quad = lane >> 4;
    int u    = blockIdx.x >> 3, xcd = blockIdx.x & 7;
    int by   = xcd*8 + u/12, bx = u%12;
    int m0   = by * 128, n0 = bx * 64;
    int l8   = lane >> 3;
    int c8s  = (((lane & 7) ^ l8) * 8);

    f32x4 acc[2][4];
    #pragma unroll
    for (int i = 0; i < 2; ++i)
        #pragma unroll
        for (int j = 0; j < 4; ++j) acc[i][j] = (f32x4){0.f,0.f,0.f,0.f};

    const unsigned short* ga = A + (size_t)(m0 + w*32 + l8)*K + c8s;
    const unsigned short* gb = B + (size_t)(n0 + w*16 + l8)*K + c8s;
    const int NS = K / 64;  // 4

    #pragma unroll
    for (int t = 0; t < 4; ++t) gload16(ga + (size_t)(t*8)*K, &As[0][w*32 + t*8][0]);
    #pragma unroll
    for (int t = 0; t < 2; ++t) gload16(gb + (size_t)(t*8)*K, &Bs[0][w*16 + t*8][0]);

    for (int s = 0; s < NS; ++s) {
        VMWAIT(0);
        pipe_barrier();
        if (s + 1 < NS) {
            int k2 = (s + 1) * 64;
            int nb = (s + 1) & 1;
            #pragma unroll
            for (int t = 0; t < 4; ++t) gload16(ga + k2 + (size_t)(t*8)*K, &As[nb][w*32 + t*8][0]);
            #pragma unroll
            for (int t = 0; t < 2; ++t) gload16(gb + k2 + (size_t)(t*8)*K, &Bs[nb][w*16 + t*8][0]);
        }
        int cur = s & 1;
        #pragma unroll
        for (int kk = 0; kk < 2; ++kk) {
            const int so = (((kk*4 + quad) ^ (col & 7)) * 8);
            bf16x8 af[2], bfr[4];
            #pragma unroll
            for (int i = 0; i < 2; ++i) af[i]  = *(const bf16x8*)&As[cur][w*32 + i*16 + col][so];
            #pragma unroll
            for (int j = 0; j < 4; ++j) bfr[j] = *(const bf16x8*)&Bs[cur][j*16 + col][so];
            #pragma unroll
            for (int i = 0; i < 2; ++i)
                #pragma unroll
                for (int j = 0; j < 4; ++j)
                    acc[i][j] = __builtin_amdgcn_mfma_f32_16x16x32_bf16(bfr[j], af[i], acc[i][j], 0, 0, 0);
        }
    }

    int region = n0 >> 8;   // 0=Q, 1=K, 2=V (uniform per block)
    if (region < 2) {
        #pragma unroll
        for (int i = 0; i < 2; ++i) {
            int m = m0 + w*32 + i*16 + col;
            int s = m >> 2, bidx = m & 3;
            #pragma unroll
            for (int j = 0; j < 4; ++j) {
                int ng = n0 + j*16 + quad*4;
                float4 bi = *(const float4*)&bias[ng];
                ushort4 uu;
                uu.x=(unsigned short)f2bf(acc[i][j][0] + bi.x);
                uu.y=(unsigned short)f2bf(acc[i][j][1] + bi.y);
                uu.z=(unsigned short)f2bf(acc[i][j][2] + bi.z);
                uu.w=(unsigned short)f2bf(acc[i][j][3] + bi.w);
                int np = ng - (region << 8);
                int hh = np >> 5, d = np & 31;
                int bh = bidx*NHEAD + hh;
                if (region == 0)
                    *(ushort4*)(Qg + ((size_t)(bh*SEQ + s))*DH + d) = uu;
                else
                    *(ushort4*)(Kg + ((size_t)(bh*SEQ + s))*DH + d) = uu;
            }
        }
    } else {
        __syncthreads();
        unsigned short* T3 = (unsigned short*)As;   // 16 KB scratch
        #pragma unroll
        for (int i = 0; i < 2; ++i) {
            int mi = w*32 + i*16 + col;
            int ss = mi >> 2, bidx = mi & 3;
            #pragma unroll
            for (int j = 0; j < 4; ++j) {
                int ni = j*16 + quad*4;
                float4 bi = *(const float4*)&bias[n0 + ni];
                T3[((ni    )*4 + bidx)*32 + ss] = (unsigned short)f2bf(acc[i][j][0] + bi.x);
                T3[((ni + 1)*4 + bidx)*32 + ss] = (unsigned short)f2bf(acc[i][j][1] + bi.y);
                T3[((ni + 2)*4 + bidx)*32 + ss] = (unsigned short)f2bf(acc[i][j][2] + bi.z);
                T3[((ni + 3)*4 + bidx)*32 + ss] = (unsigned short)f2bf(acc[i][j][3] + bi.w);
            }
        }
        __syncthreads();
        int sBase = m0 >> 2;
        #pragma unroll
        for (int r = 0; r < 4; ++r) {
            int chunk = tid + 256*r;
            int l = chunk >> 2, p = chunk & 3;
            int d = l & 31, hh_l = (l >> 5) & 1, bidx = l >> 6;
            int ni = hh_l*32 + d;
            int hh = ((n0 & 255) + ni) >> 5;
            int bh = bidx*NHEAD + hh;
            uint4 val = *(const uint4*)&T3[(ni*4 + bidx)*32 + p*8];
            *(uint4*)(Vg + ((size_t)(bh*DH + d))*SEQ + sBase + p*8) = val;
        }
    }
}

// ------- MFMA flash attention, DUAL q-tile, KVBLK=128, 512 THREADS (8 waves) --
// Waves 0-3 own group A (q<MPOS) 16-row slices; waves 4-7 own group B.
// Per-row math identical to the 256-thread dual-tile version (bit-identical).
__global__ __launch_bounds__(512) void attn_mfma(
    const unsigned short* __restrict__ Qg,
    const unsigned short* __restrict__ Kg,
    const unsigned short* __restrict__ Vg,
    unsigned short* __restrict__ o)           // bf16 [s*B+b][256]
{
    const int id  = blockIdx.x;               // 0..511
    const int sl  = id >> 3;                  // 0..63
    const int bh  = (id & 7) * 4 + (sl >> 4); // XCD (id&7) owns bh [4x,4x+4)
    const int qt2 = sl & 15;
    const int h   = bh & 7;
    const int b   = bh >> 3;
    const int q0A = qt2 * 64;                 // low tile, q < MPOS
    const int q0B = MPOS + qt2 * 64;          // high tile, q >= MPOS
    const int tid  = threadIdx.x;
    const int w    = tid >> 6;                // 0..7
    const int ws   = w & 3;                   // slice within group
    const int grp  = w >> 2;                  // 0=A, 1=B
    const int lane = tid & 63;
    const int col  = lane & 15;
    const int quad = lane >> 4;

    __shared__ unsigned short Kt[2][128][40];   // [key][d]  20 KB
    __shared__ unsigned short Vt[2][32][136];   // [d][key]  17 KB
    __shared__ unsigned short Pt[8][16][136];   // per-wave P  34.8 KB

    const int q0 = grp ? q0B : q0A;
    const int q  = q0 + 16*ws + col;
    bf16x8 qf = *(const bf16x8*)(Qg + ((size_t)(bh*SEQ + q))*DH + quad*8);

    f32x4 O0 = {0.f,0.f,0.f,0.f};
    f32x4 O1 = {0.f,0.f,0.f,0.f};
    float lsum = 0.f;

    const int kRow = tid >> 2,  kCh = (tid & 3) * 8;    // 128 K-rows
    const int vD   = tid >> 4,  vCh = (tid & 15) * 8;   // 32 V-rows x 128 cols

    uint4 kreg = *(const uint4*)(Kg + ((size_t)(bh*SEQ + kRow))*DH + kCh);
    uint4 vreg = *(const uint4*)(Vg + ((size_t)(bh*DH + vD))*SEQ + vCh);

    for (int kt = 0; kt < 8; ++kt) {
        const int p = kt & 1;
        *(uint4*)&Kt[p][kRow][kCh] = kreg;
        *(uint4*)&Vt[p][vD][vCh]   = vreg;
        __syncthreads();
        if (kt < 7) {
            int kn = (kt + 1) * 128;
            kreg = *(const uint4*)(Kg + ((size_t)(bh*SEQ + kn + kRow))*DH + kCh);
            vreg = *(const uint4*)(Vg + ((size_t)(bh*DH + vD))*SEQ + kn + vCh);
        } else {
            // prefetch the 64-key self tile (keys [q0B, q0B+64))
            if (kRow < 64)
                kreg = *(const uint4*)(Kg + ((size_t)(bh*SEQ + q0B + kRow))*DH + kCh);
            if (vCh < 64)
                vreg = *(const uint4*)(Vg + ((size_t)(bh*DH + vD))*SEQ + q0B + vCh);
        }

        #pragma unroll
        for (int mt = 0; mt < 8; ++mt) {
            bf16x8 kf = *(const bf16x8*)&Kt[p][mt*16 + col][quad*8];
            f32x4 st = {0.f,0.f,0.f,0.f};
            st = __builtin_amdgcn_mfma_f32_16x16x32_bf16(kf, qf, st, 0, 0, 0);
            ushort4 pw;
            #pragma unroll
            for (int i = 0; i < 4; ++i) {
                float pv = __expf(st[i]*ATT_SCALE);
                unsigned short us = (unsigned short)f2bf(pv);
                ((unsigned short*)&pw)[i] = us;
                lsum += bf2f(us);
            }
            *(ushort4*)&Pt[w][col][mt*16 + quad*4] = pw;
        }
        #pragma unroll
        for (int c = 0; c < 4; ++c) {
            bf16x8 v0 = *(const bf16x8*)&Vt[p][col     ][c*32 + quad*8];
            bf16x8 v1 = *(const bf16x8*)&Vt[p][col + 16][c*32 + quad*8];
            bf16x8 pf = *(const bf16x8*)&Pt[w][col][c*32 + quad*8];
            O0 = __builtin_amdgcn_mfma_f32_16x16x32_bf16(v0, pf, O0, 0, 0, 0);
            O1 = __builtin_amdgcn_mfma_f32_16x16x32_bf16(v1, pf, O1, 0, 0, 0);
        }
    }

    // ---- self tile (group B diagonal), 64 keys, buffer 0 ----
    // Buffer 0 last read at kt=6 compute; all waves passed kt=7's barrier since.
    if (kRow < 64) *(uint4*)&Kt[0][kRow][kCh] = kreg;
    if (vCh < 64)  *(uint4*)&Vt[0][vD][vCh]   = vreg;
    __syncthreads();
    if (grp == 1) {
        #pragma unroll
        for (int mt = 0; mt < 4; ++mt) {
            bf16x8 kf = *(const bf16x8*)&Kt[0][mt*16 + col][quad*8];
            f32x4 st = {0.f,0.f,0.f,0.f};
            st = __builtin_amdgcn_mfma_f32_16x16x32_bf16(kf, qf, st, 0, 0, 0);
            ushort4 pw;
            #pragma unroll
            for (int i = 0; i < 4; ++i) {
                float pv = __expf(st[i]*ATT_SCALE);
                if (mt*16 + quad*4 + i != 16*ws + col) pv = 0.f;
                unsigned short us = (unsigned short)f2bf(pv);
                ((unsigned short*)&pw)[i] = us;
                lsum += bf2f(us);
            }
            *(ushort4*)&Pt[w][col][mt*16 + quad*4] = pw;
        }
        #pragma unroll
        for (int c = 0; c < 2; ++c) {
            bf16x8 v0 = *(const bf16x8*)&Vt[0][col     ][c*32 + quad*8];
            bf16x8 v1 = *(const bf16x8*)&Vt[0][col + 16][c*32 + quad*8];
            bf16x8 pf = *(const bf16x8*)&Pt[w][col][c*32 + quad*8];
            O0 = __builtin_amdgcn_mfma_f32_16x16x32_bf16(v0, pf, O0, 0, 0, 0);
            O1 = __builtin_amdgcn_mfma_f32_16x16x32_bf16(v1, pf, O1, 0, 0, 0);
        }
    }

    lsum += __shfl_xor(lsum, 16, 64);
    lsum += __shfl_xor(lsum, 32, 64);
    float inv = 1.0f / lsum;
    ushort4 u0, u1;
    #pragma unroll
    for (int i = 0; i < 4; ++i) {
        ((unsigned short*)&u0)[i] = (unsigned short)f2bf(O0[i]*inv);
        ((unsigned short*)&u1)[i] = (unsigned short)f2bf(O1[i]*inv);
    }
    unsigned short* op = o + ((size_t)(q*BATCH + b))*DMODEL + h*DH;
    *(ushort4*)(op + quad*4)      = u0;
    *(ushort4*)(op + 16 + quad*4) = u1;
}

// ------- fused MLP, TWO 16-row groups, BK=64, 512 THREADS (8 waves) -----------
__global__ __launch_bounds__(512) void mlp_fused(
    const unsigned short* __restrict__ attb,
    const unsigned short* __restrict__ Wout, const float* __restrict__ ob,
    const float* __restrict__ g1, const float* __restrict__ be1,
    const unsigned short* __restrict__ W1, const float* __restrict__ fb1,
    const unsigned short* __restrict__ W2, const float* __restrict__ fb2,
    const float* __restrict__ g2, const float* __restrict__ be2,
    float* __restrict__ h, unsigned short* __restrict__ hb,
    const unsigned short* __restrict__ Wh1, const float* __restrict__ hb1,
    const float* __restrict__ hw2, const float* __restrict__ hb2,
    float* __restrict__ out, int doHead)
{
    __shared__ unsigned short Bs[3][256][64];         // 96 KB weight staging
    __shared__ __align__(16) unsigned char smem_u[33280];  // As (12 KB) / Pt (32.5 KB)
    __shared__ unsigned short Ht[2][16][264];         // LN1-out / LN2-out bf16
    __shared__ float sP[2][8][16], qP[2][8][16];

    typedef unsigned short AsT[2][16][64];
    AsT* As = reinterpret_cast<AsT*>(smem_u);
    typedef unsigned short PtT[16][520];
    PtT* Pt = reinterpret_cast<PtT*>(smem_u);

    const int tid  = threadIdx.x;
    const int w    = tid >> 6;            // 0..7
    const int lane = tid & 63;
    const int col  = lane & 15;
    const int quad = lane >> 4;
    const int l8   = lane >> 3;
    const int c8s  = (((lane & 7) ^ l8) * 8);
    const int bid  = blockIdx.x;
    const int m0a  = bid * 16;
    const int m0b  = 4096 + bid * 16;
    const int ma   = m0a + col;
    const int mb   = m0b + col;

    float resid[2][2][4];

    // ================= stage A: out-proj (K=256, NS=4) + residual + LN1 =======
    {
        f32x4 acc[2][2];
        #pragma unroll
        for (int g = 0; g < 2; ++g)
            #pragma unroll
            for (int j = 0; j < 2; ++j) acc[g][j] = (f32x4){0.f,0.f,0.f,0.f};

        const int gr = w >> 1;            // waves 0-3 stage As: group gr, half w&1
        const unsigned short* gaw = attb + (size_t)((gr ? m0b : m0a) + (w&1)*8 + l8)*DMODEL + c8s;
        const unsigned short* gb  = Wout + (size_t)(w*32 + l8)*DMODEL + c8s;
        const int NS = DMODEL / 64;  // 4

        #pragma unroll
        for (int pb = 0; pb < 2; ++pb) {
            int k = pb * 64;
            if (w < 4) gload16(gaw + k, &As[pb][gr][(w&1)*8][0]);
            #pragma unroll
            for (int t = 0; t < 4; ++t)
                gload16(gb + k + (size_t)(t*8)*DMODEL, &Bs[pb][w*32 + t*8][0]);
        }
        int bcur = 0;
        for (int s = 0; s < NS; ++s) {
            if (s == NS - 1)      { VMWAIT(0); }
            else if (w < 4)       { VMWAIT(5); }
            else                  { VMWAIT(4); }
            pipe_barrier();
            if (s + 2 < NS) {
                int bpre = bcur + 2; if (bpre >= 3) bpre -= 3;
                int k2 = (s + 2) * 64;
                if (w < 4) gload16(gaw + k2, &As[bpre][gr][(w&1)*8][0]);
                #pragma unroll
                for (int t = 0; t < 4; ++t)
                    gload16(gb + k2 + (size_t)(t*8)*DMODEL, &Bs[bpre][w*32 + t*8][0]);
            }
            #pragma unroll
            for (int kk = 0; kk < 2; ++kk) {
                const int so = (((kk*4 + quad) ^ (col & 7)) * 8);
                bf16x8 af0 = *(const bf16x8*)&As[bcur][0][col][so];
                bf16x8 af1 = *(const bf16x8*)&As[bcur][1][col][so];
                #pragma unroll
                for (int j = 0; j < 2; ++j) {
                    bf16x8 bfr = *(const bf16x8*)&Bs[bcur][w*32 + j*16 + col][so];
                    acc[0][j] = __builtin_amdgcn_mfma_f32_16x16x32_bf16(bfr, af0, acc[0][j], 0, 0, 0);
                    acc[1][j] = __builtin_amdgcn_mfma_f32_16x16x32_bf16(bfr, af1, acc[1][j], 0, 0, 0);
                }
            }
            bcur = (bcur == 2) ? 0 : bcur + 1;
        }

        float ssum[2] = {0.f, 0.f}, qsum[2] = {0.f, 0.f};
        #pragma unroll
        for (int g = 0; g < 2; ++g) {
            int m = g ? mb : ma;
            #pragma unroll
            for (int j = 0; j < 2; ++j) {
                int n = w*32 + j*16 + quad*4;
                float4 bi = *(const float4*)&ob[n];
                float4 hv = *(const float4*)&h[(size_t)m*DMODEL + n];
                #pragma unroll
                for (int i = 0; i < 4; ++i) {
                    float val = acc[g][j][i] + ((const float*)&bi)[i] + ((const float*)&hv)[i];
                    resid[g][j][i] = val;
                    ssum[g] += val; qsum[g] += val*val;
                }
            }
        }
        #pragma unroll
        for (int g = 0; g < 2; ++g) {
            ssum[g] += __shfl_xor(ssum[g], 16, 64); ssum[g] += __shfl_xor(ssum[g], 32, 64);
            qsum[g] += __shfl_xor(qsum[g], 16, 64); qsum[g] += __shfl_xor(qsum[g], 32, 64);
        }
        if (quad == 0) {
            sP[0][w][col] = ssum[0]; qP[0][w][col] = qsum[0];
            sP[1][w][col] = ssum[1]; qP[1][w][col] = qsum[1];
        }
        __syncthreads();
        #pragma unroll
        for (int g = 0; g < 2; ++g) {
            float st = 0.f, qt = 0.f;
            #pragma unroll
            for (int ww = 0; ww < 8; ++ww) { st += sP[g][ww][col]; qt += qP[g][ww][col]; }
            float mu   = st * (1.0f/DMODEL);
            float var  = qt * (1.0f/DMODEL) - mu*mu;
            float rstd = rsqrtf(var + 1e-5f);
            #pragma unroll
            for (int j = 0; j < 2; ++j) {
                int n = w*32 + j*16 + quad*4;
                float4 gv = *(const float4*)&g1[n];
                float4 bv = *(const float4*)&be1[n];
                ushort4 u;
                #pragma unroll
                for (int i = 0; i < 4; ++i) {
                    float o = (resid[g][j][i]-mu)*rstd*((const float*)&gv)[i] + ((const float*)&bv)[i];
                    resid[g][j][i] = o;
                    ((unsigned short*)&u)[i] = (unsigned short)f2bf(o);
                }
                *(ushort4*)&Ht[g][col][n] = u;
            }
        }
        __syncthreads();   // Ht visible; all waves past As/Bs reads
    }

    // ================= stage B: ff1 (K=256 NS=4, two N-halves) + gelu =========
    #pragma unroll 1
    for (int nh = 0; nh < 2; ++nh) {
        f32x4 acc[2][2];
        #pragma unroll
        for (int g = 0; g < 2; ++g)
            #pragma unroll
            for (int j = 0; j < 2; ++j) acc[g][j] = (f32x4){0.f,0.f,0.f,0.f};
        const unsigned short* gb = W1 + (size_t)(nh*256 + w*32 + l8)*DMODEL + c8s;
        const int NS = DMODEL / 64;  // 4

        #pragma unroll
        for (int pb = 0; pb < 2; ++pb)
            #pragma unroll
            for (int t = 0; t < 4; ++t)
                gload16(gb + pb*64 + (size_t)(t*8)*DMODEL, &Bs[pb][w*32 + t*8][0]);

        int bcur = 0;
        for (int s = 0; s < NS; ++s) {
            if (s == NS - 1) { VMWAIT(0); } else { VMWAIT(4); }
            pipe_barrier();
            if (s + 2 < NS) {
                int bpre = bcur + 2; if (bpre >= 3) bpre -= 3;
                int k2 = (s + 2) * 64;
                #pragma unroll
                for (int t = 0; t < 4; ++t)
                    gload16(gb + k2 + (size_t)(t*8)*DMODEL, &Bs[bpre][w*32 + t*8][0]);
            }
            #pragma unroll
            for (int kk = 0; kk < 2; ++kk) {
                const int so = (((kk*4 + quad) ^ (col & 7)) * 8);
                bf16x8 af0 = *(const bf16x8*)&Ht[0][col][s*64 + kk*32 + quad*8];
                bf16x8 af1 = *(const bf16x8*)&Ht[1][col][s*64 + kk*32 + quad*8];
                #pragma unroll
                for (int j = 0; j < 2; ++j) {
                    bf16x8 bfr = *(const bf16x8*)&Bs[bcur][w*32 + j*16 + col][so];
                    acc[0][j] = __builtin_amdgcn_mfma_f32_16x16x32_bf16(bfr, af0, acc[0][j], 0, 0, 0);
                    acc[1][j] = __builtin_amdgcn_mfma_f32_16x16x32_bf16(bfr, af1, acc[1][j], 0, 0, 0);
                }
            }
            bcur = (bcur == 2) ? 0 : bcur + 1;
        }
        #pragma unroll
        for (int g = 0; g < 2; ++g)
            #pragma unroll
            for (int j = 0; j < 2; ++j) {
                int n2 = nh*256 + w*32 + j*16 + quad*4;
                float4 bi = *(const float4*)&fb1[n2];
                ushort4 u;
                #pragma unroll
                for (int i = 0; i < 4; ++i)
                    ((unsigned short*)&u)[i] = (unsigned short)f2bf(gelu_exact(acc[g][j][i] + ((const float*)&bi)[i]));
                *(ushort4*)&Pt[g][col][n2] = u;
            }
        pipe_barrier();   // all waves past Bs reads before next half's staging
    }

    // ================= stage C: ff2 (K=512 NS=8) + residual + LN2 =============
    {
        __syncthreads();  // Pt visible
        f32x4 acc[2][2];
        #pragma unroll
        for (int g = 0; g < 2; ++g)
            #pragma unroll
            for (int j = 0; j < 2; ++j) acc[g][j] = (f32x4){0.f,0.f,0.f,0.f};
        const unsigned short* gb = W2 + (size_t)(w*32 + l8)*DFF + c8s;
        const int NS = DFF / 64;  // 8

        #pragma unroll
        for (int pb = 0; pb < 2; ++pb)
            #pragma unroll
            for (int t = 0; t < 4; ++t)
                gload16(gb + pb*64 + (size_t)(t*8)*DFF, &Bs[pb][w*32 + t*8][0]);

        int bcur = 0;
        for (int s = 0; s < NS; ++s) {
            if (s == NS - 1) { VMWAIT(0); } else { VMWAIT(4); }
            pipe_barrier();
            if (s + 2 < NS) {
                int bpre = bcur + 2; if (bpre >= 3) bpre -= 3;
                int k2 = (s + 2) * 64;
                #pragma unroll
                for (int t = 0; t < 4; ++t)
                    gload16(gb + k2 + (size_t)(t*8)*DFF, &Bs[bpre][w*32 + t*8][0]);
            }
            #pragma unroll
            for (int kk = 0; kk < 2; ++kk) {
                const int so = (((kk*4 + quad) ^ (col & 7)) * 8);
                bf16x8 af0 = *(const bf16x8*)&Pt[0][col][s*64 + kk*32 + quad*8];
                bf16x8 af1 = *(const bf16x8*)&Pt[1][col][s*64 + kk*32 + quad*8];
                #pragma unroll
                for (int j = 0; j < 2; ++j) {
                    bf16x8 bfr = *(const bf16x8*)&Bs[bcur][w*32 + j*16 + col][so];
                    acc[0][j] = __builtin_amdgcn_mfma_f32_16x16x32_bf16(bfr, af0, acc[0][j], 0, 0, 0);
                    acc[1][j] = __builtin_amdgcn_mfma_f32_16x16x32_bf16(bfr, af1, acc[1][j], 0, 0, 0);
                }
            }
            bcur = (bcur == 2) ? 0 : bcur + 1;
        }

        float ssum[2] = {0.f, 0.f}, qsum[2] = {0.f, 0.f};
        #pragma unroll
        for (int g = 0; g < 2; ++g)
            #pragma unroll
            for (int j = 0; j < 2; ++j) {
                int n = w*32 + j*16 + quad*4;
                float4 bi = *(const float4*)&fb2[n];
                #pragma unroll
                for (int i = 0; i < 4; ++i) {
                    float val = acc[g][j][i] + ((const float*)&bi)[i] + resid[g][j][i];
                    resid[g][j][i] = val;
                    ssum[g] += val; qsum[g] += val*val;
                }
            }
        #pragma unroll
        for (int g = 0; g < 2; ++g) {
            ssum[g] += __shfl_xor(ssum[g], 16, 64); ssum[g] += __shfl_xor(ssum[g], 32, 64);
            qsum[g] += __shfl_xor(qsum[g], 16, 64); qsum[g] += __shfl_xor(qsum[g], 32, 64);
        }
        if (quad == 0) {
            sP[0][w][col] = ssum[0]; qP[0][w][col] = qsum[0];
            sP[1][w][col] = ssum[1]; qP[1][w][col] = qsum[1];
        }
        __syncthreads();
        #pragma unroll
        for (int g = 0; g < 2; ++g) {
            int m = g ? mb : ma;
            float st = 0.f, qt = 0.f;
            #pragma unroll
            for (int ww = 0; ww < 8; ++ww) { st += sP[g][ww][col]; qt += qP[g][ww][col]; }
            float mu   = st * (1.0f/DMODEL);
            float var  = qt * (1.0f/DMODEL) - mu*mu;
            float rstd = rsqrtf(var + 1e-5f);
            #pragma unroll
            for (int j = 0; j < 2; ++j) {
                int n = w*32 + j*16 + quad*4;
                float4 gv = *(const float4*)&g2[n];
                float4 bv = *(const float4*)&be2[n];
                float4 o;
                ushort4 u;
                #pragma unroll
                for (int i = 0; i < 4; ++i) {
                    float ov = (resid[g][j][i]-mu)*rstd*((const float*)&gv)[i] + ((const float*)&bv)[i];
                    ((float*)&o)[i] = ov;
                    ((unsigned short*)&u)[i] = (unsigned short)f2bf(ov);
                }
                *(float4*)&h[(size_t)m*DMODEL + n] = o;
                *(ushort4*)(hb + (size_t)m*DMODEL + n) = u;
                *(ushort4*)&Ht[g][col][n] = u;   // LN2 bf16 for head
            }
        }
        __syncthreads();
    }

    // ================= stage D: head (layer 1; 16 head rows per block) ========
    if (doHead) {
        float sdot = 0.f;
        #pragma unroll 1
        for (int nh = 0; nh < 2; ++nh) {
            f32x4 acc[2];
            #pragma unroll
            for (int j = 0; j < 2; ++j) acc[j] = (f32x4){0.f,0.f,0.f,0.f};
            const unsigned short* gb = Wh1 + (size_t)(nh*256 + w*32 + l8)*DMODEL + c8s;
            const int NS = DMODEL / 64;  // 4

            #pragma unroll
            for (int pb = 0; pb < 2; ++pb)
                #pragma unroll
                for (int t = 0; t < 4; ++t)
                    gload16(gb + pb*64 + (size_t)(t*8)*DMODEL, &Bs[pb][w*32 + t*8][0]);

            int bcur = 0;
            for (int s = 0; s < NS; ++s) {
                if (s == NS - 1) { VMWAIT(0); } else { VMWAIT(4); }
                pipe_barrier();
                if (s + 2 < NS) {
                    int bpre = bcur + 2; if (bpre >= 3) bpre -= 3;
                    int k2 = (s + 2) * 64;
                    #pragma unroll
                    for (int t = 0; t < 4; ++t)
                        gload16(gb + k2 + (size_t)(t*8)*DMODEL, &Bs[bpre][w*32 + t*8][0]);
                }
                #pragma unroll
                for (int kk = 0; kk < 2; ++kk) {
                    const int so = (((kk*4 + quad) ^ (col & 7)) * 8);
                    bf16x8 af = *(const bf16x8*)&Ht[1][col][s*64 + kk*32 + quad*8];
                    #pragma unroll
                    for (int j = 0; j < 2; ++j) {
                        bf16x8 bfr = *(const bf16x8*)&Bs[bcur][w*32 + j*16 + col][so];
                        acc[j] = __builtin_amdgcn_mfma_f32_16x16x32_bf16(bfr, af, acc[j], 0, 0, 0);
                    }
                }
                bcur = (bcur == 2) ? 0 : bcur + 1;
            }
            #pragma unroll
            for (int j = 0; j < 2; ++j) {
                int n2 = nh*256 + w*32 + j*16 + quad*4;
                float4 b1v = *(const float4*)&hb1[n2];
                float4 w2v = *(const float4*)&hw2[n2];
                #pragma unroll
                for (int i = 0; i < 4; ++i)
                    sdot += gelu_exact(acc[j][i] + ((const float*)&b1v)[i]) * ((const float*)&w2v)[i];
            }
            pipe_barrier();
        }
        sdot += __shfl_xor(sdot, 16, 64); sdot += __shfl_xor(sdot, 32, 64);
        if (quad == 0) sP[0][w][col] = sdot;
        __syncthreads();
        if (tid < 16) {
            float r = hb2[0];
            #pragma unroll
            for (int ww = 0; ww < 8; ++ww) r += sP[0][ww][tid];
            out[bid*16 + tid] = r;
        }
    }
}

extern "C" void kernel_launch(void* const* d_in, const int* in_sizes, int n_in,
                              void* d_out, int out_size, void* d_ws, size_t ws_size,
                              hipStream_t stream)
{
    const float* x        = (const float*)d_in[0];
    const float* y        = (const float*)d_in[1];
    const float* xenc_w   = (const float*)d_in[3];
    const float* xenc_b   = (const float*)d_in[4];
    const float* yenc_w   = (const float*)d_in[5];
    const float* yenc_b   = (const float*)d_in[6];
    const float* in_proj_w  = (const float*)d_in[7];
    const float* in_proj_b  = (const float*)d_in[8];
    const float* out_proj_w = (const float*)d_in[9];
    const float* out_proj_b = (const float*)d_in[10];
    const float* ln1_g    = (const float*)d_in[11];
    const float* ln1_b    = (const float*)d_in[12];
    const float* lin1_w   = (const float*)d_in[13];
    const float* lin1_b   = (const float*)d_in[14];
    const float* lin2_w   = (const float*)d_in[15];
    const float* lin2_b   = (const float*)d_in[16];
    const float* ln2_g    = (const float*)d_in[17];
    const float* ln2_b    = (const float*)d_in[18];
    const float* head_w1  = (const float*)d_in[19];
    const float* head_b1  = (const float*)d_in[20];
    const float* head_w2  = (const float*)d_in[21];
    const float* head_b2  = (const float*)d_in[22];
    float* out = (float*)d_out;

    // ---- workspace layout ----
    float* ws  = (float*)d_ws;
    float* h    = ws;
    unsigned short* hb    = (unsigned short*)(h + (size_t)ROWS*DMODEL);
    unsigned short* attb  = hb    + (size_t)ROWS*DMODEL;
    unsigned short* Qg    = attb  + (size_t)ROWS*DMODEL;
    unsigned short* Kg    = Qg    + (size_t)BATCH*NHEAD*SEQ*DH;
    unsigned short* Vg    = Kg    + (size_t)BATCH*NHEAD*SEQ*DH;
    unsigned short* Wqkv  = Vg    + (size_t)BATCH*NHEAD*SEQ*DH;
    unsigned short* Wout  = Wqkv  + (size_t)NLAYER*3*DMODEL*DMODEL;
    unsigned short* Wl1   = Wout  + (size_t)NLAYER*DMODEL*DMODEL;
    unsigned short* Wl2   = Wl1   + (size_t)NLAYER*DFF*DMODEL;
    unsigned short* Wh1   = Wl2   + (size_t)NLAYER*DMODEL*DFF;

    encode_cast<<<ROWS/4 + 576, 256, 0, stream>>>(
        x, y, xenc_w, xenc_b, yenc_w, yenc_b, h, hb,
        in_proj_w, out_proj_w, lin1_w, lin2_w, head_w1,
        Wqkv, Wout, Wl1, Wl2, Wh1);

    for (int l = 0; l < NLAYER; ++l) {
        gemm_qkv<<<768, 256, 0, stream>>>(
            hb, Wqkv + (size_t)l*3*DMODEL*DMODEL, in_proj_b + l*3*DMODEL,
            Qg, Kg, Vg, DMODEL);
        attn_mfma<<<512, 512, 0, stream>>>(Qg, Kg, Vg, attb);
        mlp_fused<<<256, 512, 0, stream>>>(
            attb,
            Wout + (size_t)l*DMODEL*DMODEL, out_proj_b + l*DMODEL,
            ln1_g + l*DMODEL, ln1_b + l*DMODEL,
            Wl1 + (size_t)l*DFF*DMODEL, lin1_b + l*DFF,
            Wl2 + (size_t)l*DMODEL*DFF, lin2_b + l*DMODEL,
            ln2_g + l*DMODEL, ln2_b + l*DMODEL,
            h, hb,
            Wh1, head_b1, head_w2, head_b2,
            out, (l == NLAYER-1) ? 1 : 0);
    }
}

// Round 16
// 225.379 us; speedup vs baseline: 1.1077x; 1.0039x over previous
//
#include <hip/hip_runtime.h>
#include <hip/hip_bf16.h>
#include <math.h>

// Problem constants (fixed by setup_inputs)
#define SEQ    2048
#define BATCH  4
#define XDIM   16
#define DMODEL 256
#define NHEAD  8
#define DH     32
#define DFF    512
#define NLAYER 2
#define MPOS   1024
#define ROWS   (SEQ*BATCH)   // 8192

#define ATT_SCALE 0.17677669529663687f  // 1/sqrt(32)

typedef __attribute__((ext_vector_type(8))) short bf16x8;  // MFMA A/B frag
typedef __attribute__((ext_vector_type(4))) float f32x4;   // MFMA C/D frag

__device__ __forceinline__ float gelu_exact(float x) {
    return 0.5f * x * (1.0f + erff(x * 0.70710678118654752f));
}
__device__ __forceinline__ short f2bf(float f) {
    unsigned int u = __float_as_uint(f);
    u += 0x7FFFu + ((u >> 16) & 1u);
    return (short)(u >> 16);
}
__device__ __forceinline__ float bf2f(unsigned short u) {
    return __uint_as_float(((unsigned int)u) << 16);
}
__device__ __forceinline__ void gload16(const unsigned short* g, unsigned short* l) {
    __builtin_amdgcn_global_load_lds(
        (const __attribute__((address_space(1))) unsigned int*)g,
        (__attribute__((address_space(3))) unsigned int*)l, 16, 0, 0);
}
#define VMWAIT(N) asm volatile("s_waitcnt vmcnt(" #N ")" ::: "memory")
__device__ __forceinline__ void pipe_barrier() {
    __builtin_amdgcn_sched_barrier(0);
    __builtin_amdgcn_s_barrier();
    __builtin_amdgcn_sched_barrier(0);
}

// ---------------- encoder (4 rows/block) + weight casts, ONE launch -----------
__global__ __launch_bounds__(256) void encode_cast(
    const float* __restrict__ x, const float* __restrict__ y,
    const float* __restrict__ xw, const float* __restrict__ xb,
    const float* __restrict__ yw, const float* __restrict__ yb,
    float* __restrict__ h, unsigned short* __restrict__ hb,
    const float* __restrict__ s0, const float* __restrict__ s1,
    const float* __restrict__ s2, const float* __restrict__ s3,
    const float* __restrict__ s4,
    unsigned short* __restrict__ d0, unsigned short* __restrict__ d1,
    unsigned short* __restrict__ d2, unsigned short* __restrict__ d3,
    unsigned short* __restrict__ d4)
{
    if (blockIdx.x < ROWS/4) {
        int g = blockIdx.x;        // token index s (4 batch rows share it)
        int d = threadIdx.x;       // 0..255
        __shared__ float xs[4][XDIM];
        __shared__ float ys[4];
        if (d < 64) xs[d>>4][d&15] = x[(size_t)(g*4 + (d>>4))*XDIM + (d&15)];
        if (d < 4)  ys[d] = y[g*4 + d];
        __syncthreads();
        float wreg[XDIM];
        #pragma unroll
        for (int k = 0; k < XDIM; ++k) wreg[k] = xw[d*XDIM + k];
        const float xbv = xb[d], ywv = yw[d], ybv = yb[d];
        const bool train = (g < MPOS);
        #pragma unroll
        for (int r = 0; r < 4; ++r) {
            int row = g*4 + r;
            float acc = xbv;
            #pragma unroll
            for (int k = 0; k < XDIM; ++k) acc = fmaf(xs[r][k], wreg[k], acc);
            if (train) acc += ys[r]*ywv + ybv;
            h[(size_t)row*DMODEL + d]  = acc;
            hb[(size_t)row*DMODEL + d] = (unsigned short)f2bf(acc);
        }
        return;
    }
    int i = (blockIdx.x - ROWS/4)*256 + threadIdx.x;
    if (i >= 147456) return;
    const float* s; unsigned short* d; int off;
    if      (i <  49152) { s = s0; d = d0; off = i; }
    else if (i <  65536) { s = s1; d = d1; off = i - 49152; }
    else if (i <  98304) { s = s2; d = d2; off = i - 65536; }
    else if (i < 131072) { s = s3; d = d3; off = i - 98304; }
    else                 { s = s4; d = d4; off = i - 131072; }
    float4 a = *(const float4*)(s + (size_t)off*8);
    float4 c = *(const float4*)(s + (size_t)off*8 + 4);
    ushort4 u0, u1;
    u0.x=(unsigned short)f2bf(a.x); u0.y=(unsigned short)f2bf(a.y);
    u0.z=(unsigned short)f2bf(a.z); u0.w=(unsigned short)f2bf(a.w);
    u1.x=(unsigned short)f2bf(c.x); u1.y=(unsigned short)f2bf(c.y);
    u1.z=(unsigned short)f2bf(c.z); u1.w=(unsigned short)f2bf(c.w);
    *(ushort4*)(d + (size_t)off*8)     = u0;
    *(ushort4*)(d + (size_t)off*8 + 4) = u1;
}

// ------- qkv GEMM 128x64, BK=64 (NS=4), 512 THREADS (8 waves), XCD-local A ---
// Same tile/grid/LDS as the 256-thread version; wave w owns the 32x32 quadrant
// (rows (w>>1)*32, cols (w&1)*32). 6 waves/SIMD hide the vmcnt/barrier stalls.
// Staging uniform: 2 As-gloads + 1 Bs-gload per wave per batch. Bit-identical.
__global__ __launch_bounds__(512) void gemm_qkv(
    const unsigned short* __restrict__ A, const unsigned short* __restrict__ B,
    const float* __restrict__ bias,
    unsigned short* __restrict__ Qg, unsigned short* __restrict__ Kg,
    unsigned short* __restrict__ Vg, int K)
{
    __shared__ unsigned short As[2][128][64];   // 32 KB (reused as transpose buf)
    __shared__ unsigned short Bs[2][64][64];    // 16 KB
    int tid  = threadIdx.x;
    int w    = tid >> 6, lane = tid & 63;
    int col  = lane & 15, quad = lane >> 4;
    int wr   = w >> 1, wc = w & 1;
    int u    = blockIdx.x >> 3, xcd = blockIdx.x & 7;
    int by   = xcd*8 + u/12, bx = u%12;
    int m0   = by * 128, n0 = bx * 64;
    int l8   = lane >> 3;
    int c8s  = (((lane & 7) ^ l8) * 8);

    f32x4 acc[2][2];
    #pragma unroll
    for (int i = 0; i < 2; ++i)
        #pragma unroll
        for (int j = 0; j < 2; ++j) acc[i][j] = (f32x4){0.f,0.f,0.f,0.f};

    const unsigned short* ga = A + (size_t)(m0 + w*16 + l8)*K + c8s;
    const unsigned short* gb = B + (size_t)(n0 + w*8  + l8)*K + c8s;
    const int NS = K / 64;  // 4

    gload16(ga,                 &As[0][w*16    ][0]);
    gload16(ga + (size_t)8*K,   &As[0][w*16 + 8][0]);
    gload16(gb,                 &Bs[0][w*8     ][0]);

    for (int s = 0; s < NS; ++s) {
        VMWAIT(0);
        pipe_barrier();
        if (s + 1 < NS) {
            int k2 = (s + 1) * 64;
            int nb = (s + 1) & 1;
            gload16(ga + k2,               &As[nb][w*16    ][0]);
            gload16(ga + k2 + (size_t)8*K, &As[nb][w*16 + 8][0]);
            gload16(gb + k2,               &Bs[nb][w*8     ][0]);
        }
        int cur = s & 1;
        #pragma unroll
        for (int kk = 0; kk < 2; ++kk) {
            const int so = (((kk*4 + quad) ^ (col & 7)) * 8);
            bf16x8 af[2], bfr[2];
            #pragma unroll
            for (int i = 0; i < 2; ++i) af[i]  = *(const bf16x8*)&As[cur][wr*32 + i*16 + col][so];
            #pragma unroll
            for (int j = 0; j < 2; ++j) bfr[j] = *(const bf16x8*)&Bs[cur][wc*32 + j*16 + col][so];
            #pragma unroll
            for (int i = 0; i < 2; ++i)
                #pragma unroll
                for (int j = 0; j < 2; ++j)
                    acc[i][j] = __builtin_amdgcn_mfma_f32_16x16x32_bf16(bfr[j], af[i], acc[i][j], 0, 0, 0);
        }
    }

    int region = n0 >> 8;   // 0=Q, 1=K, 2=V (uniform per block)
    if (region < 2) {
        #pragma unroll
        for (int i = 0; i < 2; ++i) {
            int m = m0 + wr*32 + i*16 + col;
            int s = m >> 2, bidx = m & 3;
            #pragma unroll
            for (int j = 0; j < 2; ++j) {
                int ng = n0 + wc*32 + j*16 + quad*4;
                float4 bi = *(const float4*)&bias[ng];
                ushort4 uu;
                uu.x=(unsigned short)f2bf(acc[i][j][0] + bi.x);
                uu.y=(unsigned short)f2bf(acc[i][j][1] + bi.y);
                uu.z=(unsigned short)f2bf(acc[i][j][2] + bi.z);
                uu.w=(unsigned short)f2bf(acc[i][j][3] + bi.w);
                int np = ng - (region << 8);
                int hh = np >> 5, d = np & 31;
                int bh = bidx*NHEAD + hh;
                if (region == 0)
                    *(ushort4*)(Qg + ((size_t)(bh*SEQ + s))*DH + d) = uu;
                else
                    *(ushort4*)(Kg + ((size_t)(bh*SEQ + s))*DH + d) = uu;
            }
        }
    } else {
        __syncthreads();
        unsigned short* T3 = (unsigned short*)As;   // 16 KB scratch
        #pragma unroll
        for (int i = 0; i < 2; ++i) {
            int mi = wr*32 + i*16 + col;
            int ss = mi >> 2, bidx = mi & 3;
            #pragma unroll
            for (int j = 0; j < 2; ++j) {
                int ni = wc*32 + j*16 + quad*4;
                float4 bi = *(const float4*)&bias[n0 + ni];
                T3[((ni    )*4 + bidx)*32 + ss] = (unsigned short)f2bf(acc[i][j][0] + bi.x);
                T3[((ni + 1)*4 + bidx)*32 + ss] = (unsigned short)f2bf(acc[i][j][1] + bi.y);
                T3[((ni + 2)*4 + bidx)*32 + ss] = (unsigned short)f2bf(acc[i][j][2] + bi.z);
                T3[((ni + 3)*4 + bidx)*32 + ss] = (unsigned short)f2bf(acc[i][j][3] + bi.w);
            }
        }
        __syncthreads();
        int sBase = m0 >> 2;
        #pragma unroll
        for (int r = 0; r < 2; ++r) {
            int chunk = tid + 512*r;
            int l = chunk >> 2, p = chunk & 3;
            int d = l & 31, hh_l = (l >> 5) & 1, bidx = l >> 6;
            int ni = hh_l*32 + d;
            int hh = ((n0 & 255) + ni) >> 5;
            int bh = bidx*NHEAD + hh;
            uint4 val = *(const uint4*)&T3[(ni*4 + bidx)*32 + p*8];
            *(uint4*)(Vg + ((size_t)(bh*DH + d))*SEQ + sBase + p*8) = val;
        }
    }
}

// ------- MFMA flash attention, DUAL q-tile, KVBLK=128, 512 THREADS (8 waves) --
__global__ __launch_bounds__(512) void attn_mfma(
    const unsigned short* __restrict__ Qg,
    const unsigned short* __restrict__ Kg,
    const unsigned short* __restrict__ Vg,
    unsigned short* __restrict__ o)           // bf16 [s*B+b][256]
{
    const int id  = blockIdx.x;               // 0..511
    const int sl  = id >> 3;                  // 0..63
    const int bh  = (id & 7) * 4 + (sl >> 4); // XCD (id&7) owns bh [4x,4x+4)
    const int qt2 = sl & 15;
    const int h   = bh & 7;
    const int b   = bh >> 3;
    const int q0A = qt2 * 64;                 // low tile, q < MPOS
    const int q0B = MPOS + qt2 * 64;          // high tile, q >= MPOS
    const int tid  = threadIdx.x;
    const int w    = tid >> 6;                // 0..7
    const int ws   = w & 3;                   // slice within group
    const int grp  = w >> 2;                  // 0=A, 1=B
    const int lane = tid & 63;
    const int col  = lane & 15;
    const int quad = lane >> 4;

    __shared__ unsigned short Kt[2][128][40];   // [key][d]  20 KB
    __shared__ unsigned short Vt[2][32][136];   // [d][key]  17 KB
    __shared__ unsigned short Pt[8][16][136];   // per-wave P  34.8 KB

    const int q0 = grp ? q0B : q0A;
    const int q  = q0 + 16*ws + col;
    bf16x8 qf = *(const bf16x8*)(Qg + ((size_t)(bh*SEQ + q))*DH + quad*8);

    f32x4 O0 = {0.f,0.f,0.f,0.f};
    f32x4 O1 = {0.f,0.f,0.f,0.f};
    float lsum = 0.f;

    const int kRow = tid >> 2,  kCh = (tid & 3) * 8;    // 128 K-rows
    const int vD   = tid >> 4,  vCh = (tid & 15) * 8;   // 32 V-rows x 128 cols

    uint4 kreg = *(const uint4*)(Kg + ((size_t)(bh*SEQ + kRow))*DH + kCh);
    uint4 vreg = *(const uint4*)(Vg + ((size_t)(bh*DH + vD))*SEQ + vCh);

    for (int kt = 0; kt < 8; ++kt) {
        const int p = kt & 1;
        *(uint4*)&Kt[p][kRow][kCh] = kreg;
        *(uint4*)&Vt[p][vD][vCh]   = vreg;
        __syncthreads();
        if (kt < 7) {
            int kn = (kt + 1) * 128;
            kreg = *(const uint4*)(Kg + ((size_t)(bh*SEQ + kn + kRow))*DH + kCh);
            vreg = *(const uint4*)(Vg + ((size_t)(bh*DH + vD))*SEQ + kn + vCh);
        } else {
            // prefetch the 64-key self tile (keys [q0B, q0B+64))
            if (kRow < 64)
                kreg = *(const uint4*)(Kg + ((size_t)(bh*SEQ + q0B + kRow))*DH + kCh);
            if (vCh < 64)
                vreg = *(const uint4*)(Vg + ((size_t)(bh*DH + vD))*SEQ + q0B + vCh);
        }

        #pragma unroll
        for (int mt = 0; mt < 8; ++mt) {
            bf16x8 kf = *(const bf16x8*)&Kt[p][mt*16 + col][quad*8];
            f32x4 st = {0.f,0.f,0.f,0.f};
            st = __builtin_amdgcn_mfma_f32_16x16x32_bf16(kf, qf, st, 0, 0, 0);
            ushort4 pw;
            #pragma unroll
            for (int i = 0; i < 4; ++i) {
                float pv = __expf(st[i]*ATT_SCALE);
                unsigned short us = (unsigned short)f2bf(pv);
                ((unsigned short*)&pw)[i] = us;
                lsum += bf2f(us);
            }
            *(ushort4*)&Pt[w][col][mt*16 + quad*4] = pw;
        }
        #pragma unroll
        for (int c = 0; c < 4; ++c) {
            bf16x8 v0 = *(const bf16x8*)&Vt[p][col     ][c*32 + quad*8];
            bf16x8 v1 = *(const bf16x8*)&Vt[p][col + 16][c*32 + quad*8];
            bf16x8 pf = *(const bf16x8*)&Pt[w][col][c*32 + quad*8];
            O0 = __builtin_amdgcn_mfma_f32_16x16x32_bf16(v0, pf, O0, 0, 0, 0);
            O1 = __builtin_amdgcn_mfma_f32_16x16x32_bf16(v1, pf, O1, 0, 0, 0);
        }
    }

    // ---- self tile (group B diagonal), 64 keys, buffer 0 ----
    if (kRow < 64) *(uint4*)&Kt[0][kRow][kCh] = kreg;
    if (vCh < 64)  *(uint4*)&Vt[0][vD][vCh]   = vreg;
    __syncthreads();
    if (grp == 1) {
        #pragma unroll
        for (int mt = 0; mt < 4; ++mt) {
            bf16x8 kf = *(const bf16x8*)&Kt[0][mt*16 + col][quad*8];
            f32x4 st = {0.f,0.f,0.f,0.f};
            st = __builtin_amdgcn_mfma_f32_16x16x32_bf16(kf, qf, st, 0, 0, 0);
            ushort4 pw;
            #pragma unroll
            for (int i = 0; i < 4; ++i) {
                float pv = __expf(st[i]*ATT_SCALE);
                if (mt*16 + quad*4 + i != 16*ws + col) pv = 0.f;
                unsigned short us = (unsigned short)f2bf(pv);
                ((unsigned short*)&pw)[i] = us;
                lsum += bf2f(us);
            }
            *(ushort4*)&Pt[w][col][mt*16 + quad*4] = pw;
        }
        #pragma unroll
        for (int c = 0; c < 2; ++c) {
            bf16x8 v0 = *(const bf16x8*)&Vt[0][col     ][c*32 + quad*8];
            bf16x8 v1 = *(const bf16x8*)&Vt[0][col + 16][c*32 + quad*8];
            bf16x8 pf = *(const bf16x8*)&Pt[w][col][c*32 + quad*8];
            O0 = __builtin_amdgcn_mfma_f32_16x16x32_bf16(v0, pf, O0, 0, 0, 0);
            O1 = __builtin_amdgcn_mfma_f32_16x16x32_bf16(v1, pf, O1, 0, 0, 0);
        }
    }

    lsum += __shfl_xor(lsum, 16, 64);
    lsum += __shfl_xor(lsum, 32, 64);
    float inv = 1.0f / lsum;
    ushort4 u0, u1;
    #pragma unroll
    for (int i = 0; i < 4; ++i) {
        ((unsigned short*)&u0)[i] = (unsigned short)f2bf(O0[i]*inv);
        ((unsigned short*)&u1)[i] = (unsigned short)f2bf(O1[i]*inv);
    }
    unsigned short* op = o + ((size_t)(q*BATCH + b))*DMODEL + h*DH;
    *(ushort4*)(op + quad*4)      = u0;
    *(ushort4*)(op + 16 + quad*4) = u1;
}

// ------- fused MLP, TWO 16-row groups, BK=64, 512 THREADS (8 waves) -----------
__global__ __launch_bounds__(512) void mlp_fused(
    const unsigned short* __restrict__ attb,
    const unsigned short* __restrict__ Wout, const float* __restrict__ ob,
    const float* __restrict__ g1, const float* __restrict__ be1,
    const unsigned short* __restrict__ W1, const float* __restrict__ fb1,
    const unsigned short* __restrict__ W2, const float* __restrict__ fb2,
    const float* __restrict__ g2, const float* __restrict__ be2,
    float* __restrict__ h, unsigned short* __restrict__ hb,
    const unsigned short* __restrict__ Wh1, const float* __restrict__ hb1,
    const float* __restrict__ hw2, const float* __restrict__ hb2,
    float* __restrict__ out, int doHead)
{
    __shared__ unsigned short Bs[3][256][64];         // 96 KB weight staging
    __shared__ __align__(16) unsigned char smem_u[33280];  // As (12 KB) / Pt (32.5 KB)
    __shared__ unsigned short Ht[2][16][264];         // LN1-out / LN2-out bf16
    __shared__ float sP[2][8][16], qP[2][8][16];

    typedef unsigned short AsT[2][16][64];
    AsT* As = reinterpret_cast<AsT*>(smem_u);
    typedef unsigned short PtT[16][520];
    PtT* Pt = reinterpret_cast<PtT*>(smem_u);

    const int tid  = threadIdx.x;
    const int w    = tid >> 6;            // 0..7
    const int lane = tid & 63;
    const int col  = lane & 15;
    const int quad = lane >> 4;
    const int l8   = lane >> 3;
    const int c8s  = (((lane & 7) ^ l8) * 8);
    const int bid  = blockIdx.x;
    const int m0a  = bid * 16;
    const int m0b  = 4096 + bid * 16;
    const int ma   = m0a + col;
    const int mb   = m0b + col;

    float resid[2][2][4];

    // ================= stage A: out-proj (K=256, NS=4) + residual + LN1 =======
    {
        f32x4 acc[2][2];
        #pragma unroll
        for (int g = 0; g < 2; ++g)
            #pragma unroll
            for (int j = 0; j < 2; ++j) acc[g][j] = (f32x4){0.f,0.f,0.f,0.f};

        const int gr = w >> 1;            // waves 0-3 stage As: group gr, half w&1
        const unsigned short* gaw = attb + (size_t)((gr ? m0b : m0a) + (w&1)*8 + l8)*DMODEL + c8s;
        const unsigned short* gb  = Wout + (size_t)(w*32 + l8)*DMODEL + c8s;
        const int NS = DMODEL / 64;  // 4

        #pragma unroll
        for (int pb = 0; pb < 2; ++pb) {
            int k = pb * 64;
            if (w < 4) gload16(gaw + k, &As[pb][gr][(w&1)*8][0]);
            #pragma unroll
            for (int t = 0; t < 4; ++t)
                gload16(gb + k + (size_t)(t*8)*DMODEL, &Bs[pb][w*32 + t*8][0]);
        }
        int bcur = 0;
        for (int s = 0; s < NS; ++s) {
            if (s == NS - 1)      { VMWAIT(0); }
            else if (w < 4)       { VMWAIT(5); }
            else                  { VMWAIT(4); }
            pipe_barrier();
            if (s + 2 < NS) {
                int bpre = bcur + 2; if (bpre >= 3) bpre -= 3;
                int k2 = (s + 2) * 64;
                if (w < 4) gload16(gaw + k2, &As[bpre][gr][(w&1)*8][0]);
                #pragma unroll
                for (int t = 0; t < 4; ++t)
                    gload16(gb + k2 + (size_t)(t*8)*DMODEL, &Bs[bpre][w*32 + t*8][0]);
            }
            #pragma unroll
            for (int kk = 0; kk < 2; ++kk) {
                const int so = (((kk*4 + quad) ^ (col & 7)) * 8);
                bf16x8 af0 = *(const bf16x8*)&As[bcur][0][col][so];
                bf16x8 af1 = *(const bf16x8*)&As[bcur][1][col][so];
                #pragma unroll
                for (int j = 0; j < 2; ++j) {
                    bf16x8 bfr = *(const bf16x8*)&Bs[bcur][w*32 + j*16 + col][so];
                    acc[0][j] = __builtin_amdgcn_mfma_f32_16x16x32_bf16(bfr, af0, acc[0][j], 0, 0, 0);
                    acc[1][j] = __builtin_amdgcn_mfma_f32_16x16x32_bf16(bfr, af1, acc[1][j], 0, 0, 0);
                }
            }
            bcur = (bcur == 2) ? 0 : bcur + 1;
        }

        float ssum[2] = {0.f, 0.f}, qsum[2] = {0.f, 0.f};
        #pragma unroll
        for (int g = 0; g < 2; ++g) {
            int m = g ? mb : ma;
            #pragma unroll
            for (int j = 0; j < 2; ++j) {
                int n = w*32 + j*16 + quad*4;
                float4 bi = *(const float4*)&ob[n];
                float4 hv = *(const float4*)&h[(size_t)m*DMODEL + n];
                #pragma unroll
                for (int i = 0; i < 4; ++i) {
                    float val = acc[g][j][i] + ((const float*)&bi)[i] + ((const float*)&hv)[i];
                    resid[g][j][i] = val;
                    ssum[g] += val; qsum[g] += val*val;
                }
            }
        }
        #pragma unroll
        for (int g = 0; g < 2; ++g) {
            ssum[g] += __shfl_xor(ssum[g], 16, 64); ssum[g] += __shfl_xor(ssum[g], 32, 64);
            qsum[g] += __shfl_xor(qsum[g], 16, 64); qsum[g] += __shfl_xor(qsum[g], 32, 64);
        }
        if (quad == 0) {
            sP[0][w][col] = ssum[0]; qP[0][w][col] = qsum[0];
            sP[1][w][col] = ssum[1]; qP[1][w][col] = qsum[1];
        }
        __syncthreads();
        #pragma unroll
        for (int g = 0; g < 2; ++g) {
            float st = 0.f, qt = 0.f;
            #pragma unroll
            for (int ww = 0; ww < 8; ++ww) { st += sP[g][ww][col]; qt += qP[g][ww][col]; }
            float mu   = st * (1.0f/DMODEL);
            float var  = qt * (1.0f/DMODEL) - mu*mu;
            float rstd = rsqrtf(var + 1e-5f);
            #pragma unroll
            for (int j = 0; j < 2; ++j) {
                int n = w*32 + j*16 + quad*4;
                float4 gv = *(const float4*)&g1[n];
                float4 bv = *(const float4*)&be1[n];
                ushort4 u;
                #pragma unroll
                for (int i = 0; i < 4; ++i) {
                    float o = (resid[g][j][i]-mu)*rstd*((const float*)&gv)[i] + ((const float*)&bv)[i];
                    resid[g][j][i] = o;
                    ((unsigned short*)&u)[i] = (unsigned short)f2bf(o);
                }
                *(ushort4*)&Ht[g][col][n] = u;
            }
        }
        __syncthreads();   // Ht visible; all waves past As/Bs reads
    }

    // ================= stage B: ff1 (K=256 NS=4, two N-halves) + gelu =========
    #pragma unroll 1
    for (int nh = 0; nh < 2; ++nh) {
        f32x4 acc[2][2];
        #pragma unroll
        for (int g = 0; g < 2; ++g)
            #pragma unroll
            for (int j = 0; j < 2; ++j) acc[g][j] = (f32x4){0.f,0.f,0.f,0.f};
        const unsigned short* gb = W1 + (size_t)(nh*256 + w*32 + l8)*DMODEL + c8s;
        const int NS = DMODEL / 64;  // 4

        #pragma unroll
        for (int pb = 0; pb < 2; ++pb)
            #pragma unroll
            for (int t = 0; t < 4; ++t)
                gload16(gb + pb*64 + (size_t)(t*8)*DMODEL, &Bs[pb][w*32 + t*8][0]);

        int bcur = 0;
        for (int s = 0; s < NS; ++s) {
            if (s == NS - 1) { VMWAIT(0); } else { VMWAIT(4); }
            pipe_barrier();
            if (s + 2 < NS) {
                int bpre = bcur + 2; if (bpre >= 3) bpre -= 3;
                int k2 = (s + 2) * 64;
                #pragma unroll
                for (int t = 0; t < 4; ++t)
                    gload16(gb + k2 + (size_t)(t*8)*DMODEL, &Bs[bpre][w*32 + t*8][0]);
            }
            #pragma unroll
            for (int kk = 0; kk < 2; ++kk) {
                const int so = (((kk*4 + quad) ^ (col & 7)) * 8);
                bf16x8 af0 = *(const bf16x8*)&Ht[0][col][s*64 + kk*32 + quad*8];
                bf16x8 af1 = *(const bf16x8*)&Ht[1][col][s*64 + kk*32 + quad*8];
                #pragma unroll
                for (int j = 0; j < 2; ++j) {
                    bf16x8 bfr = *(const bf16x8*)&Bs[bcur][w*32 + j*16 + col][so];
                    acc[0][j] = __builtin_amdgcn_mfma_f32_16x16x32_bf16(bfr, af0, acc[0][j], 0, 0, 0);
                    acc[1][j] = __builtin_amdgcn_mfma_f32_16x16x32_bf16(bfr, af1, acc[1][j], 0, 0, 0);
                }
            }
            bcur = (bcur == 2) ? 0 : bcur + 1;
        }
        #pragma unroll
        for (int g = 0; g < 2; ++g)
            #pragma unroll
            for (int j = 0; j < 2; ++j) {
                int n2 = nh*256 + w*32 + j*16 + quad*4;
                float4 bi = *(const float4*)&fb1[n2];
                ushort4 u;
                #pragma unroll
                for (int i = 0; i < 4; ++i)
                    ((unsigned short*)&u)[i] = (unsigned short)f2bf(gelu_exact(acc[g][j][i] + ((const float*)&bi)[i]));
                *(ushort4*)&Pt[g][col][n2] = u;
            }
        pipe_barrier();   // all waves past Bs reads before next half's staging
    }

    // ================= stage C: ff2 (K=512 NS=8) + residual + LN2 =============
    {
        __syncthreads();  // Pt visible
        f32x4 acc[2][2];
        #pragma unroll
        for (int g = 0; g < 2; ++g)
            #pragma unroll
            for (int j = 0; j < 2; ++j) acc[g][j] = (f32x4){0.f,0.f,0.f,0.f};
        const unsigned short* gb = W2 + (size_t)(w*32 + l8)*DFF + c8s;
        const int NS = DFF / 64;  // 8

        #pragma unroll
        for (int pb = 0; pb < 2; ++pb)
            #pragma unroll
            for (int t = 0; t < 4; ++t)
                gload16(gb + pb*64 + (size_t)(t*8)*DFF, &Bs[pb][w*32 + t*8][0]);

        int bcur = 0;
        for (int s = 0; s < NS; ++s) {
            if (s == NS - 1) { VMWAIT(0); } else { VMWAIT(4); }
            pipe_barrier();
            if (s + 2 < NS) {
                int bpre = bcur + 2; if (bpre >= 3) bpre -= 3;
                int k2 = (s + 2) * 64;
                #pragma unroll
                for (int t = 0; t < 4; ++t)
                    gload16(gb + k2 + (size_t)(t*8)*DFF, &Bs[bpre][w*32 + t*8][0]);
            }
            #pragma unroll
            for (int kk = 0; kk < 2; ++kk) {
                const int so = (((kk*4 + quad) ^ (col & 7)) * 8);
                bf16x8 af0 = *(const bf16x8*)&Pt[0][col][s*64 + kk*32 + quad*8];
                bf16x8 af1 = *(const bf16x8*)&Pt[1][col][s*64 + kk*32 + quad*8];
                #pragma unroll
                for (int j = 0; j < 2; ++j) {
                    bf16x8 bfr = *(const bf16x8*)&Bs[bcur][w*32 + j*16 + col][so];
                    acc[0][j] = __builtin_amdgcn_mfma_f32_16x16x32_bf16(bfr, af0, acc[0][j], 0, 0, 0);
                    acc[1][j] = __builtin_amdgcn_mfma_f32_16x16x32_bf16(bfr, af1, acc[1][j], 0, 0, 0);
                }
            }
            bcur = (bcur == 2) ? 0 : bcur + 1;
        }

        float ssum[2] = {0.f, 0.f}, qsum[2] = {0.f, 0.f};
        #pragma unroll
        for (int g = 0; g < 2; ++g)
            #pragma unroll
            for (int j = 0; j < 2; ++j) {
                int n = w*32 + j*16 + quad*4;
                float4 bi = *(const float4*)&fb2[n];
                #pragma unroll
                for (int i = 0; i < 4; ++i) {
                    float val = acc[g][j][i] + ((const float*)&bi)[i] + resid[g][j][i];
                    resid[g][j][i] = val;
                    ssum[g] += val; qsum[g] += val*val;
                }
            }
        #pragma unroll
        for (int g = 0; g < 2; ++g) {
            ssum[g] += __shfl_xor(ssum[g], 16, 64); ssum[g] += __shfl_xor(ssum[g], 32, 64);
            qsum[g] += __shfl_xor(qsum[g], 16, 64); qsum[g] += __shfl_xor(qsum[g], 32, 64);
        }
        if (quad == 0) {
            sP[0][w][col] = ssum[0]; qP[0][w][col] = qsum[0];
            sP[1][w][col] = ssum[1]; qP[1][w][col] = qsum[1];
        }
        __syncthreads();
        #pragma unroll
        for (int g = 0; g < 2; ++g) {
            int m = g ? mb : ma;
            float st = 0.f, qt = 0.f;
            #pragma unroll
            for (int ww = 0; ww < 8; ++ww) { st += sP[g][ww][col]; qt += qP[g][ww][col]; }
            float mu   = st * (1.0f/DMODEL);
            float var  = qt * (1.0f/DMODEL) - mu*mu;
            float rstd = rsqrtf(var + 1e-5f);
            #pragma unroll
            for (int j = 0; j < 2; ++j) {
                int n = w*32 + j*16 + quad*4;
                float4 gv = *(const float4*)&g2[n];
                float4 bv = *(const float4*)&be2[n];
                float4 o;
                ushort4 u;
                #pragma unroll
                for (int i = 0; i < 4; ++i) {
                    float ov = (resid[g][j][i]-mu)*rstd*((const float*)&gv)[i] + ((const float*)&bv)[i];
                    ((float*)&o)[i] = ov;
                    ((unsigned short*)&u)[i] = (unsigned short)f2bf(ov);
                }
                *(float4*)&h[(size_t)m*DMODEL + n] = o;
                *(ushort4*)(hb + (size_t)m*DMODEL + n) = u;
                *(ushort4*)&Ht[g][col][n] = u;   // LN2 bf16 for head
            }
        }
        __syncthreads();
    }

    // ================= stage D: head (layer 1; 16 head rows per block) ========
    if (doHead) {
        float sdot = 0.f;
        #pragma unroll 1
        for (int nh = 0; nh < 2; ++nh) {
            f32x4 acc[2];
            #pragma unroll
            for (int j = 0; j < 2; ++j) acc[j] = (f32x4){0.f,0.f,0.f,0.f};
            const unsigned short* gb = Wh1 + (size_t)(nh*256 + w*32 + l8)*DMODEL + c8s;
            const int NS = DMODEL / 64;  // 4

            #pragma unroll
            for (int pb = 0; pb < 2; ++pb)
                #pragma unroll
                for (int t = 0; t < 4; ++t)
                    gload16(gb + pb*64 + (size_t)(t*8)*DMODEL, &Bs[pb][w*32 + t*8][0]);

            int bcur = 0;
            for (int s = 0; s < NS; ++s) {
                if (s == NS - 1) { VMWAIT(0); } else { VMWAIT(4); }
                pipe_barrier();
                if (s + 2 < NS) {
                    int bpre = bcur + 2; if (bpre >= 3) bpre -= 3;
                    int k2 = (s + 2) * 64;
                    #pragma unroll
                    for (int t = 0; t < 4; ++t)
                        gload16(gb + k2 + (size_t)(t*8)*DMODEL, &Bs[bpre][w*32 + t*8][0]);
                }
                #pragma unroll
                for (int kk = 0; kk < 2; ++kk) {
                    const int so = (((kk*4 + quad) ^ (col & 7)) * 8);
                    bf16x8 af = *(const bf16x8*)&Ht[1][col][s*64 + kk*32 + quad*8];
                    #pragma unroll
                    for (int j = 0; j < 2; ++j) {
                        bf16x8 bfr = *(const bf16x8*)&Bs[bcur][w*32 + j*16 + col][so];
                        acc[j] = __builtin_amdgcn_mfma_f32_16x16x32_bf16(bfr, af, acc[j], 0, 0, 0);
                    }
                }
                bcur = (bcur == 2) ? 0 : bcur + 1;
            }
            #pragma unroll
            for (int j = 0; j < 2; ++j) {
                int n2 = nh*256 + w*32 + j*16 + quad*4;
                float4 b1v = *(const float4*)&hb1[n2];
                float4 w2v = *(const float4*)&hw2[n2];
                #pragma unroll
                for (int i = 0; i < 4; ++i)
                    sdot += gelu_exact(acc[j][i] + ((const float*)&b1v)[i]) * ((const float*)&w2v)[i];
            }
            pipe_barrier();
        }
        sdot += __shfl_xor(sdot, 16, 64); sdot += __shfl_xor(sdot, 32, 64);
        if (quad == 0) sP[0][w][col] = sdot;
        __syncthreads();
        if (tid < 16) {
            float r = hb2[0];
            #pragma unroll
            for (int ww = 0; ww < 8; ++ww) r += sP[0][ww][tid];
            out[bid*16 + tid] = r;
        }
    }
}

extern "C" void kernel_launch(void* const* d_in, const int* in_sizes, int n_in,
                              void* d_out, int out_size, void* d_ws, size_t ws_size,
                              hipStream_t stream)
{
    const float* x        = (const float*)d_in[0];
    const float* y        = (const float*)d_in[1];
    const float* xenc_w   = (const float*)d_in[3];
    const float* xenc_b   = (const float*)d_in[4];
    const float* yenc_w   = (const float*)d_in[5];
    const float* yenc_b   = (const float*)d_in[6];
    const float* in_proj_w  = (const float*)d_in[7];
    const float* in_proj_b  = (const float*)d_in[8];
    const float* out_proj_w = (const float*)d_in[9];
    const float* out_proj_b = (const float*)d_in[10];
    const float* ln1_g    = (const float*)d_in[11];
    const float* ln1_b    = (const float*)d_in[12];
    const float* lin1_w   = (const float*)d_in[13];
    const float* lin1_b   = (const float*)d_in[14];
    const float* lin2_w   = (const float*)d_in[15];
    const float* lin2_b   = (const float*)d_in[16];
    const float* ln2_g    = (const float*)d_in[17];
    const float* ln2_b    = (const float*)d_in[18];
    const float* head_w1  = (const float*)d_in[19];
    const float* head_b1  = (const float*)d_in[20];
    const float* head_w2  = (const float*)d_in[21];
    const float* head_b2  = (const float*)d_in[22];
    float* out = (float*)d_out;

    // ---- workspace layout ----
    float* ws  = (float*)d_ws;
    float* h    = ws;
    unsigned short* hb    = (unsigned short*)(h + (size_t)ROWS*DMODEL);
    unsigned short* attb  = hb    + (size_t)ROWS*DMODEL;
    unsigned short* Qg    = attb  + (size_t)ROWS*DMODEL;
    unsigned short* Kg    = Qg    + (size_t)BATCH*NHEAD*SEQ*DH;
    unsigned short* Vg    = Kg    + (size_t)BATCH*NHEAD*SEQ*DH;
    unsigned short* Wqkv  = Vg    + (size_t)BATCH*NHEAD*SEQ*DH;
    unsigned short* Wout  = Wqkv  + (size_t)NLAYER*3*DMODEL*DMODEL;
    unsigned short* Wl1   = Wout  + (size_t)NLAYER*DMODEL*DMODEL;
    unsigned short* Wl2   = Wl1   + (size_t)NLAYER*DFF*DMODEL;
    unsigned short* Wh1   = Wl2   + (size_t)NLAYER*DMODEL*DFF;

    encode_cast<<<ROWS/4 + 576, 256, 0, stream>>>(
        x, y, xenc_w, xenc_b, yenc_w, yenc_b, h, hb,
        in_proj_w, out_proj_w, lin1_w, lin2_w, head_w1,
        Wqkv, Wout, Wl1, Wl2, Wh1);

    for (int l = 0; l < NLAYER; ++l) {
        gemm_qkv<<<768, 512, 0, stream>>>(
            hb, Wqkv + (size_t)l*3*DMODEL*DMODEL, in_proj_b + l*3*DMODEL,
            Qg, Kg, Vg, DMODEL);
        attn_mfma<<<512, 512, 0, stream>>>(Qg, Kg, Vg, attb);
        mlp_fused<<<256, 512, 0, stream>>>(
            attb,
            Wout + (size_t)l*DMODEL*DMODEL, out_proj_b + l*DMODEL,
            ln1_g + l*DMODEL, ln1_b + l*DMODEL,
            Wl1 + (size_t)l*DFF*DMODEL, lin1_b + l*DFF,
            Wl2 + (size_t)l*DMODEL*DFF, lin2_b + l*DMODEL,
            ln2_g + l*DMODEL, ln2_b + l*DMODEL,
            h, hb,
            Wh1, head_b1, head_w2, head_b2,
            out, (l == NLAYER-1) ? 1 : 0);
    }
}

// Round 17
// 222.892 us; speedup vs baseline: 1.1200x; 1.0112x over previous
//
#include <hip/hip_runtime.h>
#include <hip/hip_bf16.h>
#include <math.h>

// Problem constants (fixed by setup_inputs)
#define SEQ    2048
#define BATCH  4
#define XDIM   16
#define DMODEL 256
#define NHEAD  8
#define DH     32
#define DFF    512
#define NLAYER 2
#define MPOS   1024
#define ROWS   (SEQ*BATCH)   // 8192

#define ATT_SCALE 0.17677669529663687f  // 1/sqrt(32)

typedef __attribute__((ext_vector_type(8))) short bf16x8;  // MFMA A/B frag
typedef __attribute__((ext_vector_type(4))) float f32x4;   // MFMA C/D frag

__device__ __forceinline__ float gelu_exact(float x) {
    return 0.5f * x * (1.0f + erff(x * 0.70710678118654752f));
}
__device__ __forceinline__ short f2bf(float f) {
    unsigned int u = __float_as_uint(f);
    u += 0x7FFFu + ((u >> 16) & 1u);
    return (short)(u >> 16);
}
__device__ __forceinline__ float bf2f(unsigned short u) {
    return __uint_as_float(((unsigned int)u) << 16);
}
__device__ __forceinline__ void gload16(const unsigned short* g, unsigned short* l) {
    __builtin_amdgcn_global_load_lds(
        (const __attribute__((address_space(1))) unsigned int*)g,
        (__attribute__((address_space(3))) unsigned int*)l, 16, 0, 0);
}
#define VMWAIT(N) asm volatile("s_waitcnt vmcnt(" #N ")" ::: "memory")
__device__ __forceinline__ void pipe_barrier() {
    __builtin_amdgcn_sched_barrier(0);
    __builtin_amdgcn_s_barrier();
    __builtin_amdgcn_sched_barrier(0);
}

// ---------------- encoder (4 rows/block) + weight casts, ONE launch -----------
__global__ __launch_bounds__(256) void encode_cast(
    const float* __restrict__ x, const float* __restrict__ y,
    const float* __restrict__ xw, const float* __restrict__ xb,
    const float* __restrict__ yw, const float* __restrict__ yb,
    float* __restrict__ h, unsigned short* __restrict__ hb,
    const float* __restrict__ s0, const float* __restrict__ s1,
    const float* __restrict__ s2, const float* __restrict__ s3,
    const float* __restrict__ s4,
    unsigned short* __restrict__ d0, unsigned short* __restrict__ d1,
    unsigned short* __restrict__ d2, unsigned short* __restrict__ d3,
    unsigned short* __restrict__ d4)
{
    if (blockIdx.x < ROWS/4) {
        int g = blockIdx.x;        // token index s (4 batch rows share it)
        int d = threadIdx.x;       // 0..255
        __shared__ float xs[4][XDIM];
        __shared__ float ys[4];
        if (d < 64) xs[d>>4][d&15] = x[(size_t)(g*4 + (d>>4))*XDIM + (d&15)];
        if (d < 4)  ys[d] = y[g*4 + d];
        __syncthreads();
        float wreg[XDIM];
        #pragma unroll
        for (int k = 0; k < XDIM; ++k) wreg[k] = xw[d*XDIM + k];
        const float xbv = xb[d], ywv = yw[d], ybv = yb[d];
        const bool train = (g < MPOS);
        #pragma unroll
        for (int r = 0; r < 4; ++r) {
            int row = g*4 + r;
            float acc = xbv;
            #pragma unroll
            for (int k = 0; k < XDIM; ++k) acc = fmaf(xs[r][k], wreg[k], acc);
            if (train) acc += ys[r]*ywv + ybv;
            h[(size_t)row*DMODEL + d]  = acc;
            hb[(size_t)row*DMODEL + d] = (unsigned short)f2bf(acc);
        }
        return;
    }
    int i = (blockIdx.x - ROWS/4)*256 + threadIdx.x;
    if (i >= 147456) return;
    const float* s; unsigned short* d; int off;
    if      (i <  49152) { s = s0; d = d0; off = i; }
    else if (i <  65536) { s = s1; d = d1; off = i - 49152; }
    else if (i <  98304) { s = s2; d = d2; off = i - 65536; }
    else if (i < 131072) { s = s3; d = d3; off = i - 98304; }
    else                 { s = s4; d = d4; off = i - 131072; }
    float4 a = *(const float4*)(s + (size_t)off*8);
    float4 c = *(const float4*)(s + (size_t)off*8 + 4);
    ushort4 u0, u1;
    u0.x=(unsigned short)f2bf(a.x); u0.y=(unsigned short)f2bf(a.y);
    u0.z=(unsigned short)f2bf(a.z); u0.w=(unsigned short)f2bf(a.w);
    u1.x=(unsigned short)f2bf(c.x); u1.y=(unsigned short)f2bf(c.y);
    u1.z=(unsigned short)f2bf(c.z); u1.w=(unsigned short)f2bf(c.w);
    *(ushort4*)(d + (size_t)off*8)     = u0;
    *(ushort4*)(d + (size_t)off*8 + 4) = u1;
}

// ------- qkv GEMM 128x64, BK=64 (NS=4), 512 THREADS (8 waves), XCD-local A ---
__global__ __launch_bounds__(512) void gemm_qkv(
    const unsigned short* __restrict__ A, const unsigned short* __restrict__ B,
    const float* __restrict__ bias,
    unsigned short* __restrict__ Qg, unsigned short* __restrict__ Kg,
    unsigned short* __restrict__ Vg, int K)
{
    __shared__ unsigned short As[2][128][64];   // 32 KB (reused as transpose buf)
    __shared__ unsigned short Bs[2][64][64];    // 16 KB
    int tid  = threadIdx.x;
    int w    = tid >> 6, lane = tid & 63;
    int col  = lane & 15, quad = lane >> 4;
    int wr   = w >> 1, wc = w & 1;
    int u    = blockIdx.x >> 3, xcd = blockIdx.x & 7;
    int by   = xcd*8 + u/12, bx = u%12;
    int m0   = by * 128, n0 = bx * 64;
    int l8   = lane >> 3;
    int c8s  = (((lane & 7) ^ l8) * 8);

    f32x4 acc[2][2];
    #pragma unroll
    for (int i = 0; i < 2; ++i)
        #pragma unroll
        for (int j = 0; j < 2; ++j) acc[i][j] = (f32x4){0.f,0.f,0.f,0.f};

    const unsigned short* ga = A + (size_t)(m0 + w*16 + l8)*K + c8s;
    const unsigned short* gb = B + (size_t)(n0 + w*8  + l8)*K + c8s;
    const int NS = K / 64;  // 4

    gload16(ga,                 &As[0][w*16    ][0]);
    gload16(ga + (size_t)8*K,   &As[0][w*16 + 8][0]);
    gload16(gb,                 &Bs[0][w*8     ][0]);

    for (int s = 0; s < NS; ++s) {
        VMWAIT(0);
        pipe_barrier();
        if (s + 1 < NS) {
            int k2 = (s + 1) * 64;
            int nb = (s + 1) & 1;
            gload16(ga + k2,               &As[nb][w*16    ][0]);
            gload16(ga + k2 + (size_t)8*K, &As[nb][w*16 + 8][0]);
            gload16(gb + k2,               &Bs[nb][w*8     ][0]);
        }
        int cur = s & 1;
        #pragma unroll
        for (int kk = 0; kk < 2; ++kk) {
            const int so = (((kk*4 + quad) ^ (col & 7)) * 8);
            bf16x8 af[2], bfr[2];
            #pragma unroll
            for (int i = 0; i < 2; ++i) af[i]  = *(const bf16x8*)&As[cur][wr*32 + i*16 + col][so];
            #pragma unroll
            for (int j = 0; j < 2; ++j) bfr[j] = *(const bf16x8*)&Bs[cur][wc*32 + j*16 + col][so];
            #pragma unroll
            for (int i = 0; i < 2; ++i)
                #pragma unroll
                for (int j = 0; j < 2; ++j)
                    acc[i][j] = __builtin_amdgcn_mfma_f32_16x16x32_bf16(bfr[j], af[i], acc[i][j], 0, 0, 0);
        }
    }

    int region = n0 >> 8;   // 0=Q, 1=K, 2=V (uniform per block)
    if (region < 2) {
        #pragma unroll
        for (int i = 0; i < 2; ++i) {
            int m = m0 + wr*32 + i*16 + col;
            int s = m >> 2, bidx = m & 3;
            #pragma unroll
            for (int j = 0; j < 2; ++j) {
                int ng = n0 + wc*32 + j*16 + quad*4;
                float4 bi = *(const float4*)&bias[ng];
                ushort4 uu;
                uu.x=(unsigned short)f2bf(acc[i][j][0] + bi.x);
                uu.y=(unsigned short)f2bf(acc[i][j][1] + bi.y);
                uu.z=(unsigned short)f2bf(acc[i][j][2] + bi.z);
                uu.w=(unsigned short)f2bf(acc[i][j][3] + bi.w);
                int np = ng - (region << 8);
                int hh = np >> 5, d = np & 31;
                int bh = bidx*NHEAD + hh;
                if (region == 0)
                    *(ushort4*)(Qg + ((size_t)(bh*SEQ + s))*DH + d) = uu;
                else
                    *(ushort4*)(Kg + ((size_t)(bh*SEQ + s))*DH + d) = uu;
            }
        }
    } else {
        __syncthreads();
        unsigned short* T3 = (unsigned short*)As;   // 16 KB scratch
        #pragma unroll
        for (int i = 0; i < 2; ++i) {
            int mi = wr*32 + i*16 + col;
            int ss = mi >> 2, bidx = mi & 3;
            #pragma unroll
            for (int j = 0; j < 2; ++j) {
                int ni = wc*32 + j*16 + quad*4;
                float4 bi = *(const float4*)&bias[n0 + ni];
                T3[((ni    )*4 + bidx)*32 + ss] = (unsigned short)f2bf(acc[i][j][0] + bi.x);
                T3[((ni + 1)*4 + bidx)*32 + ss] = (unsigned short)f2bf(acc[i][j][1] + bi.y);
                T3[((ni + 2)*4 + bidx)*32 + ss] = (unsigned short)f2bf(acc[i][j][2] + bi.z);
                T3[((ni + 3)*4 + bidx)*32 + ss] = (unsigned short)f2bf(acc[i][j][3] + bi.w);
            }
        }
        __syncthreads();
        int sBase = m0 >> 2;
        #pragma unroll
        for (int r = 0; r < 2; ++r) {
            int chunk = tid + 512*r;
            int l = chunk >> 2, p = chunk & 3;
            int d = l & 31, hh_l = (l >> 5) & 1, bidx = l >> 6;
            int ni = hh_l*32 + d;
            int hh = ((n0 & 255) + ni) >> 5;
            int bh = bidx*NHEAD + hh;
            uint4 val = *(const uint4*)&T3[(ni*4 + bidx)*32 + p*8];
            *(uint4*)(Vg + ((size_t)(bh*DH + d))*SEQ + sBase + p*8) = val;
        }
    }
}

// ------- MFMA flash attention, DUAL q-tile, KVBLK=128, 512 THREADS (8 waves) --
__global__ __launch_bounds__(512) void attn_mfma(
    const unsigned short* __restrict__ Qg,
    const unsigned short* __restrict__ Kg,
    const unsigned short* __restrict__ Vg,
    unsigned short* __restrict__ o)           // bf16 [s*B+b][256]
{
    const int id  = blockIdx.x;               // 0..511
    const int sl  = id >> 3;                  // 0..63
    const int bh  = (id & 7) * 4 + (sl >> 4); // XCD (id&7) owns bh [4x,4x+4)
    const int qt2 = sl & 15;
    const int h   = bh & 7;
    const int b   = bh >> 3;
    const int q0A = qt2 * 64;                 // low tile, q < MPOS
    const int q0B = MPOS + qt2 * 64;          // high tile, q >= MPOS
    const int tid  = threadIdx.x;
    const int w    = tid >> 6;                // 0..7
    const int ws   = w & 3;                   // slice within group
    const int grp  = w >> 2;                  // 0=A, 1=B
    const int lane = tid & 63;
    const int col  = lane & 15;
    const int quad = lane >> 4;

    __shared__ unsigned short Kt[2][128][40];   // [key][d]  20 KB
    __shared__ unsigned short Vt[2][32][136];   // [d][key]  17 KB
    __shared__ unsigned short Pt[8][16][136];   // per-wave P  34.8 KB

    const int q0 = grp ? q0B : q0A;
    const int q  = q0 + 16*ws + col;
    bf16x8 qf = *(const bf16x8*)(Qg + ((size_t)(bh*SEQ + q))*DH + quad*8);

    f32x4 O0 = {0.f,0.f,0.f,0.f};
    f32x4 O1 = {0.f,0.f,0.f,0.f};
    float lsum = 0.f;

    const int kRow = tid >> 2,  kCh = (tid & 3) * 8;    // 128 K-rows
    const int vD   = tid >> 4,  vCh = (tid & 15) * 8;   // 32 V-rows x 128 cols

    uint4 kreg = *(const uint4*)(Kg + ((size_t)(bh*SEQ + kRow))*DH + kCh);
    uint4 vreg = *(const uint4*)(Vg + ((size_t)(bh*DH + vD))*SEQ + vCh);

    for (int kt = 0; kt < 8; ++kt) {
        const int p = kt & 1;
        *(uint4*)&Kt[p][kRow][kCh] = kreg;
        *(uint4*)&Vt[p][vD][vCh]   = vreg;
        __syncthreads();
        if (kt < 7) {
            int kn = (kt + 1) * 128;
            kreg = *(const uint4*)(Kg + ((size_t)(bh*SEQ + kn + kRow))*DH + kCh);
            vreg = *(const uint4*)(Vg + ((size_t)(bh*DH + vD))*SEQ + kn + vCh);
        } else {
            // prefetch the 64-key self tile (keys [q0B, q0B+64))
            if (kRow < 64)
                kreg = *(const uint4*)(Kg + ((size_t)(bh*SEQ + q0B + kRow))*DH + kCh);
            if (vCh < 64)
                vreg = *(const uint4*)(Vg + ((size_t)(bh*DH + vD))*SEQ + q0B + vCh);
        }

        #pragma unroll
        for (int mt = 0; mt < 8; ++mt) {
            bf16x8 kf = *(const bf16x8*)&Kt[p][mt*16 + col][quad*8];
            f32x4 st = {0.f,0.f,0.f,0.f};
            st = __builtin_amdgcn_mfma_f32_16x16x32_bf16(kf, qf, st, 0, 0, 0);
            ushort4 pw;
            #pragma unroll
            for (int i = 0; i < 4; ++i) {
                float pv = __expf(st[i]*ATT_SCALE);
                unsigned short us = (unsigned short)f2bf(pv);
                ((unsigned short*)&pw)[i] = us;
                lsum += bf2f(us);
            }
            *(ushort4*)&Pt[w][col][mt*16 + quad*4] = pw;
        }
        #pragma unroll
        for (int c = 0; c < 4; ++c) {
            bf16x8 v0 = *(const bf16x8*)&Vt[p][col     ][c*32 + quad*8];
            bf16x8 v1 = *(const bf16x8*)&Vt[p][col + 16][c*32 + quad*8];
            bf16x8 pf = *(const bf16x8*)&Pt[w][col][c*32 + quad*8];
            O0 = __builtin_amdgcn_mfma_f32_16x16x32_bf16(v0, pf, O0, 0, 0, 0);
            O1 = __builtin_amdgcn_mfma_f32_16x16x32_bf16(v1, pf, O1, 0, 0, 0);
        }
    }

    // ---- self tile (group B diagonal), 64 keys, buffer 0 ----
    if (kRow < 64) *(uint4*)&Kt[0][kRow][kCh] = kreg;
    if (vCh < 64)  *(uint4*)&Vt[0][vD][vCh]   = vreg;
    __syncthreads();
    if (grp == 1) {
        #pragma unroll
        for (int mt = 0; mt < 4; ++mt) {
            bf16x8 kf = *(const bf16x8*)&Kt[0][mt*16 + col][quad*8];
            f32x4 st = {0.f,0.f,0.f,0.f};
            st = __builtin_amdgcn_mfma_f32_16x16x32_bf16(kf, qf, st, 0, 0, 0);
            ushort4 pw;
            #pragma unroll
            for (int i = 0; i < 4; ++i) {
                float pv = __expf(st[i]*ATT_SCALE);
                if (mt*16 + quad*4 + i != 16*ws + col) pv = 0.f;
                unsigned short us = (unsigned short)f2bf(pv);
                ((unsigned short*)&pw)[i] = us;
                lsum += bf2f(us);
            }
            *(ushort4*)&Pt[w][col][mt*16 + quad*4] = pw;
        }
        #pragma unroll
        for (int c = 0; c < 2; ++c) {
            bf16x8 v0 = *(const bf16x8*)&Vt[0][col     ][c*32 + quad*8];
            bf16x8 v1 = *(const bf16x8*)&Vt[0][col + 16][c*32 + quad*8];
            bf16x8 pf = *(const bf16x8*)&Pt[w][col][c*32 + quad*8];
            O0 = __builtin_amdgcn_mfma_f32_16x16x32_bf16(v0, pf, O0, 0, 0, 0);
            O1 = __builtin_amdgcn_mfma_f32_16x16x32_bf16(v1, pf, O1, 0, 0, 0);
        }
    }

    lsum += __shfl_xor(lsum, 16, 64);
    lsum += __shfl_xor(lsum, 32, 64);
    float inv = 1.0f / lsum;
    ushort4 u0, u1;
    #pragma unroll
    for (int i = 0; i < 4; ++i) {
        ((unsigned short*)&u0)[i] = (unsigned short)f2bf(O0[i]*inv);
        ((unsigned short*)&u1)[i] = (unsigned short)f2bf(O1[i]*inv);
    }
    unsigned short* op = o + ((size_t)(q*BATCH + b))*DMODEL + h*DH;
    *(ushort4*)(op + quad*4)      = u0;
    *(ushort4*)(op + 16 + quad*4) = u1;
}

// ------- fused MLP, TWO 16-row groups, BK=64, 512 THREADS, BARRIER-FREE B/C/D -
// Ownership audit: in stages B/C/D wave w reads ONLY the Bs rows it staged
// itself ([w*32, w*32+32)) and read-only Ht/Pt (synced at stage boundaries).
// So intra-loop barriers are pure convoy overhead -> removed; each wave is an
// independent 2-deep pipeline gated by its own vmcnt. Stage A keeps barriers
// (As staged by waves 0-3, read by all). Outputs bit-identical.
__global__ __launch_bounds__(512) void mlp_fused(
    const unsigned short* __restrict__ attb,
    const unsigned short* __restrict__ Wout, const float* __restrict__ ob,
    const float* __restrict__ g1, const float* __restrict__ be1,
    const unsigned short* __restrict__ W1, const float* __restrict__ fb1,
    const unsigned short* __restrict__ W2, const float* __restrict__ fb2,
    const float* __restrict__ g2, const float* __restrict__ be2,
    float* __restrict__ h, unsigned short* __restrict__ hb,
    const unsigned short* __restrict__ Wh1, const float* __restrict__ hb1,
    const float* __restrict__ hw2, const float* __restrict__ hb2,
    float* __restrict__ out, int doHead)
{
    __shared__ unsigned short Bs[3][256][64];         // 96 KB weight staging
    __shared__ __align__(16) unsigned char smem_u[33280];  // As (12 KB) / Pt (32.5 KB)
    __shared__ unsigned short Ht[2][16][264];         // LN1-out / LN2-out bf16
    __shared__ float sP[2][8][16], qP[2][8][16];

    typedef unsigned short AsT[2][16][64];
    AsT* As = reinterpret_cast<AsT*>(smem_u);
    typedef unsigned short PtT[16][520];
    PtT* Pt = reinterpret_cast<PtT*>(smem_u);

    const int tid  = threadIdx.x;
    const int w    = tid >> 6;            // 0..7
    const int lane = tid & 63;
    const int col  = lane & 15;
    const int quad = lane >> 4;
    const int l8   = lane >> 3;
    const int c8s  = (((lane & 7) ^ l8) * 8);
    const int bid  = blockIdx.x;
    const int m0a  = bid * 16;
    const int m0b  = 4096 + bid * 16;
    const int ma   = m0a + col;
    const int mb   = m0b + col;

    float resid[2][2][4];

    // ================= stage A: out-proj (K=256, NS=4) + residual + LN1 =======
    // As is cross-wave (staged by waves 0-3, read by all) -> keep barriers.
    {
        f32x4 acc[2][2];
        #pragma unroll
        for (int g = 0; g < 2; ++g)
            #pragma unroll
            for (int j = 0; j < 2; ++j) acc[g][j] = (f32x4){0.f,0.f,0.f,0.f};

        const int gr = w >> 1;            // waves 0-3 stage As: group gr, half w&1
        const unsigned short* gaw = attb + (size_t)((gr ? m0b : m0a) + (w&1)*8 + l8)*DMODEL + c8s;
        const unsigned short* gb  = Wout + (size_t)(w*32 + l8)*DMODEL + c8s;
        const int NS = DMODEL / 64;  // 4

        #pragma unroll
        for (int pb = 0; pb < 2; ++pb) {
            int k = pb * 64;
            if (w < 4) gload16(gaw + k, &As[pb][gr][(w&1)*8][0]);
            #pragma unroll
            for (int t = 0; t < 4; ++t)
                gload16(gb + k + (size_t)(t*8)*DMODEL, &Bs[pb][w*32 + t*8][0]);
        }
        int bcur = 0;
        for (int s = 0; s < NS; ++s) {
            if (s == NS - 1)      { VMWAIT(0); }
            else if (w < 4)       { VMWAIT(5); }
            else                  { VMWAIT(4); }
            pipe_barrier();
            if (s + 2 < NS) {
                int bpre = bcur + 2; if (bpre >= 3) bpre -= 3;
                int k2 = (s + 2) * 64;
                if (w < 4) gload16(gaw + k2, &As[bpre][gr][(w&1)*8][0]);
                #pragma unroll
                for (int t = 0; t < 4; ++t)
                    gload16(gb + k2 + (size_t)(t*8)*DMODEL, &Bs[bpre][w*32 + t*8][0]);
            }
            #pragma unroll
            for (int kk = 0; kk < 2; ++kk) {
                const int so = (((kk*4 + quad) ^ (col & 7)) * 8);
                bf16x8 af0 = *(const bf16x8*)&As[bcur][0][col][so];
                bf16x8 af1 = *(const bf16x8*)&As[bcur][1][col][so];
                #pragma unroll
                for (int j = 0; j < 2; ++j) {
                    bf16x8 bfr = *(const bf16x8*)&Bs[bcur][w*32 + j*16 + col][so];
                    acc[0][j] = __builtin_amdgcn_mfma_f32_16x16x32_bf16(bfr, af0, acc[0][j], 0, 0, 0);
                    acc[1][j] = __builtin_amdgcn_mfma_f32_16x16x32_bf16(bfr, af1, acc[1][j], 0, 0, 0);
                }
            }
            bcur = (bcur == 2) ? 0 : bcur + 1;
        }

        float ssum[2] = {0.f, 0.f}, qsum[2] = {0.f, 0.f};
        #pragma unroll
        for (int g = 0; g < 2; ++g) {
            int m = g ? mb : ma;
            #pragma unroll
            for (int j = 0; j < 2; ++j) {
                int n = w*32 + j*16 + quad*4;
                float4 bi = *(const float4*)&ob[n];
                float4 hv = *(const float4*)&h[(size_t)m*DMODEL + n];
                #pragma unroll
                for (int i = 0; i < 4; ++i) {
                    float val = acc[g][j][i] + ((const float*)&bi)[i] + ((const float*)&hv)[i];
                    resid[g][j][i] = val;
                    ssum[g] += val; qsum[g] += val*val;
                }
            }
        }
        #pragma unroll
        for (int g = 0; g < 2; ++g) {
            ssum[g] += __shfl_xor(ssum[g], 16, 64); ssum[g] += __shfl_xor(ssum[g], 32, 64);
            qsum[g] += __shfl_xor(qsum[g], 16, 64); qsum[g] += __shfl_xor(qsum[g], 32, 64);
        }
        if (quad == 0) {
            sP[0][w][col] = ssum[0]; qP[0][w][col] = qsum[0];
            sP[1][w][col] = ssum[1]; qP[1][w][col] = qsum[1];
        }
        __syncthreads();
        #pragma unroll
        for (int g = 0; g < 2; ++g) {
            float st = 0.f, qt = 0.f;
            #pragma unroll
            for (int ww = 0; ww < 8; ++ww) { st += sP[g][ww][col]; qt += qP[g][ww][col]; }
            float mu   = st * (1.0f/DMODEL);
            float var  = qt * (1.0f/DMODEL) - mu*mu;
            float rstd = rsqrtf(var + 1e-5f);
            #pragma unroll
            for (int j = 0; j < 2; ++j) {
                int n = w*32 + j*16 + quad*4;
                float4 gv = *(const float4*)&g1[n];
                float4 bv = *(const float4*)&be1[n];
                ushort4 u;
                #pragma unroll
                for (int i = 0; i < 4; ++i) {
                    float o = (resid[g][j][i]-mu)*rstd*((const float*)&gv)[i] + ((const float*)&bv)[i];
                    resid[g][j][i] = o;
                    ((unsigned short*)&u)[i] = (unsigned short)f2bf(o);
                }
                *(ushort4*)&Ht[g][col][n] = u;
            }
        }
        __syncthreads();   // Ht visible; all waves past As/Bs reads
    }

    // ====== stage B: ff1 (K=256 NS=4, two N-halves) + gelu — BARRIER-FREE =====
    #pragma unroll 1
    for (int nh = 0; nh < 2; ++nh) {
        f32x4 acc[2][2];
        #pragma unroll
        for (int g = 0; g < 2; ++g)
            #pragma unroll
            for (int j = 0; j < 2; ++j) acc[g][j] = (f32x4){0.f,0.f,0.f,0.f};
        const unsigned short* gb = W1 + (size_t)(nh*256 + w*32 + l8)*DMODEL + c8s;
        const int NS = DMODEL / 64;  // 4

        #pragma unroll
        for (int pb = 0; pb < 2; ++pb)
            #pragma unroll
            for (int t = 0; t < 4; ++t)
                gload16(gb + pb*64 + (size_t)(t*8)*DMODEL, &Bs[pb][w*32 + t*8][0]);

        int bcur = 0;
        for (int s = 0; s < NS; ++s) {
            if (s == NS - 1) { VMWAIT(0); } else { VMWAIT(4); }
            if (s + 2 < NS) {
                int bpre = bcur + 2; if (bpre >= 3) bpre -= 3;
                int k2 = (s + 2) * 64;
                #pragma unroll
                for (int t = 0; t < 4; ++t)
                    gload16(gb + k2 + (size_t)(t*8)*DMODEL, &Bs[bpre][w*32 + t*8][0]);
            }
            #pragma unroll
            for (int kk = 0; kk < 2; ++kk) {
                const int so = (((kk*4 + quad) ^ (col & 7)) * 8);
                bf16x8 af0 = *(const bf16x8*)&Ht[0][col][s*64 + kk*32 + quad*8];
                bf16x8 af1 = *(const bf16x8*)&Ht[1][col][s*64 + kk*32 + quad*8];
                #pragma unroll
                for (int j = 0; j < 2; ++j) {
                    bf16x8 bfr = *(const bf16x8*)&Bs[bcur][w*32 + j*16 + col][so];
                    acc[0][j] = __builtin_amdgcn_mfma_f32_16x16x32_bf16(bfr, af0, acc[0][j], 0, 0, 0);
                    acc[1][j] = __builtin_amdgcn_mfma_f32_16x16x32_bf16(bfr, af1, acc[1][j], 0, 0, 0);
                }
            }
            bcur = (bcur == 2) ? 0 : bcur + 1;
        }
        #pragma unroll
        for (int g = 0; g < 2; ++g)
            #pragma unroll
            for (int j = 0; j < 2; ++j) {
                int n2 = nh*256 + w*32 + j*16 + quad*4;
                float4 bi = *(const float4*)&fb1[n2];
                ushort4 u;
                #pragma unroll
                for (int i = 0; i < 4; ++i)
                    ((unsigned short*)&u)[i] = (unsigned short)f2bf(gelu_exact(acc[g][j][i] + ((const float*)&bi)[i]));
                *(ushort4*)&Pt[g][col][n2] = u;
            }
    }

    // ====== stage C: ff2 (K=512 NS=8) + residual + LN2 — BARRIER-FREE loop ====
    {
        __syncthreads();  // Pt visible (all waves wrote their column slices)
        f32x4 acc[2][2];
        #pragma unroll
        for (int g = 0; g < 2; ++g)
            #pragma unroll
            for (int j = 0; j < 2; ++j) acc[g][j] = (f32x4){0.f,0.f,0.f,0.f};
        const unsigned short* gb = W2 + (size_t)(w*32 + l8)*DFF + c8s;
        const int NS = DFF / 64;  // 8

        #pragma unroll
        for (int pb = 0; pb < 2; ++pb)
            #pragma unroll
            for (int t = 0; t < 4; ++t)
                gload16(gb + pb*64 + (size_t)(t*8)*DFF, &Bs[pb][w*32 + t*8][0]);

        int bcur = 0;
        for (int s = 0; s < NS; ++s) {
            if (s == NS - 1) { VMWAIT(0); } else { VMWAIT(4); }
            if (s + 2 < NS) {
                int bpre = bcur + 2; if (bpre >= 3) bpre -= 3;
                int k2 = (s + 2) * 64;
                #pragma unroll
                for (int t = 0; t < 4; ++t)
                    gload16(gb + k2 + (size_t)(t*8)*DFF, &Bs[bpre][w*32 + t*8][0]);
            }
            #pragma unroll
            for (int kk = 0; kk < 2; ++kk) {
                const int so = (((kk*4 + quad) ^ (col & 7)) * 8);
                bf16x8 af0 = *(const bf16x8*)&Pt[0][col][s*64 + kk*32 + quad*8];
                bf16x8 af1 = *(const bf16x8*)&Pt[1][col][s*64 + kk*32 + quad*8];
                #pragma unroll
                for (int j = 0; j < 2; ++j) {
                    bf16x8 bfr = *(const bf16x8*)&Bs[bcur][w*32 + j*16 + col][so];
                    acc[0][j] = __builtin_amdgcn_mfma_f32_16x16x32_bf16(bfr, af0, acc[0][j], 0, 0, 0);
                    acc[1][j] = __builtin_amdgcn_mfma_f32_16x16x32_bf16(bfr, af1, acc[1][j], 0, 0, 0);
                }
            }
            bcur = (bcur == 2) ? 0 : bcur + 1;
        }

        float ssum[2] = {0.f, 0.f}, qsum[2] = {0.f, 0.f};
        #pragma unroll
        for (int g = 0; g < 2; ++g)
            #pragma unroll
            for (int j = 0; j < 2; ++j) {
                int n = w*32 + j*16 + quad*4;
                float4 bi = *(const float4*)&fb2[n];
                #pragma unroll
                for (int i = 0; i < 4; ++i) {
                    float val = acc[g][j][i] + ((const float*)&bi)[i] + resid[g][j][i];
                    resid[g][j][i] = val;
                    ssum[g] += val; qsum[g] += val*val;
                }
            }
        #pragma unroll
        for (int g = 0; g < 2; ++g) {
            ssum[g] += __shfl_xor(ssum[g], 16, 64); ssum[g] += __shfl_xor(ssum[g], 32, 64);
            qsum[g] += __shfl_xor(qsum[g], 16, 64); qsum[g] += __shfl_xor(qsum[g], 32, 64);
        }
        if (quad == 0) {
            sP[0][w][col] = ssum[0]; qP[0][w][col] = qsum[0];
            sP[1][w][col] = ssum[1]; qP[1][w][col] = qsum[1];
        }
        __syncthreads();
        #pragma unroll
        for (int g = 0; g < 2; ++g) {
            int m = g ? mb : ma;
            float st = 0.f, qt = 0.f;
            #pragma unroll
            for (int ww = 0; ww < 8; ++ww) { st += sP[g][ww][col]; qt += qP[g][ww][col]; }
            float mu   = st * (1.0f/DMODEL);
            float var  = qt * (1.0f/DMODEL) - mu*mu;
            float rstd = rsqrtf(var + 1e-5f);
            #pragma unroll
            for (int j = 0; j < 2; ++j) {
                int n = w*32 + j*16 + quad*4;
                float4 gv = *(const float4*)&g2[n];
                float4 bv = *(const float4*)&be2[n];
                float4 o;
                ushort4 u;
                #pragma unroll
                for (int i = 0; i < 4; ++i) {
                    float ov = (resid[g][j][i]-mu)*rstd*((const float*)&gv)[i] + ((const float*)&bv)[i];
                    ((float*)&o)[i] = ov;
                    ((unsigned short*)&u)[i] = (unsigned short)f2bf(ov);
                }
                *(float4*)&h[(size_t)m*DMODEL + n] = o;
                *(ushort4*)(hb + (size_t)m*DMODEL + n) = u;
                *(ushort4*)&Ht[g][col][n] = u;   // LN2 bf16 for head
            }
        }
        __syncthreads();
    }

    // ====== stage D: head (layer 1; 16 head rows/block) — BARRIER-FREE loop ===
    if (doHead) {
        float sdot = 0.f;
        #pragma unroll 1
        for (int nh = 0; nh < 2; ++nh) {
            f32x4 acc[2];
            #pragma unroll
            for (int j = 0; j < 2; ++j) acc[j] = (f32x4){0.f,0.f,0.f,0.f};
            const unsigned short* gb = Wh1 + (size_t)(nh*256 + w*32 + l8)*DMODEL + c8s;
            const int NS = DMODEL / 64;  // 4

            #pragma unroll
            for (int pb = 0; pb < 2; ++pb)
                #pragma unroll
                for (int t = 0; t < 4; ++t)
                    gload16(gb + pb*64 + (size_t)(t*8)*DMODEL, &Bs[pb][w*32 + t*8][0]);

            int bcur = 0;
            for (int s = 0; s < NS; ++s) {
                if (s == NS - 1) { VMWAIT(0); } else { VMWAIT(4); }
                if (s + 2 < NS) {
                    int bpre = bcur + 2; if (bpre >= 3) bpre -= 3;
                    int k2 = (s + 2) * 64;
                    #pragma unroll
                    for (int t = 0; t < 4; ++t)
                        gload16(gb + k2 + (size_t)(t*8)*DMODEL, &Bs[bpre][w*32 + t*8][0]);
                }
                #pragma unroll
                for (int kk = 0; kk < 2; ++kk) {
                    const int so = (((kk*4 + quad) ^ (col & 7)) * 8);
                    bf16x8 af = *(const bf16x8*)&Ht[1][col][s*64 + kk*32 + quad*8];
                    #pragma unroll
                    for (int j = 0; j < 2; ++j) {
                        bf16x8 bfr = *(const bf16x8*)&Bs[bcur][w*32 + j*16 + col][so];
                        acc[j] = __builtin_amdgcn_mfma_f32_16x16x32_bf16(bfr, af, acc[j], 0, 0, 0);
                    }
                }
                bcur = (bcur == 2) ? 0 : bcur + 1;
            }
            #pragma unroll
            for (int j = 0; j < 2; ++j) {
                int n2 = nh*256 + w*32 + j*16 + quad*4;
                float4 b1v = *(const float4*)&hb1[n2];
                float4 w2v = *(const float4*)&hw2[n2];
                #pragma unroll
                for (int i = 0; i < 4; ++i)
                    sdot += gelu_exact(acc[j][i] + ((const float*)&b1v)[i]) * ((const float*)&w2v)[i];
            }
        }
        sdot += __shfl_xor(sdot, 16, 64); sdot += __shfl_xor(sdot, 32, 64);
        if (quad == 0) sP[0][w][col] = sdot;
        __syncthreads();
        if (tid < 16) {
            float r = hb2[0];
            #pragma unroll
            for (int ww = 0; ww < 8; ++ww) r += sP[0][ww][tid];
            out[bid*16 + tid] = r;
        }
    }
}

extern "C" void kernel_launch(void* const* d_in, const int* in_sizes, int n_in,
                              void* d_out, int out_size, void* d_ws, size_t ws_size,
                              hipStream_t stream)
{
    const float* x        = (const float*)d_in[0];
    const float* y        = (const float*)d_in[1];
    const float* xenc_w   = (const float*)d_in[3];
    const float* xenc_b   = (const float*)d_in[4];
    const float* yenc_w   = (const float*)d_in[5];
    const float* yenc_b   = (const float*)d_in[6];
    const float* in_proj_w  = (const float*)d_in[7];
    const float* in_proj_b  = (const float*)d_in[8];
    const float* out_proj_w = (const float*)d_in[9];
    const float* out_proj_b = (const float*)d_in[10];
    const float* ln1_g    = (const float*)d_in[11];
    const float* ln1_b    = (const float*)d_in[12];
    const float* lin1_w   = (const float*)d_in[13];
    const float* lin1_b   = (const float*)d_in[14];
    const float* lin2_w   = (const float*)d_in[15];
    const float* lin2_b   = (const float*)d_in[16];
    const float* ln2_g    = (const float*)d_in[17];
    const float* ln2_b    = (const float*)d_in[18];
    const float* head_w1  = (const float*)d_in[19];
    const float* head_b1  = (const float*)d_in[20];
    const float* head_w2  = (const float*)d_in[21];
    const float* head_b2  = (const float*)d_in[22];
    float* out = (float*)d_out;

    // ---- workspace layout ----
    float* ws  = (float*)d_ws;
    float* h    = ws;
    unsigned short* hb    = (unsigned short*)(h + (size_t)ROWS*DMODEL);
    unsigned short* attb  = hb    + (size_t)ROWS*DMODEL;
    unsigned short* Qg    = attb  + (size_t)ROWS*DMODEL;
    unsigned short* Kg    = Qg    + (size_t)BATCH*NHEAD*SEQ*DH;
    unsigned short* Vg    = Kg    + (size_t)BATCH*NHEAD*SEQ*DH;
    unsigned short* Wqkv  = Vg    + (size_t)BATCH*NHEAD*SEQ*DH;
    unsigned short* Wout  = Wqkv  + (size_t)NLAYER*3*DMODEL*DMODEL;
    unsigned short* Wl1   = Wout  + (size_t)NLAYER*DMODEL*DMODEL;
    unsigned short* Wl2   = Wl1   + (size_t)NLAYER*DFF*DMODEL;
    unsigned short* Wh1   = Wl2   + (size_t)NLAYER*DMODEL*DFF;

    encode_cast<<<ROWS/4 + 576, 256, 0, stream>>>(
        x, y, xenc_w, xenc_b, yenc_w, yenc_b, h, hb,
        in_proj_w, out_proj_w, lin1_w, lin2_w, head_w1,
        Wqkv, Wout, Wl1, Wl2, Wh1);

    for (int l = 0; l < NLAYER; ++l) {
        gemm_qkv<<<768, 512, 0, stream>>>(
            hb, Wqkv + (size_t)l*3*DMODEL*DMODEL, in_proj_b + l*3*DMODEL,
            Qg, Kg, Vg, DMODEL);
        attn_mfma<<<512, 512, 0, stream>>>(Qg, Kg, Vg, attb);
        mlp_fused<<<256, 512, 0, stream>>>(
            attb,
            Wout + (size_t)l*DMODEL*DMODEL, out_proj_b + l*DMODEL,
            ln1_g + l*DMODEL, ln1_b + l*DMODEL,
            Wl1 + (size_t)l*DFF*DMODEL, lin1_b + l*DFF,
            Wl2 + (size_t)l*DMODEL*DFF, lin2_b + l*DMODEL,
            ln2_g + l*DMODEL, ln2_b + l*DMODEL,
            h, hb,
            Wh1, head_b1, head_w2, head_b2,
            out, (l == NLAYER-1) ? 1 : 0);
    }
}

// Round 18
// 220.884 us; speedup vs baseline: 1.1302x; 1.0091x over previous
//
#include <hip/hip_runtime.h>
#include <hip/hip_bf16.h>
#include <math.h>

// Problem constants (fixed by setup_inputs)
#define SEQ    2048
#define BATCH  4
#define XDIM   16
#define DMODEL 256
#define NHEAD  8
#define DH     32
#define DFF    512
#define NLAYER 2
#define MPOS   1024
#define ROWS   (SEQ*BATCH)   // 8192

#define ATT_SCALE 0.17677669529663687f  // 1/sqrt(32)

typedef __attribute__((ext_vector_type(8))) short bf16x8;  // MFMA A/B frag
typedef __attribute__((ext_vector_type(4))) float f32x4;   // MFMA C/D frag

__device__ __forceinline__ float gelu_exact(float x) {
    return 0.5f * x * (1.0f + erff(x * 0.70710678118654752f));
}
__device__ __forceinline__ short f2bf(float f) {
    unsigned int u = __float_as_uint(f);
    u += 0x7FFFu + ((u >> 16) & 1u);
    return (short)(u >> 16);
}
__device__ __forceinline__ float bf2f(unsigned short u) {
    return __uint_as_float(((unsigned int)u) << 16);
}
__device__ __forceinline__ void gload16(const unsigned short* g, unsigned short* l) {
    __builtin_amdgcn_global_load_lds(
        (const __attribute__((address_space(1))) unsigned int*)g,
        (__attribute__((address_space(3))) unsigned int*)l, 16, 0, 0);
}
#define VMWAIT(N) asm volatile("s_waitcnt vmcnt(" #N ")" ::: "memory")
__device__ __forceinline__ void pipe_barrier() {
    __builtin_amdgcn_sched_barrier(0);
    __builtin_amdgcn_s_barrier();
    __builtin_amdgcn_sched_barrier(0);
}

// ---------------- encoder (4 rows/block) + weight casts, ONE launch -----------
__global__ __launch_bounds__(256) void encode_cast(
    const float* __restrict__ x, const float* __restrict__ y,
    const float* __restrict__ xw, const float* __restrict__ xb,
    const float* __restrict__ yw, const float* __restrict__ yb,
    float* __restrict__ h, unsigned short* __restrict__ hb,
    const float* __restrict__ s0, const float* __restrict__ s1,
    const float* __restrict__ s2, const float* __restrict__ s3,
    const float* __restrict__ s4,
    unsigned short* __restrict__ d0, unsigned short* __restrict__ d1,
    unsigned short* __restrict__ d2, unsigned short* __restrict__ d3,
    unsigned short* __restrict__ d4)
{
    if (blockIdx.x < ROWS/4) {
        int g = blockIdx.x;        // token index s (4 batch rows share it)
        int d = threadIdx.x;       // 0..255
        __shared__ float xs[4][XDIM];
        __shared__ float ys[4];
        if (d < 64) xs[d>>4][d&15] = x[(size_t)(g*4 + (d>>4))*XDIM + (d&15)];
        if (d < 4)  ys[d] = y[g*4 + d];
        __syncthreads();
        float wreg[XDIM];
        #pragma unroll
        for (int k = 0; k < XDIM; ++k) wreg[k] = xw[d*XDIM + k];
        const float xbv = xb[d], ywv = yw[d], ybv = yb[d];
        const bool train = (g < MPOS);
        #pragma unroll
        for (int r = 0; r < 4; ++r) {
            int row = g*4 + r;
            float acc = xbv;
            #pragma unroll
            for (int k = 0; k < XDIM; ++k) acc = fmaf(xs[r][k], wreg[k], acc);
            if (train) acc += ys[r]*ywv + ybv;
            h[(size_t)row*DMODEL + d]  = acc;
            hb[(size_t)row*DMODEL + d] = (unsigned short)f2bf(acc);
        }
        return;
    }
    int i = (blockIdx.x - ROWS/4)*256 + threadIdx.x;
    if (i >= 147456) return;
    const float* s; unsigned short* d; int off;
    if      (i <  49152) { s = s0; d = d0; off = i; }
    else if (i <  65536) { s = s1; d = d1; off = i - 49152; }
    else if (i <  98304) { s = s2; d = d2; off = i - 65536; }
    else if (i < 131072) { s = s3; d = d3; off = i - 98304; }
    else                 { s = s4; d = d4; off = i - 131072; }
    float4 a = *(const float4*)(s + (size_t)off*8);
    float4 c = *(const float4*)(s + (size_t)off*8 + 4);
    ushort4 u0, u1;
    u0.x=(unsigned short)f2bf(a.x); u0.y=(unsigned short)f2bf(a.y);
    u0.z=(unsigned short)f2bf(a.z); u0.w=(unsigned short)f2bf(a.w);
    u1.x=(unsigned short)f2bf(c.x); u1.y=(unsigned short)f2bf(c.y);
    u1.z=(unsigned short)f2bf(c.z); u1.w=(unsigned short)f2bf(c.w);
    *(ushort4*)(d + (size_t)off*8)     = u0;
    *(ushort4*)(d + (size_t)off*8 + 4) = u1;
}

// ------- qkv GEMM 128x64, BARRIER-FREE K-loop, 512 threads, XCD-local A ------
// Bsf = whole B tile preloaded once (read-only after ONE barrier). Wave w owns
// output rows [w*16,w*16+16) x all 64 cols and stages its OWN As rows -> the
// K-loop has no barriers; per-wave vmcnt(0) + lgkmcnt(0) gate the single-buffer
// As reuse. Same kk/s accumulation order as before -> bit-identical outputs.
__global__ __launch_bounds__(512) void gemm_qkv(
    const unsigned short* __restrict__ A, const unsigned short* __restrict__ B,
    const float* __restrict__ bias,
    unsigned short* __restrict__ Qg, unsigned short* __restrict__ Kg,
    unsigned short* __restrict__ Vg, int K)
{
    __shared__ unsigned short Bsf[4][64][64];   // 32 KB, whole B tile (K=256)
    __shared__ unsigned short As[8][16][64];    // 16 KB, per-wave rows (T3 alias)
    int tid  = threadIdx.x;
    int w    = tid >> 6, lane = tid & 63;
    int col  = lane & 15, quad = lane >> 4;
    int u    = blockIdx.x >> 3, xcd = blockIdx.x & 7;
    int by   = xcd*8 + u/12, bx = u%12;
    int m0   = by * 128, n0 = bx * 64;
    int l8   = lane >> 3;
    int c8s  = (((lane & 7) ^ l8) * 8);

    f32x4 acc[4];
    #pragma unroll
    for (int j = 0; j < 4; ++j) acc[j] = (f32x4){0.f,0.f,0.f,0.f};

    const unsigned short* ga = A + (size_t)(m0 + w*16 + l8)*K + c8s;
    const int NS = K / 64;  // 4

    // prologue: preload whole Bsf (wave pair (w>>1) stages seg, 32 rows each)
    {
        int seg = w >> 1;
        int r0  = (w & 1) * 32;
        const unsigned short* gbw = B + (size_t)(n0 + r0 + l8)*K + seg*64 + c8s;
        #pragma unroll
        for (int t = 0; t < 4; ++t)
            gload16(gbw + (size_t)(t*8)*K, &Bsf[seg][r0 + t*8][0]);
    }
    gload16(ga,               &As[w][0][0]);
    gload16(ga + (size_t)8*K, &As[w][8][0]);
    VMWAIT(0);
    pipe_barrier();   // Bsf + all As step-0 visible; ONLY barrier before epilogue

    for (int s = 0; s < NS; ++s) {
        if (s > 0) VMWAIT(0);   // own As loads for step s complete (per-wave)
        // pull both A fragments into registers before overwriting As
        bf16x8 af0 = *(const bf16x8*)&As[w][col][(((0*4 + quad) ^ (col & 7)) * 8)];
        bf16x8 af1 = *(const bf16x8*)&As[w][col][(((1*4 + quad) ^ (col & 7)) * 8)];
        asm volatile("s_waitcnt lgkmcnt(0)" ::: "memory");
        __builtin_amdgcn_sched_barrier(0);
        if (s + 1 < NS) {
            int k2 = (s + 1) * 64;
            gload16(ga + k2,               &As[w][0][0]);
            gload16(ga + k2 + (size_t)8*K, &As[w][8][0]);
        }
        #pragma unroll
        for (int kk = 0; kk < 2; ++kk) {
            const int so = (((kk*4 + quad) ^ (col & 7)) * 8);
            bf16x8 af = kk ? af1 : af0;
            #pragma unroll
            for (int j = 0; j < 4; ++j) {
                bf16x8 bfr = *(const bf16x8*)&Bsf[s][j*16 + col][so];
                acc[j] = __builtin_amdgcn_mfma_f32_16x16x32_bf16(bfr, af, acc[j], 0, 0, 0);
            }
        }
    }

    int region = n0 >> 8;   // 0=Q, 1=K, 2=V (uniform per block)
    if (region < 2) {
        int m = m0 + w*16 + col;
        int s = m >> 2, bidx = m & 3;
        #pragma unroll
        for (int j = 0; j < 4; ++j) {
            int ng = n0 + j*16 + quad*4;
            float4 bi = *(const float4*)&bias[ng];
            ushort4 uu;
            uu.x=(unsigned short)f2bf(acc[j][0] + bi.x);
            uu.y=(unsigned short)f2bf(acc[j][1] + bi.y);
            uu.z=(unsigned short)f2bf(acc[j][2] + bi.z);
            uu.w=(unsigned short)f2bf(acc[j][3] + bi.w);
            int np = ng - (region << 8);
            int hh = np >> 5, d = np & 31;
            int bh = bidx*NHEAD + hh;
            if (region == 0)
                *(ushort4*)(Qg + ((size_t)(bh*SEQ + s))*DH + d) = uu;
            else
                *(ushort4*)(Kg + ((size_t)(bh*SEQ + s))*DH + d) = uu;
        }
    } else {
        __syncthreads();   // all waves done with As before aliasing it as T3
        unsigned short* T3 = (unsigned short*)As;   // 16 KB scratch
        int mi = w*16 + col;
        int ss = mi >> 2, bidx = mi & 3;
        #pragma unroll
        for (int j = 0; j < 4; ++j) {
            int ni = j*16 + quad*4;
            float4 bi = *(const float4*)&bias[n0 + ni];
            T3[((ni    )*4 + bidx)*32 + ss] = (unsigned short)f2bf(acc[j][0] + bi.x);
            T3[((ni + 1)*4 + bidx)*32 + ss] = (unsigned short)f2bf(acc[j][1] + bi.y);
            T3[((ni + 2)*4 + bidx)*32 + ss] = (unsigned short)f2bf(acc[j][2] + bi.z);
            T3[((ni + 3)*4 + bidx)*32 + ss] = (unsigned short)f2bf(acc[j][3] + bi.w);
        }
        __syncthreads();
        int sBase = m0 >> 2;
        #pragma unroll
        for (int r = 0; r < 2; ++r) {
            int chunk = tid + 512*r;
            int l = chunk >> 2, p = chunk & 3;
            int d = l & 31, hh_l = (l >> 5) & 1, bidx2 = l >> 6;
            int ni = hh_l*32 + d;
            int hh = ((n0 & 255) + ni) >> 5;
            int bh = bidx2*NHEAD + hh;
            uint4 val = *(const uint4*)&T3[(ni*4 + bidx2)*32 + p*8];
            *(uint4*)(Vg + ((size_t)(bh*DH + d))*SEQ + sBase + p*8) = val;
        }
    }
}

// ------- MFMA flash attention, DUAL q-tile, KVBLK=128, 512 THREADS (8 waves) --
__global__ __launch_bounds__(512) void attn_mfma(
    const unsigned short* __restrict__ Qg,
    const unsigned short* __restrict__ Kg,
    const unsigned short* __restrict__ Vg,
    unsigned short* __restrict__ o)           // bf16 [s*B+b][256]
{
    const int id  = blockIdx.x;               // 0..511
    const int sl  = id >> 3;                  // 0..63
    const int bh  = (id & 7) * 4 + (sl >> 4); // XCD (id&7) owns bh [4x,4x+4)
    const int qt2 = sl & 15;
    const int h   = bh & 7;
    const int b   = bh >> 3;
    const int q0A = qt2 * 64;                 // low tile, q < MPOS
    const int q0B = MPOS + qt2 * 64;          // high tile, q >= MPOS
    const int tid  = threadIdx.x;
    const int w    = tid >> 6;                // 0..7
    const int ws   = w & 3;                   // slice within group
    const int grp  = w >> 2;                  // 0=A, 1=B
    const int lane = tid & 63;
    const int col  = lane & 15;
    const int quad = lane >> 4;

    __shared__ unsigned short Kt[2][128][40];   // [key][d]  20 KB
    __shared__ unsigned short Vt[2][32][136];   // [d][key]  17 KB
    __shared__ unsigned short Pt[8][16][136];   // per-wave P  34.8 KB

    const int q0 = grp ? q0B : q0A;
    const int q  = q0 + 16*ws + col;
    bf16x8 qf = *(const bf16x8*)(Qg + ((size_t)(bh*SEQ + q))*DH + quad*8);

    f32x4 O0 = {0.f,0.f,0.f,0.f};
    f32x4 O1 = {0.f,0.f,0.f,0.f};
    float lsum = 0.f;

    const int kRow = tid >> 2,  kCh = (tid & 3) * 8;    // 128 K-rows
    const int vD   = tid >> 4,  vCh = (tid & 15) * 8;   // 32 V-rows x 128 cols

    uint4 kreg = *(const uint4*)(Kg + ((size_t)(bh*SEQ + kRow))*DH + kCh);
    uint4 vreg = *(const uint4*)(Vg + ((size_t)(bh*DH + vD))*SEQ + vCh);

    for (int kt = 0; kt < 8; ++kt) {
        const int p = kt & 1;
        *(uint4*)&Kt[p][kRow][kCh] = kreg;
        *(uint4*)&Vt[p][vD][vCh]   = vreg;
        __syncthreads();
        if (kt < 7) {
            int kn = (kt + 1) * 128;
            kreg = *(const uint4*)(Kg + ((size_t)(bh*SEQ + kn + kRow))*DH + kCh);
            vreg = *(const uint4*)(Vg + ((size_t)(bh*DH + vD))*SEQ + kn + vCh);
        } else {
            // prefetch the 64-key self tile (keys [q0B, q0B+64))
            if (kRow < 64)
                kreg = *(const uint4*)(Kg + ((size_t)(bh*SEQ + q0B + kRow))*DH + kCh);
            if (vCh < 64)
                vreg = *(const uint4*)(Vg + ((size_t)(bh*DH + vD))*SEQ + q0B + vCh);
        }

        #pragma unroll
        for (int mt = 0; mt < 8; ++mt) {
            bf16x8 kf = *(const bf16x8*)&Kt[p][mt*16 + col][quad*8];
            f32x4 st = {0.f,0.f,0.f,0.f};
            st = __builtin_amdgcn_mfma_f32_16x16x32_bf16(kf, qf, st, 0, 0, 0);
            ushort4 pw;
            #pragma unroll
            for (int i = 0; i < 4; ++i) {
                float pv = __expf(st[i]*ATT_SCALE);
                unsigned short us = (unsigned short)f2bf(pv);
                ((unsigned short*)&pw)[i] = us;
                lsum += bf2f(us);
            }
            *(ushort4*)&Pt[w][col][mt*16 + quad*4] = pw;
        }
        #pragma unroll
        for (int c = 0; c < 4; ++c) {
            bf16x8 v0 = *(const bf16x8*)&Vt[p][col     ][c*32 + quad*8];
            bf16x8 v1 = *(const bf16x8*)&Vt[p][col + 16][c*32 + quad*8];
            bf16x8 pf = *(const bf16x8*)&Pt[w][col][c*32 + quad*8];
            O0 = __builtin_amdgcn_mfma_f32_16x16x32_bf16(v0, pf, O0, 0, 0, 0);
            O1 = __builtin_amdgcn_mfma_f32_16x16x32_bf16(v1, pf, O1, 0, 0, 0);
        }
    }

    // ---- self tile (group B diagonal), 64 keys, buffer 0 ----
    if (kRow < 64) *(uint4*)&Kt[0][kRow][kCh] = kreg;
    if (vCh < 64)  *(uint4*)&Vt[0][vD][vCh]   = vreg;
    __syncthreads();
    if (grp == 1) {
        #pragma unroll
        for (int mt = 0; mt < 4; ++mt) {
            bf16x8 kf = *(const bf16x8*)&Kt[0][mt*16 + col][quad*8];
            f32x4 st = {0.f,0.f,0.f,0.f};
            st = __builtin_amdgcn_mfma_f32_16x16x32_bf16(kf, qf, st, 0, 0, 0);
            ushort4 pw;
            #pragma unroll
            for (int i = 0; i < 4; ++i) {
                float pv = __expf(st[i]*ATT_SCALE);
                if (mt*16 + quad*4 + i != 16*ws + col) pv = 0.f;
                unsigned short us = (unsigned short)f2bf(pv);
                ((unsigned short*)&pw)[i] = us;
                lsum += bf2f(us);
            }
            *(ushort4*)&Pt[w][col][mt*16 + quad*4] = pw;
        }
        #pragma unroll
        for (int c = 0; c < 2; ++c) {
            bf16x8 v0 = *(const bf16x8*)&Vt[0][col     ][c*32 + quad*8];
            bf16x8 v1 = *(const bf16x8*)&Vt[0][col + 16][c*32 + quad*8];
            bf16x8 pf = *(const bf16x8*)&Pt[w][col][c*32 + quad*8];
            O0 = __builtin_amdgcn_mfma_f32_16x16x32_bf16(v0, pf, O0, 0, 0, 0);
            O1 = __builtin_amdgcn_mfma_f32_16x16x32_bf16(v1, pf, O1, 0, 0, 0);
        }
    }

    lsum += __shfl_xor(lsum, 16, 64);
    lsum += __shfl_xor(lsum, 32, 64);
    float inv = 1.0f / lsum;
    ushort4 u0, u1;
    #pragma unroll
    for (int i = 0; i < 4; ++i) {
        ((unsigned short*)&u0)[i] = (unsigned short)f2bf(O0[i]*inv);
        ((unsigned short*)&u1)[i] = (unsigned short)f2bf(O1[i]*inv);
    }
    unsigned short* op = o + ((size_t)(q*BATCH + b))*DMODEL + h*DH;
    *(ushort4*)(op + quad*4)      = u0;
    *(ushort4*)(op + 16 + quad*4) = u1;
}

// ------- fused MLP, TWO 16-row groups, BK=64, 512 THREADS, BARRIER-FREE B/C/D -
__global__ __launch_bounds__(512) void mlp_fused(
    const unsigned short* __restrict__ attb,
    const unsigned short* __restrict__ Wout, const float* __restrict__ ob,
    const float* __restrict__ g1, const float* __restrict__ be1,
    const unsigned short* __restrict__ W1, const float* __restrict__ fb1,
    const unsigned short* __restrict__ W2, const float* __restrict__ fb2,
    const float* __restrict__ g2, const float* __restrict__ be2,
    float* __restrict__ h, unsigned short* __restrict__ hb,
    const unsigned short* __restrict__ Wh1, const float* __restrict__ hb1,
    const float* __restrict__ hw2, const float* __restrict__ hb2,
    float* __restrict__ out, int doHead)
{
    __shared__ unsigned short Bs[3][256][64];         // 96 KB weight staging
    __shared__ __align__(16) unsigned char smem_u[33280];  // As (12 KB) / Pt (32.5 KB)
    __shared__ unsigned short Ht[2][16][264];         // LN1-out / LN2-out bf16
    __shared__ float sP[2][8][16], qP[2][8][16];

    typedef unsigned short AsT[2][16][64];
    AsT* As = reinterpret_cast<AsT*>(smem_u);
    typedef unsigned short PtT[16][520];
    PtT* Pt = reinterpret_cast<PtT*>(smem_u);

    const int tid  = threadIdx.x;
    const int w    = tid >> 6;            // 0..7
    const int lane = tid & 63;
    const int col  = lane & 15;
    const int quad = lane >> 4;
    const int l8   = lane >> 3;
    const int c8s  = (((lane & 7) ^ l8) * 8);
    const int bid  = blockIdx.x;
    const int m0a  = bid * 16;
    const int m0b  = 4096 + bid * 16;
    const int ma   = m0a + col;
    const int mb   = m0b + col;

    float resid[2][2][4];

    // ================= stage A: out-proj (K=256, NS=4) + residual + LN1 =======
    {
        f32x4 acc[2][2];
        #pragma unroll
        for (int g = 0; g < 2; ++g)
            #pragma unroll
            for (int j = 0; j < 2; ++j) acc[g][j] = (f32x4){0.f,0.f,0.f,0.f};

        const int gr = w >> 1;            // waves 0-3 stage As: group gr, half w&1
        const unsigned short* gaw = attb + (size_t)((gr ? m0b : m0a) + (w&1)*8 + l8)*DMODEL + c8s;
        const unsigned short* gb  = Wout + (size_t)(w*32 + l8)*DMODEL + c8s;
        const int NS = DMODEL / 64;  // 4

        #pragma unroll
        for (int pb = 0; pb < 2; ++pb) {
            int k = pb * 64;
            if (w < 4) gload16(gaw + k, &As[pb][gr][(w&1)*8][0]);
            #pragma unroll
            for (int t = 0; t < 4; ++t)
                gload16(gb + k + (size_t)(t*8)*DMODEL, &Bs[pb][w*32 + t*8][0]);
        }
        int bcur = 0;
        for (int s = 0; s < NS; ++s) {
            if (s == NS - 1)      { VMWAIT(0); }
            else if (w < 4)       { VMWAIT(5); }
            else                  { VMWAIT(4); }
            pipe_barrier();
            if (s + 2 < NS) {
                int bpre = bcur + 2; if (bpre >= 3) bpre -= 3;
                int k2 = (s + 2) * 64;
                if (w < 4) gload16(gaw + k2, &As[bpre][gr][(w&1)*8][0]);
                #pragma unroll
                for (int t = 0; t < 4; ++t)
                    gload16(gb + k2 + (size_t)(t*8)*DMODEL, &Bs[bpre][w*32 + t*8][0]);
            }
            #pragma unroll
            for (int kk = 0; kk < 2; ++kk) {
                const int so = (((kk*4 + quad) ^ (col & 7)) * 8);
                bf16x8 af0 = *(const bf16x8*)&As[bcur][0][col][so];
                bf16x8 af1 = *(const bf16x8*)&As[bcur][1][col][so];
                #pragma unroll
                for (int j = 0; j < 2; ++j) {
                    bf16x8 bfr = *(const bf16x8*)&Bs[bcur][w*32 + j*16 + col][so];
                    acc[0][j] = __builtin_amdgcn_mfma_f32_16x16x32_bf16(bfr, af0, acc[0][j], 0, 0, 0);
                    acc[1][j] = __builtin_amdgcn_mfma_f32_16x16x32_bf16(bfr, af1, acc[1][j], 0, 0, 0);
                }
            }
            bcur = (bcur == 2) ? 0 : bcur + 1;
        }

        float ssum[2] = {0.f, 0.f}, qsum[2] = {0.f, 0.f};
        #pragma unroll
        for (int g = 0; g < 2; ++g) {
            int m = g ? mb : ma;
            #pragma unroll
            for (int j = 0; j < 2; ++j) {
                int n = w*32 + j*16 + quad*4;
                float4 bi = *(const float4*)&ob[n];
                float4 hv = *(const float4*)&h[(size_t)m*DMODEL + n];
                #pragma unroll
                for (int i = 0; i < 4; ++i) {
                    float val = acc[g][j][i] + ((const float*)&bi)[i] + ((const float*)&hv)[i];
                    resid[g][j][i] = val;
                    ssum[g] += val; qsum[g] += val*val;
                }
            }
        }
        #pragma unroll
        for (int g = 0; g < 2; ++g) {
            ssum[g] += __shfl_xor(ssum[g], 16, 64); ssum[g] += __shfl_xor(ssum[g], 32, 64);
            qsum[g] += __shfl_xor(qsum[g], 16, 64); qsum[g] += __shfl_xor(qsum[g], 32, 64);
        }
        if (quad == 0) {
            sP[0][w][col] = ssum[0]; qP[0][w][col] = qsum[0];
            sP[1][w][col] = ssum[1]; qP[1][w][col] = qsum[1];
        }
        __syncthreads();
        #pragma unroll
        for (int g = 0; g < 2; ++g) {
            float st = 0.f, qt = 0.f;
            #pragma unroll
            for (int ww = 0; ww < 8; ++ww) { st += sP[g][ww][col]; qt += qP[g][ww][col]; }
            float mu   = st * (1.0f/DMODEL);
            float var  = qt * (1.0f/DMODEL) - mu*mu;
            float rstd = rsqrtf(var + 1e-5f);
            #pragma unroll
            for (int j = 0; j < 2; ++j) {
                int n = w*32 + j*16 + quad*4;
                float4 gv = *(const float4*)&g1[n];
                float4 bv = *(const float4*)&be1[n];
                ushort4 u;
                #pragma unroll
                for (int i = 0; i < 4; ++i) {
                    float o = (resid[g][j][i]-mu)*rstd*((const float*)&gv)[i] + ((const float*)&bv)[i];
                    resid[g][j][i] = o;
                    ((unsigned short*)&u)[i] = (unsigned short)f2bf(o);
                }
                *(ushort4*)&Ht[g][col][n] = u;
            }
        }
        __syncthreads();   // Ht visible; all waves past As/Bs reads
    }

    // ====== stage B: ff1 (K=256 NS=4, two N-halves) + gelu — BARRIER-FREE =====
    #pragma unroll 1
    for (int nh = 0; nh < 2; ++nh) {
        f32x4 acc[2][2];
        #pragma unroll
        for (int g = 0; g < 2; ++g)
            #pragma unroll
            for (int j = 0; j < 2; ++j) acc[g][j] = (f32x4){0.f,0.f,0.f,0.f};
        const unsigned short* gb = W1 + (size_t)(nh*256 + w*32 + l8)*DMODEL + c8s;
        const int NS = DMODEL / 64;  // 4

        #pragma unroll
        for (int pb = 0; pb < 2; ++pb)
            #pragma unroll
            for (int t = 0; t < 4; ++t)
                gload16(gb + pb*64 + (size_t)(t*8)*DMODEL, &Bs[pb][w*32 + t*8][0]);

        int bcur = 0;
        for (int s = 0; s < NS; ++s) {
            if (s == NS - 1) { VMWAIT(0); } else { VMWAIT(4); }
            if (s + 2 < NS) {
                int bpre = bcur + 2; if (bpre >= 3) bpre -= 3;
                int k2 = (s + 2) * 64;
                #pragma unroll
                for (int t = 0; t < 4; ++t)
                    gload16(gb + k2 + (size_t)(t*8)*DMODEL, &Bs[bpre][w*32 + t*8][0]);
            }
            #pragma unroll
            for (int kk = 0; kk < 2; ++kk) {
                const int so = (((kk*4 + quad) ^ (col & 7)) * 8);
                bf16x8 af0 = *(const bf16x8*)&Ht[0][col][s*64 + kk*32 + quad*8];
                bf16x8 af1 = *(const bf16x8*)&Ht[1][col][s*64 + kk*32 + quad*8];
                #pragma unroll
                for (int j = 0; j < 2; ++j) {
                    bf16x8 bfr = *(const bf16x8*)&Bs[bcur][w*32 + j*16 + col][so];
                    acc[0][j] = __builtin_amdgcn_mfma_f32_16x16x32_bf16(bfr, af0, acc[0][j], 0, 0, 0);
                    acc[1][j] = __builtin_amdgcn_mfma_f32_16x16x32_bf16(bfr, af1, acc[1][j], 0, 0, 0);
                }
            }
            bcur = (bcur == 2) ? 0 : bcur + 1;
        }
        #pragma unroll
        for (int g = 0; g < 2; ++g)
            #pragma unroll
            for (int j = 0; j < 2; ++j) {
                int n2 = nh*256 + w*32 + j*16 + quad*4;
                float4 bi = *(const float4*)&fb1[n2];
                ushort4 u;
                #pragma unroll
                for (int i = 0; i < 4; ++i)
                    ((unsigned short*)&u)[i] = (unsigned short)f2bf(gelu_exact(acc[g][j][i] + ((const float*)&bi)[i]));
                *(ushort4*)&Pt[g][col][n2] = u;
            }
    }

    // ====== stage C: ff2 (K=512 NS=8) + residual + LN2 — BARRIER-FREE loop ====
    {
        __syncthreads();  // Pt visible (all waves wrote their column slices)
        f32x4 acc[2][2];
        #pragma unroll
        for (int g = 0; g < 2; ++g)
            #pragma unroll
            for (int j = 0; j < 2; ++j) acc[g][j] = (f32x4){0.f,0.f,0.f,0.f};
        const unsigned short* gb = W2 + (size_t)(w*32 + l8)*DFF + c8s;
        const int NS = DFF / 64;  // 8

        #pragma unroll
        for (int pb = 0; pb < 2; ++pb)
            #pragma unroll
            for (int t = 0; t < 4; ++t)
                gload16(gb + pb*64 + (size_t)(t*8)*DFF, &Bs[pb][w*32 + t*8][0]);

        int bcur = 0;
        for (int s = 0; s < NS; ++s) {
            if (s == NS - 1) { VMWAIT(0); } else { VMWAIT(4); }
            if (s + 2 < NS) {
                int bpre = bcur + 2; if (bpre >= 3) bpre -= 3;
                int k2 = (s + 2) * 64;
                #pragma unroll
                for (int t = 0; t < 4; ++t)
                    gload16(gb + k2 + (size_t)(t*8)*DFF, &Bs[bpre][w*32 + t*8][0]);
            }
            #pragma unroll
            for (int kk = 0; kk < 2; ++kk) {
                const int so = (((kk*4 + quad) ^ (col & 7)) * 8);
                bf16x8 af0 = *(const bf16x8*)&Pt[0][col][s*64 + kk*32 + quad*8];
                bf16x8 af1 = *(const bf16x8*)&Pt[1][col][s*64 + kk*32 + quad*8];
                #pragma unroll
                for (int j = 0; j < 2; ++j) {
                    bf16x8 bfr = *(const bf16x8*)&Bs[bcur][w*32 + j*16 + col][so];
                    acc[0][j] = __builtin_amdgcn_mfma_f32_16x16x32_bf16(bfr, af0, acc[0][j], 0, 0, 0);
                    acc[1][j] = __builtin_amdgcn_mfma_f32_16x16x32_bf16(bfr, af1, acc[1][j], 0, 0, 0);
                }
            }
            bcur = (bcur == 2) ? 0 : bcur + 1;
        }

        float ssum[2] = {0.f, 0.f}, qsum[2] = {0.f, 0.f};
        #pragma unroll
        for (int g = 0; g < 2; ++g)
            #pragma unroll
            for (int j = 0; j < 2; ++j) {
                int n = w*32 + j*16 + quad*4;
                float4 bi = *(const float4*)&fb2[n];
                #pragma unroll
                for (int i = 0; i < 4; ++i) {
                    float val = acc[g][j][i] + ((const float*)&bi)[i] + resid[g][j][i];
                    resid[g][j][i] = val;
                    ssum[g] += val; qsum[g] += val*val;
                }
            }
        #pragma unroll
        for (int g = 0; g < 2; ++g) {
            ssum[g] += __shfl_xor(ssum[g], 16, 64); ssum[g] += __shfl_xor(ssum[g], 32, 64);
            qsum[g] += __shfl_xor(qsum[g], 16, 64); qsum[g] += __shfl_xor(qsum[g], 32, 64);
        }
        if (quad == 0) {
            sP[0][w][col] = ssum[0]; qP[0][w][col] = qsum[0];
            sP[1][w][col] = ssum[1]; qP[1][w][col] = qsum[1];
        }
        __syncthreads();
        #pragma unroll
        for (int g = 0; g < 2; ++g) {
            int m = g ? mb : ma;
            float st = 0.f, qt = 0.f;
            #pragma unroll
            for (int ww = 0; ww < 8; ++ww) { st += sP[g][ww][col]; qt += qP[g][ww][col]; }
            float mu   = st * (1.0f/DMODEL);
            float var  = qt * (1.0f/DMODEL) - mu*mu;
            float rstd = rsqrtf(var + 1e-5f);
            #pragma unroll
            for (int j = 0; j < 2; ++j) {
                int n = w*32 + j*16 + quad*4;
                float4 gv = *(const float4*)&g2[n];
                float4 bv = *(const float4*)&be2[n];
                float4 o;
                ushort4 u;
                #pragma unroll
                for (int i = 0; i < 4; ++i) {
                    float ov = (resid[g][j][i]-mu)*rstd*((const float*)&gv)[i] + ((const float*)&bv)[i];
                    ((float*)&o)[i] = ov;
                    ((unsigned short*)&u)[i] = (unsigned short)f2bf(ov);
                }
                *(float4*)&h[(size_t)m*DMODEL + n] = o;
                *(ushort4*)(hb + (size_t)m*DMODEL + n) = u;
                *(ushort4*)&Ht[g][col][n] = u;   // LN2 bf16 for head
            }
        }
        __syncthreads();
    }

    // ====== stage D: head (layer 1; 16 head rows/block) — BARRIER-FREE loop ===
    if (doHead) {
        float sdot = 0.f;
        #pragma unroll 1
        for (int nh = 0; nh < 2; ++nh) {
            f32x4 acc[2];
            #pragma unroll
            for (int j = 0; j < 2; ++j) acc[j] = (f32x4){0.f,0.f,0.f,0.f};
            const unsigned short* gb = Wh1 + (size_t)(nh*256 + w*32 + l8)*DMODEL + c8s;
            const int NS = DMODEL / 64;  // 4

            #pragma unroll
            for (int pb = 0; pb < 2; ++pb)
                #pragma unroll
                for (int t = 0; t < 4; ++t)
                    gload16(gb + pb*64 + (size_t)(t*8)*DMODEL, &Bs[pb][w*32 + t*8][0]);

            int bcur = 0;
            for (int s = 0; s < NS; ++s) {
                if (s == NS - 1) { VMWAIT(0); } else { VMWAIT(4); }
                if (s + 2 < NS) {
                    int bpre = bcur + 2; if (bpre >= 3) bpre -= 3;
                    int k2 = (s + 2) * 64;
                    #pragma unroll
                    for (int t = 0; t < 4; ++t)
                        gload16(gb + k2 + (size_t)(t*8)*DMODEL, &Bs[bpre][w*32 + t*8][0]);
                }
                #pragma unroll
                for (int kk = 0; kk < 2; ++kk) {
                    const int so = (((kk*4 + quad) ^ (col & 7)) * 8);
                    bf16x8 af = *(const bf16x8*)&Ht[1][col][s*64 + kk*32 + quad*8];
                    #pragma unroll
                    for (int j = 0; j < 2; ++j) {
                        bf16x8 bfr = *(const bf16x8*)&Bs[bcur][w*32 + j*16 + col][so];
                        acc[j] = __builtin_amdgcn_mfma_f32_16x16x32_bf16(bfr, af, acc[j], 0, 0, 0);
                    }
                }
                bcur = (bcur == 2) ? 0 : bcur + 1;
            }
            #pragma unroll
            for (int j = 0; j < 2; ++j) {
                int n2 = nh*256 + w*32 + j*16 + quad*4;
                float4 b1v = *(const float4*)&hb1[n2];
                float4 w2v = *(const float4*)&hw2[n2];
                #pragma unroll
                for (int i = 0; i < 4; ++i)
                    sdot += gelu_exact(acc[j][i] + ((const float*)&b1v)[i]) * ((const float*)&w2v)[i];
            }
        }
        sdot += __shfl_xor(sdot, 16, 64); sdot += __shfl_xor(sdot, 32, 64);
        if (quad == 0) sP[0][w][col] = sdot;
        __syncthreads();
        if (tid < 16) {
            float r = hb2[0];
            #pragma unroll
            for (int ww = 0; ww < 8; ++ww) r += sP[0][ww][tid];
            out[bid*16 + tid] = r;
        }
    }
}

extern "C" void kernel_launch(void* const* d_in, const int* in_sizes, int n_in,
                              void* d_out, int out_size, void* d_ws, size_t ws_size,
                              hipStream_t stream)
{
    const float* x        = (const float*)d_in[0];
    const float* y        = (const float*)d_in[1];
    const float* xenc_w   = (const float*)d_in[3];
    const float* xenc_b   = (const float*)d_in[4];
    const float* yenc_w   = (const float*)d_in[5];
    const float* yenc_b   = (const float*)d_in[6];
    const float* in_proj_w  = (const float*)d_in[7];
    const float* in_proj_b  = (const float*)d_in[8];
    const float* out_proj_w = (const float*)d_in[9];
    const float* out_proj_b = (const float*)d_in[10];
    const float* ln1_g    = (const float*)d_in[11];
    const float* ln1_b    = (const float*)d_in[12];
    const float* lin1_w   = (const float*)d_in[13];
    const float* lin1_b   = (const float*)d_in[14];
    const float* lin2_w   = (const float*)d_in[15];
    const float* lin2_b   = (const float*)d_in[16];
    const float* ln2_g    = (const float*)d_in[17];
    const float* ln2_b    = (const float*)d_in[18];
    const float* head_w1  = (const float*)d_in[19];
    const float* head_b1  = (const float*)d_in[20];
    const float* head_w2  = (const float*)d_in[21];
    const float* head_b2  = (const float*)d_in[22];
    float* out = (float*)d_out;

    // ---- workspace layout ----
    float* ws  = (float*)d_ws;
    float* h    = ws;
    unsigned short* hb    = (unsigned short*)(h + (size_t)ROWS*DMODEL);
    unsigned short* attb  = hb    + (size_t)ROWS*DMODEL;
    unsigned short* Qg    = attb  + (size_t)ROWS*DMODEL;
    unsigned short* Kg    = Qg    + (size_t)BATCH*NHEAD*SEQ*DH;
    unsigned short* Vg    = Kg    + (size_t)BATCH*NHEAD*SEQ*DH;
    unsigned short* Wqkv  = Vg    + (size_t)BATCH*NHEAD*SEQ*DH;
    unsigned short* Wout  = Wqkv  + (size_t)NLAYER*3*DMODEL*DMODEL;
    unsigned short* Wl1   = Wout  + (size_t)NLAYER*DMODEL*DMODEL;
    unsigned short* Wl2   = Wl1   + (size_t)NLAYER*DFF*DMODEL;
    unsigned short* Wh1   = Wl2   + (size_t)NLAYER*DMODEL*DFF;

    encode_cast<<<ROWS/4 + 576, 256, 0, stream>>>(
        x, y, xenc_w, xenc_b, yenc_w, yenc_b, h, hb,
        in_proj_w, out_proj_w, lin1_w, lin2_w, head_w1,
        Wqkv, Wout, Wl1, Wl2, Wh1);

    for (int l = 0; l < NLAYER; ++l) {
        gemm_qkv<<<768, 512, 0, stream>>>(
            hb, Wqkv + (size_t)l*3*DMODEL*DMODEL, in_proj_b + l*3*DMODEL,
            Qg, Kg, Vg, DMODEL);
        attn_mfma<<<512, 512, 0, stream>>>(Qg, Kg, Vg, attb);
        mlp_fused<<<256, 512, 0, stream>>>(
            attb,
            Wout + (size_t)l*DMODEL*DMODEL, out_proj_b + l*DMODEL,
            ln1_g + l*DMODEL, ln1_b + l*DMODEL,
            Wl1 + (size_t)l*DFF*DMODEL, lin1_b + l*DFF,
            Wl2 + (size_t)l*DMODEL*DFF, lin2_b + l*DMODEL,
            ln2_g + l*DMODEL, ln2_b + l*DMODEL,
            h, hb,
            Wh1, head_b1, head_w2, head_b2,
            out, (l == NLAYER-1) ? 1 : 0);
    }
}